// Round 1
// baseline (768.923 us; speedup 1.0000x reference)
//
#include <hip/hip_runtime.h>
#include <math.h>

#define NH 8
#define DHD 64
#define DMODEL 512
#define QB 16
#define SEQ 512
#define NROWS (QB*SEQ)      /* 8192 rows per input */
#define NHQ (NH*QB)         /* 128 (h,q) pairs */

__device__ __forceinline__ float clampf(float x, float lo, float hi){ return fminf(fmaxf(x, lo), hi); }

// cov constant: (0.001/512) / (8 + 1e-8)  (8+1e-8 rounds to 8.0f in fp32, matching jnp)
#define KCOV ((0.001f/512.0f)/(8.0f+1e-8f))

// ---------------------------------------------------------------- K1a: LN row stats
__global__ void __launch_bounds__(256) ln_stats_kernel(
    const float* __restrict__ xq, const float* __restrict__ xk, const float* __restrict__ xv,
    float* __restrict__ mu, float* __restrict__ rstd)
{
  int which = blockIdx.y;
  const float* src = which==0 ? xq : (which==1 ? xk : xv);
  int w = threadIdx.x >> 6, lane = threadIdx.x & 63;
  int row = blockIdx.x*4 + w;
  const float* x = src + (size_t)row*DMODEL;
  float4 v1 = *reinterpret_cast<const float4*>(&x[lane*8]);
  float4 v2 = *reinterpret_cast<const float4*>(&x[lane*8+4]);
  float s  = v1.x+v1.y+v1.z+v1.w + v2.x+v2.y+v2.z+v2.w;
  float ss = v1.x*v1.x+v1.y*v1.y+v1.z*v1.z+v1.w*v1.w
           + v2.x*v2.x+v2.y*v2.y+v2.z*v2.z+v2.w*v2.w;
  #pragma unroll
  for (int m=32; m>0; m>>=1){ s += __shfl_xor(s,m,64); ss += __shfl_xor(ss,m,64); }
  if (lane==0){
    float m_ = s*(1.0f/DMODEL);
    float var = ss*(1.0f/DMODEL) - m_*m_;
    mu[(size_t)which*NROWS + row]   = m_;
    rstd[(size_t)which*NROWS + row] = rsqrtf(var + 1e-5f);
  }
}

// ---------------------------------------------------------------- K1b: LN-fused projection GEMM
// f[h][q][n][d] = sum_k LN(x[q,n,k]) * W[k][h*64+d]
__global__ void __launch_bounds__(256) proj_gemm_kernel(
    const float* __restrict__ xq, const float* __restrict__ xk, const float* __restrict__ xv,
    const float* __restrict__ g, const float* __restrict__ bb,
    const float* __restrict__ W,
    const float* __restrict__ mu, const float* __restrict__ rstd,
    float* __restrict__ fq, float* __restrict__ fk, float* __restrict__ fv)
{
  int rt = blockIdx.x, ct = blockIdx.y, which = blockIdx.z;
  const float* src = which==0 ? xq : (which==1 ? xk : xv);
  float* dst = which==0 ? fq : (which==1 ? fk : fv);
  __shared__ float At[32][68];   // transposed A tile [k][row]
  __shared__ float Bs[32][68];   // B tile [k][col]
  __shared__ float gs[DMODEL], bs[DMODEL];
  __shared__ float mus[64], rss[64];
  int t = threadIdx.x;
  int r0 = rt*64, c0 = ct*64;
  for (int i=t; i<DMODEL; i+=256){ gs[i]=g[i]; bs[i]=bb[i]; }
  if (t<64){ mus[t]=mu[(size_t)which*NROWS + r0+t]; rss[t]=rstd[(size_t)which*NROWS + r0+t]; }
  int ty = t>>4, tx = t&15;
  float acc[4][4] = {};
  for (int k0=0; k0<DMODEL; k0+=32){
    __syncthreads();
    for (int idx=t; idx<512; idx+=256){
      int kq = idx&7, i = idx>>3;
      float4 x4 = *reinterpret_cast<const float4*>(&src[(size_t)(r0+i)*DMODEL + k0 + 4*kq]);
      float m_ = mus[i], r_ = rss[i];
      int kb = k0 + 4*kq;
      At[4*kq+0][i] = (x4.x-m_)*r_*gs[kb+0] + bs[kb+0];
      At[4*kq+1][i] = (x4.y-m_)*r_*gs[kb+1] + bs[kb+1];
      At[4*kq+2][i] = (x4.z-m_)*r_*gs[kb+2] + bs[kb+2];
      At[4*kq+3][i] = (x4.w-m_)*r_*gs[kb+3] + bs[kb+3];
    }
    for (int idx=t; idx<512; idx+=256){
      int cq = idx&15, kk = idx>>4;
      float4 w4 = *reinterpret_cast<const float4*>(&W[(size_t)(k0+kk)*DMODEL + c0 + 4*cq]);
      *reinterpret_cast<float4*>(&Bs[kk][4*cq]) = w4;
    }
    __syncthreads();
    #pragma unroll 8
    for (int kk=0; kk<32; kk++){
      float4 a4 = *reinterpret_cast<const float4*>(&At[kk][ty*4]);
      float4 b4 = *reinterpret_cast<const float4*>(&Bs[kk][tx*4]);
      float a_[4] = {a4.x,a4.y,a4.z,a4.w};
      float b_[4] = {b4.x,b4.y,b4.z,b4.w};
      #pragma unroll
      for (int i=0;i<4;i++)
        #pragma unroll
        for (int jj=0;jj<4;jj++) acc[i][jj] += a_[i]*b_[jj];
    }
  }
  int qi = r0 >> 9;  // 512 rows per q-batch; 64-row tiles never straddle
  #pragma unroll
  for (int i=0;i<4;i++){
    int rr = r0 + ty*4 + i, n = rr & 511;
    size_t base = (((size_t)ct*QB + qi)*SEQ + n)*DHD + tx*4;
    #pragma unroll
    for (int jj=0;jj<4;jj++) dst[base+jj] = acc[i][jj];
  }
}

// ---------------------------------------------------------------- K2: per-(h,q) row/col stats
__global__ void __launch_bounds__(256) stats_kernel(
    const float* __restrict__ fq, const float* __restrict__ fk,
    float* __restrict__ aqA, float* __restrict__ c1A,
    float* __restrict__ i1qA, float* __restrict__ i2qA,
    float* __restrict__ rskA, float* __restrict__ i1kA, float* __restrict__ i2kA,
    float* __restrict__ c2A, float* __restrict__ qgp, float* __restrict__ kgp)
{
  int hq = blockIdx.x;
  const float* Fq = fq + (size_t)hq*SEQ*DHD;
  const float* Fk = fk + (size_t)hq*SEQ*DHD;
  int t = threadIdx.x, d = t&63, rr = t>>6;
  float bkacc=0.f, qga=0.f, kga=0.f;
  for (int n=rr; n<SEQ; n+=4){
    float vq = Fq[n*DHD+d], vk = Fk[n*DHD+d];
    qga += vq; kga += vk; bkacc += vk;
    float sq=vq, s2q=vq*vq, sk=vk, s2k=vk*vk;
    #pragma unroll
    for (int m=32; m>0; m>>=1){
      sq  += __shfl_xor(sq,m,64);  s2q += __shfl_xor(s2q,m,64);
      sk  += __shfl_xor(sk,m,64);  s2k += __shfl_xor(s2k,m,64);
    }
    if (d==0){
      float nq = sqrtf(s2q), nk = sqrtf(s2k);
      aqA[hq*SEQ+n]  = sq*(1.0f/64.0f);
      i1qA[hq*SEQ+n] = 1.0f/(nq+1e-8f);
      i2qA[hq*SEQ+n] = 1.0f/fmaxf(nq,1e-8f);
      rskA[hq*SEQ+n] = sk;
      i1kA[hq*SEQ+n] = 1.0f/(nk+1e-8f);
      i2kA[hq*SEQ+n] = 1.0f/fmaxf(nk,1e-8f);
    }
  }
  __shared__ float sh[4][64];
  __shared__ float bksh[64];
  sh[rr][d]=bkacc; __syncthreads();
  if (t<64) bksh[t] = (sh[0][t]+sh[1][t]+sh[2][t]+sh[3][t])*(1.0f/512.0f);
  __syncthreads();
  float bkd = bksh[d];
  if (t<64){
    float cc = bksh[t];
    #pragma unroll
    for (int m=32;m>0;m>>=1) cc += __shfl_xor(cc,m,64);
    if (t==0) c2A[hq]=cc;
  }
  __syncthreads();
  sh[rr][d]=qga; __syncthreads();
  if (t<64) qgp[hq*64+t] = sh[0][t]+sh[1][t]+sh[2][t]+sh[3][t];
  __syncthreads();
  sh[rr][d]=kga; __syncthreads();
  if (t<64) kgp[hq*64+t] = sh[0][t]+sh[1][t]+sh[2][t]+sh[3][t];
  for (int n=rr; n<SEQ; n+=4){
    float p = Fq[n*DHD+d]*bkd;
    #pragma unroll
    for (int m=32;m>0;m>>=1) p += __shfl_xor(p,m,64);
    if (d==0) c1A[hq*SEQ+n]=p;
  }
}

// ---------------------------------------------------------------- M1: moment pass over scores
__global__ void __launch_bounds__(256) score_pass1_kernel(
    const float* __restrict__ fq, const float* __restrict__ fk,
    const float* __restrict__ aqA, const float* __restrict__ c1A,
    const float* __restrict__ i1qA, const float* __restrict__ i2qA,
    const float* __restrict__ rskA, const float* __restrict__ i1kA, const float* __restrict__ i2kA,
    const float* __restrict__ c2A,
    float* __restrict__ rs_part, float* __restrict__ mom_part)
{
  int ms = blockIdx.x, q_ = blockIdx.y, h = blockIdx.z;
  int hq = h*QB + q_;
  int m0 = ms*128;
  const float* Fq = fq + (size_t)hq*SEQ*DHD;
  const float* Fk = fk + (size_t)hq*SEQ*DHD;
  __shared__ float BkT[64][132];    // [d][m]
  __shared__ float AqT[64][68];     // [d][n]
  __shared__ float kst[3][128];     // rsk, i1k, i2k
  __shared__ float qst[4][64];      // aq, c1, i1q, i2q
  int t = threadIdx.x, ty = t>>4, tx = t&15;
  for (int idx=t; idx<128*16; idx+=256){
    int dq = idx&15, m = idx>>4;
    float4 v4 = *reinterpret_cast<const float4*>(&Fk[(size_t)(m0+m)*DHD + 4*dq]);
    BkT[4*dq+0][m]=v4.x; BkT[4*dq+1][m]=v4.y; BkT[4*dq+2][m]=v4.z; BkT[4*dq+3][m]=v4.w;
  }
  if (t<128){
    kst[0][t]=rskA[hq*SEQ+m0+t];
    kst[1][t]=i1kA[hq*SEQ+m0+t];
    kst[2][t]=i2kA[hq*SEQ+m0+t];
  }
  float c2v = c2A[hq];
  float sc=0,sc2=0,so=0,so2=0,sco=0;
  for (int sub=0; sub<8; ++sub){
    int n0 = sub*64;
    __syncthreads();
    for (int idx=t; idx<64*16; idx+=256){
      int dq=idx&15, i=idx>>4;
      float4 v4 = *reinterpret_cast<const float4*>(&Fq[(size_t)(n0+i)*DHD + 4*dq]);
      AqT[4*dq+0][i]=v4.x; AqT[4*dq+1][i]=v4.y; AqT[4*dq+2][i]=v4.z; AqT[4*dq+3][i]=v4.w;
    }
    if (t<64){
      qst[0][t]=aqA[hq*SEQ+n0+t]; qst[1][t]=c1A[hq*SEQ+n0+t];
      qst[2][t]=i1qA[hq*SEQ+n0+t]; qst[3][t]=i2qA[hq*SEQ+n0+t];
    }
    __syncthreads();
    float acc[4][8] = {};
    #pragma unroll 4
    for (int d=0; d<64; d++){
      float4 a4  = *reinterpret_cast<const float4*>(&AqT[d][ty*4]);
      float4 b40 = *reinterpret_cast<const float4*>(&BkT[d][tx*8]);
      float4 b41 = *reinterpret_cast<const float4*>(&BkT[d][tx*8+4]);
      float a_[4]={a4.x,a4.y,a4.z,a4.w};
      float b_[8]={b40.x,b40.y,b40.z,b40.w,b41.x,b41.y,b41.z,b41.w};
      #pragma unroll
      for (int i=0;i<4;i++)
        #pragma unroll
        for (int j=0;j<8;j++) acc[i][j] += a_[i]*b_[j];
    }
    float rcs[4], rco[4], rcm[4];
    #pragma unroll
    for (int i=0;i<4;i++){
      int rl = ty*4+i;
      float av=qst[0][rl], c1v=qst[1][rl], iq1=qst[2][rl], iq2=qst[3][rl];
      float rc=0, ro=0, rm=0;
      #pragma unroll
      for (int j=0;j<8;j++){
        int m = tx*8+j;
        float S = acc[i][j];
        float cosv = clampf(S*iq1*kst[1][m], -0.99f, 0.99f);
        float covv = clampf((S - c1v - av*(kst[0][m]-c2v))*KCOV, -10.0f, 10.0f);
        float csv  = clampf(S*iq2*kst[2][m], -0.99f, 0.99f);
        float marg = clampf(0.01f - csv, 0.0f, 2.0f);
        sc += cosv; sc2 += cosv*cosv;
        so += covv; so2 += covv*covv;
        sco += cosv*covv;
        rc += cosv; ro += covv; rm += marg;
      }
      rcs[i]=rc; rco[i]=ro; rcm[i]=rm;
    }
    #pragma unroll
    for (int m=1;m<16;m<<=1){
      #pragma unroll
      for (int i=0;i<4;i++){
        rcs[i]+=__shfl_xor(rcs[i],m,64);
        rco[i]+=__shfl_xor(rco[i],m,64);
        rcm[i]+=__shfl_xor(rcm[i],m,64);
      }
    }
    if (tx==0){
      #pragma unroll
      for (int i=0;i<4;i++){
        size_t base = ((size_t)(hq*4+ms)*SEQ + n0+ty*4+i)*3;
        rs_part[base]=rcs[i]; rs_part[base+1]=rco[i]; rs_part[base+2]=rcm[i];
      }
    }
  }
  __shared__ float buf[256];
  float sums[5] = {sc,sc2,so,so2,sco};
  for (int c=0;c<5;c++){
    __syncthreads();
    buf[t]=sums[c]; __syncthreads();
    for (int o=128;o>0;o>>=1){ if (t<o) buf[t]+=buf[t+o]; __syncthreads(); }
    if (t==0) mom_part[(size_t)(hq*4+ms)*5 + c] = buf[0];
  }
}

// ---------------------------------------------------------------- R: reduce row-partials per (h,q)
__device__ __forceinline__ double blockReduceD(double v, double* buf){
  int t = threadIdx.x;
  buf[t]=v; __syncthreads();
  for (int o=128;o>0;o>>=1){ if (t<o) buf[t]+=buf[t+o]; __syncthreads(); }
  double r = buf[0]; __syncthreads();
  return r;
}

__global__ void __launch_bounds__(256) rowred_kernel(
    const float* __restrict__ rs_part, double* __restrict__ hq_sums)
{
  int hq = blockIdx.x, t = threadIdx.x;
  double a0=0,a1=0,a2=0,a3=0;
  for (int n=t; n<SEQ; n+=256){
    float rc=0, ro=0, rm=0;
    for (int ms=0;ms<4;ms++){
      size_t base = ((size_t)(hq*4+ms)*SEQ + n)*3;
      rc += rs_part[base]; ro += rs_part[base+1]; rm += rs_part[base+2];
    }
    float mm = rm*(1.0f/512.0f);
    a0 += mm; a1 += (double)mm*mm; a2 += (double)mm*rc; a3 += (double)mm*ro;
  }
  __shared__ double dbuf[256];
  a0 = blockReduceD(a0,dbuf);
  a1 = blockReduceD(a1,dbuf);
  a2 = blockReduceD(a2,dbuf);
  a3 = blockReduceD(a3,dbuf);
  if (t==0){
    hq_sums[hq*4+0]=a0; hq_sums[hq*4+1]=a1; hq_sums[hq*4+2]=a2; hq_sums[hq*4+3]=a3;
  }
}

// ---------------------------------------------------------------- F: MLP + stds + mix params
__global__ void __launch_bounds__(256) finalize_kernel(
    const float* __restrict__ qgp, const float* __restrict__ kgp,
    const float* __restrict__ wp1w, const float* __restrict__ wp1b,
    const float* __restrict__ wplg, const float* __restrict__ wplb,
    const float* __restrict__ wp2w, const float* __restrict__ wp2b,
    const float* __restrict__ wp3w, const float* __restrict__ wp3b,
    const float* __restrict__ temp,
    const float* __restrict__ mom_part, const double* __restrict__ hq_sums,
    float* __restrict__ params)
{
  int t = threadIdx.x;
  __shared__ float feats[8][128];
  __shared__ float h1s[8][64];
  __shared__ float h2s[8][32];
  __shared__ float wts[8][3];
  __shared__ double Sh[8][9];  // S1c,S2c,S1o,S2o,Scc, Smm,Smm2,Scv,Sov
  for (int idx=t; idx<512; idx+=256){
    int h = idx>>6, d = idx&63;
    float s1=0, s2=0;
    for (int qq=0; qq<QB; qq++){ s1 += qgp[(h*QB+qq)*64+d]; s2 += kgp[(h*QB+qq)*64+d]; }
    feats[h][d]    = s1*(1.0f/8192.0f);
    feats[h][64+d] = s2*(1.0f/8192.0f);
  }
  __syncthreads();
  int w = t>>6, j = t&63;
  for (int pp=0; pp<2; pp++){
    int h = w + pp*4;
    float acc = wp1b[j];
    for (int k=0;k<128;k++) acc += feats[h][k]*wp1w[k*64+j];
    float s=acc, s2=acc*acc;
    #pragma unroll
    for (int m=32;m>0;m>>=1){ s+=__shfl_xor(s,m,64); s2+=__shfl_xor(s2,m,64); }
    float mean = s*(1.0f/64.0f);
    float var  = s2*(1.0f/64.0f) - mean*mean;
    float xh = (acc-mean)*rsqrtf(var+1e-5f)*wplg[j] + wplb[j];
    h1s[h][j] = fmaxf(xh, 0.0f);
  }
  __syncthreads();
  {
    int h = t>>5, j2 = t&31;
    float acc = wp2b[j2];
    for (int k=0;k<64;k++) acc += h1s[h][k]*wp2w[k*32+j2];
    h2s[h][j2] = fmaxf(acc, 0.0f);
  }
  __syncthreads();
  if (t<8){
    int h = t;
    float z[3] = {wp3b[0], wp3b[1], wp3b[2]};
    for (int k=0;k<32;k++){
      float hv = h2s[h][k];
      z[0]+=hv*wp3w[k*3]; z[1]+=hv*wp3w[k*3+1]; z[2]+=hv*wp3w[k*3+2];
    }
    float mx = fmaxf(z[0], fmaxf(z[1], z[2]));
    float e0=expf(z[0]-mx), e1=expf(z[1]-mx), e2=expf(z[2]-mx);
    float inv = 1.0f/(e0+e1+e2);
    float l0=e0*inv, l1=e1*inv, l2=e2*inv;
    float tv = temp[0]; tv = fminf(fmaxf(tv, 0.1f), 20.0f);
    float y0=l0/tv, y1=l1/tv, y2=l2/tv;
    float mx2 = fmaxf(y0, fmaxf(y1, y2));
    float f0=expf(y0-mx2), f1=expf(y1-mx2), f2=expf(y2-mx2);
    float inv2 = 1.0f/(f0+f1+f2);
    wts[h][0]=f0*inv2; wts[h][1]=f1*inv2; wts[h][2]=f2*inv2;
  }
  __syncthreads();
  if (t<40){
    int h = t/5, c = t%5;
    double s = 0;
    for (int b2=0; b2<64; b2++) s += (double)mom_part[(size_t)(h*64+b2)*5 + c];
    Sh[h][c] = s;
  }
  __syncthreads();
  if (t<32){
    int h = t>>2, c = t&3;
    double s = 0;
    for (int qq=0; qq<QB; qq++) s += hq_sums[(h*QB+qq)*4 + c];
    Sh[h][5+c] = s;
  }
  __syncthreads();
  if (t==0){
    const double Ntot = 33554432.0;
    double T1c=0,T2c=0,T1o=0,T2o=0,T1v=0,T2v=0;
    for (int h=0;h<8;h++){
      T1c+=Sh[h][0]; T2c+=Sh[h][1]; T1o+=Sh[h][2]; T2o+=Sh[h][3];
      T1v+=512.0*Sh[h][5]; T2v+=512.0*Sh[h][6];
    }
    double stdc = sqrt(fmax((T2c - T1c*T1c/Ntot)/(Ntot-1.0), 0.0));
    double stdo = sqrt(fmax((T2o - T1o*T1o/Ntot)/(Ntot-1.0), 0.0));
    double stdv = sqrt(fmax((T2v - T1v*T1v/Ntot)/(Ntot-1.0), 0.0));
    double ah[8], bh[8];
    double Sd1=0, Sd2=0;
    for (int h=0;h<8;h++){
      double a = (double)wts[h][0]/(stdc+1e-8);
      double b = (double)wts[h][1]*0.1/(stdo+1e-8);
      double c = (double)wts[h][2]*0.1/(stdv+1e-8);
      ah[h]=a; bh[h]=b;
      Sd1 += a*Sh[h][0] + b*Sh[h][2] + c*512.0*Sh[h][5];
      Sd2 += a*a*Sh[h][1] + b*b*Sh[h][3] + c*c*512.0*Sh[h][6]
           + 2.0*a*b*Sh[h][4] + 2.0*a*c*Sh[h][7] + 2.0*b*c*Sh[h][8];
    }
    double stdd = sqrt(fmax((Sd2 - Sd1*Sd1/Ntot)/(Ntot-1.0), 0.0));
    double att = 1.0 + 0.5*stdd;
    att = fmin(fmax(att, 0.5), 5.0);
    double scale = 1.0/att;
    for (int h=0;h<8;h++){
      params[h*2+0] = (float)(scale*ah[h]);
      params[h*2+1] = (float)(scale*bh[h]);
    }
  }
}

// ---------------------------------------------------------------- M2: logits + flash softmax + PV
__global__ void __launch_bounds__(256) attn_pass2_kernel(
    const float* __restrict__ fq, const float* __restrict__ fk, const float* __restrict__ fv,
    const float* __restrict__ aqA, const float* __restrict__ c1A, const float* __restrict__ i1qA,
    const float* __restrict__ rskA, const float* __restrict__ i1kA,
    const float* __restrict__ c2A, const float* __restrict__ params,
    float* __restrict__ attn_out)
{
  int nb = blockIdx.x, q_ = blockIdx.y, h = blockIdx.z;
  int hq = h*QB + q_, n0 = nb*32;
  const float* Fq = fq + (size_t)hq*SEQ*DHD;
  const float* Fk = fk + (size_t)hq*SEQ*DHD;
  const float* Fv = fv + (size_t)hq*SEQ*DHD;
  __shared__ float P[32][129];
  __shared__ float KVu[8704];        // union: FkT[64][132] (8448) / Fv [128][68] (8704)
  __shared__ float AqT[64][36];
  __shared__ float qst[3][32];
  __shared__ float kst[2][128];
  __shared__ float Mrow[32], Drow[32], Frow[32];
  int t = threadIdx.x, ty = t>>4, tx = t&15;
  float pa = params[h*2], pb = params[h*2+1];
  float c2v = c2A[hq];
  for (int idx=t; idx<32*16; idx+=256){
    int dq = idx&15, i = idx>>4;
    float4 v4 = *reinterpret_cast<const float4*>(&Fq[(size_t)(n0+i)*DHD + 4*dq]);
    AqT[4*dq+0][i]=v4.x; AqT[4*dq+1][i]=v4.y; AqT[4*dq+2][i]=v4.z; AqT[4*dq+3][i]=v4.w;
  }
  if (t<32){
    qst[0][t]=aqA[hq*SEQ+n0+t]; qst[1][t]=c1A[hq*SEQ+n0+t]; qst[2][t]=i1qA[hq*SEQ+n0+t];
    Mrow[t] = -3.0e38f; Drow[t] = 0.0f;
  }
  float accO[2][4] = {};
  for (int mc=0; mc<4; ++mc){
    int m0 = mc*128;
    __syncthreads();
    for (int idx=t; idx<128*16; idx+=256){
      int dq = idx&15, m = idx>>4;
      float4 v4 = *reinterpret_cast<const float4*>(&Fk[(size_t)(m0+m)*DHD + 4*dq]);
      KVu[(4*dq+0)*132+m]=v4.x; KVu[(4*dq+1)*132+m]=v4.y;
      KVu[(4*dq+2)*132+m]=v4.z; KVu[(4*dq+3)*132+m]=v4.w;
    }
    if (t<128){ kst[0][t]=rskA[hq*SEQ+m0+t]; kst[1][t]=i1kA[hq*SEQ+m0+t]; }
    __syncthreads();
    float acc[2][8] = {};
    #pragma unroll 4
    for (int d=0; d<64; d++){
      float a0 = AqT[d][2*ty], a1 = AqT[d][2*ty+1];
      float4 b40 = *reinterpret_cast<const float4*>(&KVu[d*132 + tx*8]);
      float4 b41 = *reinterpret_cast<const float4*>(&KVu[d*132 + tx*8 + 4]);
      float b_[8]={b40.x,b40.y,b40.z,b40.w,b41.x,b41.y,b41.z,b41.w};
      #pragma unroll
      for (int jj=0;jj<8;jj++){ acc[0][jj]+=a0*b_[jj]; acc[1][jj]+=a1*b_[jj]; }
    }
    #pragma unroll
    for (int i=0;i<2;i++){
      int rl = 2*ty+i;
      float av=qst[0][rl], c1v=qst[1][rl], iq1=qst[2][rl];
      #pragma unroll
      for (int jj=0;jj<8;jj++){
        int m = tx*8+jj;
        float S = acc[i][jj];
        float cosv = clampf(S*iq1*kst[1][m], -0.99f, 0.99f);
        float covv = clampf((S - c1v - av*(kst[0][m]-c2v))*KCOV, -10.0f, 10.0f);
        P[rl][m] = pa*cosv + pb*covv;
      }
    }
    __syncthreads();
    int r = t>>3, l8 = t&7;
    float mx = -3.0e38f;
    for (int c=l8*16; c<l8*16+16; c++) mx = fmaxf(mx, P[r][c]);
    #pragma unroll
    for (int m=1;m<8;m<<=1) mx = fmaxf(mx, __shfl_xor(mx,m,64));
    if (l8==0){
      float Mo = Mrow[r], Mn = fmaxf(Mo, mx);
      Frow[r] = __expf(Mo - Mn);
      Mrow[r] = Mn;
    }
    __syncthreads();
    float Mn = Mrow[r];
    float ps = 0.0f;
    for (int c=l8*16; c<l8*16+16; c++){
      float e = __expf(P[r][c]-Mn);
      P[r][c] = e; ps += e;
    }
    #pragma unroll
    for (int m=1;m<8;m<<=1) ps += __shfl_xor(ps,m,64);
    if (l8==0) Drow[r] = Drow[r]*Frow[r] + ps;
    __syncthreads();
    for (int idx=t; idx<128*16; idx+=256){
      int dq = idx&15, m = idx>>4;
      float4 v4 = *reinterpret_cast<const float4*>(&Fv[(size_t)(m0+m)*DHD + 4*dq]);
      *reinterpret_cast<float4*>(&KVu[m*68 + 4*dq]) = v4;
    }
    __syncthreads();
    float f0 = Frow[2*ty], f1 = Frow[2*ty+1];
    #pragma unroll
    for (int jj=0;jj<4;jj++){ accO[0][jj]*=f0; accO[1][jj]*=f1; }
    #pragma unroll 2
    for (int m=0;m<128;m++){
      float p0 = P[2*ty][m], p1 = P[2*ty+1][m];
      float4 v4 = *reinterpret_cast<const float4*>(&KVu[m*68 + tx*4]);
      float v_[4]={v4.x,v4.y,v4.z,v4.w};
      #pragma unroll
      for (int jj=0;jj<4;jj++){ accO[0][jj]+=p0*v_[jj]; accO[1][jj]+=p1*v_[jj]; }
    }
  }
  __syncthreads();
  #pragma unroll
  for (int i=0;i<2;i++){
    int rl = 2*ty+i, n = n0+rl;
    float inv = 1.0f/Drow[rl];
    size_t base = ((size_t)(q_*SEQ+n))*DMODEL + h*DHD + tx*4;
    #pragma unroll
    for (int jj=0;jj<4;jj++) attn_out[base+jj] = accO[i][jj]*inv;
  }
}

// ---------------------------------------------------------------- KO: output projection
__global__ void __launch_bounds__(256) out_gemm_kernel(
    const float* __restrict__ A, const float* __restrict__ W,
    const float* __restrict__ bias, float* __restrict__ out)
{
  int rt = blockIdx.x, ct = blockIdx.y;
  __shared__ float At[32][68];
  __shared__ float Bs[32][68];
  int t = threadIdx.x, ty = t>>4, tx = t&15;
  int r0 = rt*64, c0 = ct*64;
  float acc[4][4] = {};
  for (int k0=0; k0<DMODEL; k0+=32){
    __syncthreads();
    for (int idx=t; idx<512; idx+=256){
      int kq = idx&7, i = idx>>3;
      float4 x4 = *reinterpret_cast<const float4*>(&A[(size_t)(r0+i)*DMODEL + k0 + 4*kq]);
      At[4*kq+0][i]=x4.x; At[4*kq+1][i]=x4.y; At[4*kq+2][i]=x4.z; At[4*kq+3][i]=x4.w;
    }
    for (int idx=t; idx<512; idx+=256){
      int cq = idx&15, kk = idx>>4;
      float4 w4 = *reinterpret_cast<const float4*>(&W[(size_t)(k0+kk)*DMODEL + c0 + 4*cq]);
      *reinterpret_cast<float4*>(&Bs[kk][4*cq]) = w4;
    }
    __syncthreads();
    #pragma unroll 8
    for (int kk=0; kk<32; kk++){
      float4 a4 = *reinterpret_cast<const float4*>(&At[kk][ty*4]);
      float4 b4 = *reinterpret_cast<const float4*>(&Bs[kk][tx*4]);
      float a_[4]={a4.x,a4.y,a4.z,a4.w}, b_[4]={b4.x,b4.y,b4.z,b4.w};
      #pragma unroll
      for (int i=0;i<4;i++)
        #pragma unroll
        for (int jj=0;jj<4;jj++) acc[i][jj]+=a_[i]*b_[jj];
    }
  }
  #pragma unroll
  for (int i=0;i<4;i++){
    int rr = r0+ty*4+i;
    #pragma unroll
    for (int jj=0;jj<4;jj++)
      out[(size_t)rr*DMODEL + c0 + tx*4 + jj] = acc[i][jj] + bias[c0+tx*4+jj];
  }
}

// ----------------------------------------------------------------
extern "C" void kernel_launch(void* const* d_in, const int* in_sizes, int n_in,
                              void* d_out, int out_size, void* d_ws, size_t ws_size,
                              hipStream_t stream)
{
  (void)in_sizes; (void)n_in; (void)out_size; (void)ws_size;
  const float* q     = (const float*)d_in[0];
  const float* k     = (const float*)d_in[1];
  const float* v     = (const float*)d_in[2];
  const float* ln_g  = (const float*)d_in[3];
  const float* ln_b  = (const float*)d_in[4];
  const float* W_in  = (const float*)d_in[5];
  const float* wp1w  = (const float*)d_in[6];
  const float* wp1b  = (const float*)d_in[7];
  const float* wplg  = (const float*)d_in[8];
  const float* wplb  = (const float*)d_in[9];
  const float* wp2w  = (const float*)d_in[10];
  const float* wp2b  = (const float*)d_in[11];
  const float* wp3w  = (const float*)d_in[12];
  const float* wp3b  = (const float*)d_in[13];
  const float* temp  = (const float*)d_in[14];
  const float* W_out = (const float*)d_in[15];
  const float* b_out = (const float*)d_in[16];
  float* out = (float*)d_out;

  float* ws = (float*)d_ws;
  size_t off = 0;
  float* fq   = ws+off; off += (size_t)NHQ*SEQ*DHD;      // 4194304
  float* fk   = ws+off; off += (size_t)NHQ*SEQ*DHD;
  float* fv   = ws+off; off += (size_t)NHQ*SEQ*DHD;
  float* attn = ws+off; off += (size_t)QB*SEQ*DMODEL;    // 4194304
  float* mu   = ws+off; off += 3*NROWS;
  float* rstd = ws+off; off += 3*NROWS;
  float* aqA  = ws+off; off += NHQ*SEQ;
  float* c1A  = ws+off; off += NHQ*SEQ;
  float* i1qA = ws+off; off += NHQ*SEQ;
  float* i2qA = ws+off; off += NHQ*SEQ;
  float* rskA = ws+off; off += NHQ*SEQ;
  float* i1kA = ws+off; off += NHQ*SEQ;
  float* i2kA = ws+off; off += NHQ*SEQ;
  float* c2A  = ws+off; off += NHQ;
  float* qgp  = ws+off; off += NHQ*64;
  float* kgp  = ws+off; off += NHQ*64;
  float* rs_part  = ws+off; off += (size_t)NHQ*4*SEQ*3;  // 786432
  float* mom_part = ws+off; off += 512*5;
  float* params   = ws+off; off += 16;
  if (off & 1) off++;                     // 8B-align for doubles
  double* hq_sums = (double*)(ws+off); off += 2*NHQ*4;

  ln_stats_kernel<<<dim3(NROWS/4, 3), 256, 0, stream>>>(q, k, v, mu, rstd);
  proj_gemm_kernel<<<dim3(128, 8, 3), 256, 0, stream>>>(q, k, v, ln_g, ln_b, W_in, mu, rstd, fq, fk, fv);
  stats_kernel<<<dim3(NHQ), 256, 0, stream>>>(fq, fk, aqA, c1A, i1qA, i2qA, rskA, i1kA, i2kA, c2A, qgp, kgp);
  score_pass1_kernel<<<dim3(4, QB, NH), 256, 0, stream>>>(fq, fk, aqA, c1A, i1qA, i2qA, rskA, i1kA, i2kA, c2A, rs_part, mom_part);
  rowred_kernel<<<dim3(NHQ), 256, 0, stream>>>(rs_part, hq_sums);
  finalize_kernel<<<1, 256, 0, stream>>>(qgp, kgp, wp1w, wp1b, wplg, wplb, wp2w, wp2b, wp3w, wp3b,
                                         temp, mom_part, hq_sums, params);
  attn_pass2_kernel<<<dim3(16, QB, NH), 256, 0, stream>>>(fq, fk, fv, aqA, c1A, i1qA, rskA, i1kA, c2A, params, attn);
  out_gemm_kernel<<<dim3(128, 8), 256, 0, stream>>>(attn, W_out, b_out, out);
}

// Round 2
// 303.674 us; speedup vs baseline: 2.5321x; 2.5321x over previous
//
#include <hip/hip_runtime.h>
#include <math.h>

#define NH 8
#define DHD 64
#define DMODEL 512
#define QB 16
#define SEQ 512
#define NROWS (QB*SEQ)      /* 8192 rows per input */
#define NHQ (NH*QB)         /* 128 (h,q) pairs */
#define KCOV ((float)((0.001/512.0)/(8.0+1e-8)))

typedef __attribute__((ext_vector_type(8))) short short8;      // 8 bf16 -> 4 VGPR
typedef __attribute__((ext_vector_type(8))) unsigned short ushort8v;
typedef __attribute__((ext_vector_type(4))) unsigned short ushort4v;
typedef __attribute__((ext_vector_type(4))) float f32x4;

__device__ __forceinline__ float bf2f(unsigned short u){
  union { unsigned int i; float f; } c; c.i = ((unsigned int)u)<<16; return c.f;
}
__device__ __forceinline__ unsigned short f2bf(float f){
  union { float f; unsigned int i; } c; c.f = f;
  unsigned int u = c.i;
  u += 0x7fffu + ((u>>16)&1u);   // RNE
  return (unsigned short)(u>>16);
}
__device__ __forceinline__ float clampf(float x, float lo, float hi){ return fminf(fmaxf(x,lo),hi); }

__device__ __forceinline__ f32x4 MFMA(short8 a, short8 b, f32x4 c){
  return __builtin_amdgcn_mfma_f32_16x16x32_bf16(a, b, c, 0, 0, 0);
}
// swizzled-tile access: element (row, kbyte), rowbytes pitch, XOR-swizzle bits 4-6 by row&7
__device__ __forceinline__ short8 frag_ld(const unsigned short* T, int row, int rowbytes, int kbyte){
  int addr = row*rowbytes + (kbyte ^ ((row&7)<<4));
  return *reinterpret_cast<const short8*>(reinterpret_cast<const char*>(T) + addr);
}
__device__ __forceinline__ void tile_st16(unsigned short* T, int row, int rowbytes, int kbyte, ushort8v v){
  int addr = row*rowbytes + (kbyte ^ ((row&7)<<4));
  *reinterpret_cast<ushort8v*>(reinterpret_cast<char*>(T) + addr) = v;
}
__device__ __forceinline__ void tile_st8(unsigned short* T, int row, int rowbytes, int kbyte, ushort4v v){
  int addr = row*rowbytes + (kbyte ^ ((row&7)<<4));
  *reinterpret_cast<ushort4v*>(reinterpret_cast<char*>(T) + addr) = v;
}

// ---------------------------------------------------------------- K1a: LN row stats
__global__ void __launch_bounds__(256) ln_stats_kernel(
    const float* __restrict__ xq, const float* __restrict__ xk, const float* __restrict__ xv,
    float* __restrict__ mu, float* __restrict__ rstd)
{
  int which = blockIdx.y;
  const float* src = which==0 ? xq : (which==1 ? xk : xv);
  int w = threadIdx.x >> 6, lane = threadIdx.x & 63;
  int row = blockIdx.x*4 + w;
  const float* x = src + (size_t)row*DMODEL;
  float4 v1 = *reinterpret_cast<const float4*>(&x[lane*8]);
  float4 v2 = *reinterpret_cast<const float4*>(&x[lane*8+4]);
  float s  = v1.x+v1.y+v1.z+v1.w + v2.x+v2.y+v2.z+v2.w;
  float ss = v1.x*v1.x+v1.y*v1.y+v1.z*v1.z+v1.w*v1.w
           + v2.x*v2.x+v2.y*v2.y+v2.z*v2.z+v2.w*v2.w;
  #pragma unroll
  for (int m=32; m>0; m>>=1){ s += __shfl_xor(s,m,64); ss += __shfl_xor(ss,m,64); }
  if (lane==0){
    float m_ = s*(1.0f/DMODEL);
    float var = ss*(1.0f/DMODEL) - m_*m_;
    mu[(size_t)which*NROWS + row]   = m_;
    rstd[(size_t)which*NROWS + row] = rsqrtf(var + 1e-5f);
  }
}

// ---------------------------------------------------------------- K1w: transpose+cast weights
__global__ void __launch_bounds__(256) convert_w_kernel(
    const float* __restrict__ Wi, const float* __restrict__ Wo,
    unsigned short* __restrict__ WiT, unsigned short* __restrict__ WoT)
{
  const float* src = blockIdx.z ? Wo : Wi;
  unsigned short* dst = blockIdx.z ? WoT : WiT;
  int r0 = blockIdx.x*64, c0 = blockIdx.y*64;
  __shared__ float T[64][68];
  int t = threadIdx.x;
  for (int it=0; it<4; ++it){
    int idx = it*256+t, row = idx>>4, q = idx&15;
    float4 v = *reinterpret_cast<const float4*>(&src[(size_t)(r0+row)*DMODEL + c0 + q*4]);
    T[row][q*4+0]=v.x; T[row][q*4+1]=v.y; T[row][q*4+2]=v.z; T[row][q*4+3]=v.w;
  }
  __syncthreads();
  for (int it=0; it<4; ++it){
    int idx = it*256+t, oc = idx>>4, q = idx&15;
    ushort4v o;
    o[0]=f2bf(T[q*4+0][oc]); o[1]=f2bf(T[q*4+1][oc]);
    o[2]=f2bf(T[q*4+2][oc]); o[3]=f2bf(T[q*4+3][oc]);
    *reinterpret_cast<ushort4v*>(&dst[(size_t)(c0+oc)*DMODEL + r0 + q*4]) = o;
  }
}

// ---------------------------------------------------------------- K1b: LN-fused projection (MFMA)
// which<2: writes f[hq][n][d] bf16 (row-major).  which==2: writes fvT[hq][d][n] bf16.
__global__ void __launch_bounds__(256) proj_mfma_kernel(
    const float* __restrict__ xq, const float* __restrict__ xk, const float* __restrict__ xv,
    const float* __restrict__ g, const float* __restrict__ bb,
    const unsigned short* __restrict__ WiT,
    const float* __restrict__ mu, const float* __restrict__ rstd,
    unsigned short* __restrict__ fq, unsigned short* __restrict__ fk, unsigned short* __restrict__ fvT)
{
  int which = blockIdx.z;
  const float* src = which==0?xq:(which==1?xk:xv);
  int r0 = blockIdx.x*128;   // x rows (n-dim)
  int c0 = blockIdx.y*128;   // output cols (head*64+d dim)
  __shared__ unsigned short XT[128*64];  // LN(x) tile, rows n-local, pitch 128B
  __shared__ unsigned short WT[128*64];  // WiT tile, rows c-local, pitch 128B
  __shared__ float gs[DMODEL], bs[DMODEL], mus[128], rss[128];
  int t = threadIdx.x;
  for (int i=t;i<DMODEL;i+=256){ gs[i]=g[i]; bs[i]=bb[i]; }
  if (t<128){ mus[t]=mu[(size_t)which*NROWS+r0+t]; rss[t]=rstd[(size_t)which*NROWS+r0+t]; }
  int w=t>>6, lane=t&63, l16=lane&15, lh=lane>>4;
  f32x4 acc[4][4];
  #pragma unroll
  for(int i=0;i<4;i++){ for(int j=0;j<4;j++) acc[i][j]=(f32x4){0.f,0.f,0.f,0.f}; }
  for (int k0=0;k0<DMODEL;k0+=64){
    __syncthreads();
    for (int it=0; it<8; ++it){
      int idx=it*256+t, row=idx>>4, q=idx&15;
      float4 x4 = *reinterpret_cast<const float4*>(&src[(size_t)(r0+row)*DMODEL + k0 + q*4]);
      float m_=mus[row], rs_=rss[row];
      const float* g4=&gs[k0+q*4]; const float* b4=&bs[k0+q*4];
      ushort4v o;
      o[0]=f2bf((x4.x-m_)*rs_*g4[0]+b4[0]);
      o[1]=f2bf((x4.y-m_)*rs_*g4[1]+b4[1]);
      o[2]=f2bf((x4.z-m_)*rs_*g4[2]+b4[2]);
      o[3]=f2bf((x4.w-m_)*rs_*g4[3]+b4[3]);
      tile_st8(XT, row, 128, q*8, o);
    }
    for (int it=0; it<4; ++it){
      int idx=it*256+t, row=idx>>3, q=idx&7;
      ushort8v v = *reinterpret_cast<const ushort8v*>(&WiT[(size_t)(c0+row)*DMODEL + k0 + q*8]);
      tile_st16(WT, row, 128, q*16, v);
    }
    __syncthreads();
    if (which<2){
      int dr=(w&1)*64, nc=(w>>1)*64;   // D rows = c-local, D cols = n-local
      #pragma unroll
      for (int ks=0; ks<2; ++ks){
        int kb = lh*16 + ks*64;
        short8 a[4], b[4];
        #pragma unroll
        for (int i=0;i<4;i++) a[i] = frag_ld(WT, dr+i*16+l16, 128, kb);
        #pragma unroll
        for (int j=0;j<4;j++) b[j] = frag_ld(XT, nc+j*16+l16, 128, kb);
        #pragma unroll
        for (int i=0;i<4;i++){
          #pragma unroll
          for (int j=0;j<4;j++) acc[i][j]=MFMA(a[i],b[j],acc[i][j]);
        }
      }
    } else {
      int nr=(w>>1)*64, dc=(w&1)*64;   // D rows = n-local, D cols = d-local
      #pragma unroll
      for (int ks=0; ks<2; ++ks){
        int kb = lh*16 + ks*64;
        short8 a[4], b[4];
        #pragma unroll
        for (int i=0;i<4;i++) a[i] = frag_ld(XT, nr+i*16+l16, 128, kb);
        #pragma unroll
        for (int j=0;j<4;j++) b[j] = frag_ld(WT, dc+j*16+l16, 128, kb);
        #pragma unroll
        for (int i=0;i<4;i++){
          #pragma unroll
          for (int j=0;j<4;j++) acc[i][j]=MFMA(a[i],b[j],acc[i][j]);
        }
      }
    }
  }
  if (which<2){
    unsigned short* dst = which ? fk : fq;
    int dr=(w&1)*64, nc=(w>>1)*64;
    #pragma unroll
    for (int i=0;i<4;i++){
      #pragma unroll
      for (int j=0;j<4;j++){
        int cl = c0 + dr + i*16 + lh*4;   // 4 consecutive output cols
        int ng = r0 + nc + j*16 + l16;    // row
        int head = cl>>6, dd = cl&63;
        int hq = head*QB + (ng>>9);
        int n = ng&511;
        ushort4v o;
        o[0]=f2bf(acc[i][j][0]); o[1]=f2bf(acc[i][j][1]);
        o[2]=f2bf(acc[i][j][2]); o[3]=f2bf(acc[i][j][3]);
        *reinterpret_cast<ushort4v*>(&dst[((size_t)hq*SEQ+n)*DHD + dd]) = o;
      }
    }
  } else {
    int nr=(w>>1)*64, dc=(w&1)*64;
    #pragma unroll
    for (int i=0;i<4;i++){
      #pragma unroll
      for (int j=0;j<4;j++){
        int ngb = r0 + nr + i*16 + lh*4;  // 4 consecutive n
        int dg  = c0 + dc + j*16 + l16;   // col
        int head = dg>>6, dd = dg&63;
        int hq = head*QB + (ngb>>9);
        int n = ngb&511;
        ushort4v o;
        o[0]=f2bf(acc[i][j][0]); o[1]=f2bf(acc[i][j][1]);
        o[2]=f2bf(acc[i][j][2]); o[3]=f2bf(acc[i][j][3]);
        *reinterpret_cast<ushort4v*>(&fvT[((size_t)hq*DHD+dd)*SEQ + n]) = o;
      }
    }
  }
}

// ---------------------------------------------------------------- K2: per-(h,q) row/col stats
__global__ void __launch_bounds__(256) stats_kernel(
    const unsigned short* __restrict__ fq, const unsigned short* __restrict__ fk,
    float* __restrict__ aqA, float* __restrict__ c1A,
    float* __restrict__ i1qA, float* __restrict__ i2qA,
    float* __restrict__ rskA, float* __restrict__ i1kA, float* __restrict__ i2kA,
    float* __restrict__ c2A, float* __restrict__ qgp, float* __restrict__ kgp)
{
  int hq = blockIdx.x;
  const unsigned short* Fq = fq + (size_t)hq*SEQ*DHD;
  const unsigned short* Fk = fk + (size_t)hq*SEQ*DHD;
  int t = threadIdx.x, d = t&63, rr = t>>6;
  float bkacc=0.f, qga=0.f, kga=0.f;
  for (int n=rr; n<SEQ; n+=4){
    float vq = bf2f(Fq[n*DHD+d]), vk = bf2f(Fk[n*DHD+d]);
    qga += vq; kga += vk; bkacc += vk;
    float sq=vq, s2q=vq*vq, sk=vk, s2k=vk*vk;
    #pragma unroll
    for (int m=32; m>0; m>>=1){
      sq  += __shfl_xor(sq,m,64);  s2q += __shfl_xor(s2q,m,64);
      sk  += __shfl_xor(sk,m,64);  s2k += __shfl_xor(s2k,m,64);
    }
    if (d==0){
      float nq = sqrtf(s2q), nk = sqrtf(s2k);
      aqA[hq*SEQ+n]  = sq*(1.0f/64.0f);
      i1qA[hq*SEQ+n] = 1.0f/(nq+1e-8f);
      i2qA[hq*SEQ+n] = 1.0f/fmaxf(nq,1e-8f);
      rskA[hq*SEQ+n] = sk;
      i1kA[hq*SEQ+n] = 1.0f/(nk+1e-8f);
      i2kA[hq*SEQ+n] = 1.0f/fmaxf(nk,1e-8f);
    }
  }
  __shared__ float sh[4][64];
  __shared__ float bksh[64];
  sh[rr][d]=bkacc; __syncthreads();
  if (t<64) bksh[t] = (sh[0][t]+sh[1][t]+sh[2][t]+sh[3][t])*(1.0f/512.0f);
  __syncthreads();
  float bkd = bksh[d];
  if (t<64){
    float cc = bksh[t];
    #pragma unroll
    for (int m=32;m>0;m>>=1) cc += __shfl_xor(cc,m,64);
    if (t==0) c2A[hq]=cc;
  }
  __syncthreads();
  sh[rr][d]=qga; __syncthreads();
  if (t<64) qgp[hq*64+t] = sh[0][t]+sh[1][t]+sh[2][t]+sh[3][t];
  __syncthreads();
  sh[rr][d]=kga; __syncthreads();
  if (t<64) kgp[hq*64+t] = sh[0][t]+sh[1][t]+sh[2][t]+sh[3][t];
  for (int n=rr; n<SEQ; n+=4){
    float p = bf2f(Fq[n*DHD+d])*bkd;
    #pragma unroll
    for (int m=32;m>0;m>>=1) p += __shfl_xor(p,m,64);
    if (d==0) c1A[hq*SEQ+n]=p;
  }
}

// ---------------------------------------------------------------- M1: moment pass (MFMA)
__global__ void __launch_bounds__(256) score_m1_kernel(
    const unsigned short* __restrict__ fq, const unsigned short* __restrict__ fk,
    const float* __restrict__ aqA, const float* __restrict__ c1A,
    const float* __restrict__ i1qA, const float* __restrict__ i2qA,
    const float* __restrict__ rskA, const float* __restrict__ i1kA, const float* __restrict__ i2kA,
    const float* __restrict__ c2A,
    float* __restrict__ rs_part, float* __restrict__ mom_part)
{
  int strip = blockIdx.x, q_=blockIdx.y, h=blockIdx.z;
  int hq = h*QB+q_;
  int n0 = strip*128;
  const unsigned short* Fq = fq + (size_t)hq*SEQ*DHD;
  const unsigned short* Fk = fk + (size_t)hq*SEQ*DHD;
  __shared__ unsigned short KT[128*64];
  __shared__ float kdL[128], i1kL[128], i2kL[128];
  __shared__ float aqL[128], c1L[128], i1qL[128], i2qL[128];
  __shared__ float red[256];
  int t=threadIdx.x, w=t>>6, lane=t&63, l16=lane&15, lh=lane>>4;
  float c2v = c2A[hq];
  if (t<128){
    aqL[t]=aqA[hq*SEQ+n0+t]; c1L[t]=c1A[hq*SEQ+n0+t];
    i1qL[t]=i1qA[hq*SEQ+n0+t]; i2qL[t]=i2qA[hq*SEQ+n0+t];
  }
  short8 qa[2][2];
  #pragma unroll
  for (int rf=0;rf<2;rf++){
    int ng = n0 + w*32 + rf*16 + l16;
    #pragma unroll
    for (int ks=0;ks<2;ks++)
      qa[rf][ks] = *reinterpret_cast<const short8*>(&Fq[(size_t)ng*DHD + ks*32 + lh*8]);
  }
  float sc=0,sc2=0,so=0,so2=0,sco=0;
  float rcs[8]={0,0,0,0,0,0,0,0}, rco[8]={0,0,0,0,0,0,0,0}, rcm[8]={0,0,0,0,0,0,0,0};
  for (int mc=0;mc<4;mc++){
    int m0=mc*128;
    __syncthreads();
    for (int it=0;it<4;++it){
      int idx=it*256+t,row=idx>>3,qc=idx&7;
      ushort8v vv = *reinterpret_cast<const ushort8v*>(&Fk[(size_t)(m0+row)*DHD + qc*8]);
      tile_st16(KT,row,128,qc*16,vv);
    }
    if (t<128){
      kdL[t]=rskA[hq*SEQ+m0+t]-c2v;
      i1kL[t]=i1kA[hq*SEQ+m0+t];
      i2kL[t]=i2kA[hq*SEQ+m0+t];
    }
    __syncthreads();
    f32x4 acc[2][8];
    #pragma unroll
    for (int rf=0;rf<2;rf++){ for (int cf=0;cf<8;cf++) acc[rf][cf]=(f32x4){0.f,0.f,0.f,0.f}; }
    #pragma unroll
    for (int cf=0; cf<8; ++cf){
      #pragma unroll
      for (int ks=0; ks<2; ++ks){
        short8 b = frag_ld(KT, cf*16+l16, 128, lh*16+ks*64);
        acc[0][cf]=MFMA(qa[0][ks],b,acc[0][cf]);
        acc[1][cf]=MFMA(qa[1][ks],b,acc[1][cf]);
      }
    }
    #pragma unroll
    for (int rf=0;rf<2;rf++){
      #pragma unroll
      for (int reg=0;reg<4;reg++){
        int rl = w*32 + rf*16 + lh*4 + reg;
        float aqv=aqL[rl], c1v=c1L[rl], iq1=i1qL[rl], iq2=i2qL[rl];
        int s = rf*4+reg;
        #pragma unroll
        for (int cf=0;cf<8;cf++){
          int ml = cf*16 + l16;
          float S = acc[rf][cf][reg];
          float cosv = clampf(S*iq1*i1kL[ml], -0.99f, 0.99f);
          float covv = clampf((S - c1v - aqv*kdL[ml])*KCOV, -10.0f, 10.0f);
          float csv  = clampf(S*iq2*i2kL[ml], -0.99f, 0.99f);
          float marg = clampf(0.01f - csv, 0.0f, 2.0f);
          sc += cosv; sc2 = fmaf(cosv,cosv,sc2);
          so += covv; so2 = fmaf(covv,covv,so2);
          sco = fmaf(cosv,covv,sco);
          rcs[s]+=cosv; rco[s]+=covv; rcm[s]+=marg;
        }
      }
    }
  }
  #pragma unroll
  for (int m=1;m<16;m<<=1){
    #pragma unroll
    for (int s=0;s<8;s++){
      rcs[s]+=__shfl_xor(rcs[s],m,64);
      rco[s]+=__shfl_xor(rco[s],m,64);
      rcm[s]+=__shfl_xor(rcm[s],m,64);
    }
  }
  if (l16==0){
    #pragma unroll
    for (int s=0;s<8;s++){
      int rf=s>>2, reg=s&3;
      int n = n0 + w*32 + rf*16 + lh*4 + reg;
      size_t base=((size_t)hq*SEQ+n)*3;
      rs_part[base]=rcs[s]; rs_part[base+1]=rco[s]; rs_part[base+2]=rcm[s];
    }
  }
  float sums[5]={sc,sc2,so,so2,sco};
  for (int c=0;c<5;c++){
    __syncthreads();
    red[t]=sums[c]; __syncthreads();
    for (int o=128;o>0;o>>=1){ if (t<o) red[t]+=red[t+o]; __syncthreads(); }
    if (t==0) mom_part[(size_t)(hq*4+strip)*5 + c] = red[0];
  }
}

// ---------------------------------------------------------------- R: reduce row-partials
__device__ __forceinline__ double blockReduceD(double v, double* buf){
  int t = threadIdx.x;
  buf[t]=v; __syncthreads();
  for (int o=128;o>0;o>>=1){ if (t<o) buf[t]+=buf[t+o]; __syncthreads(); }
  double r = buf[0]; __syncthreads();
  return r;
}

__global__ void __launch_bounds__(256) rowred_kernel(
    const float* __restrict__ rs_part, double* __restrict__ hq_sums)
{
  int hq = blockIdx.x, t = threadIdx.x;
  double a0=0,a1=0,a2=0,a3=0;
  for (int n=t; n<SEQ; n+=256){
    size_t base = ((size_t)hq*SEQ + n)*3;
    float rc=rs_part[base], ro=rs_part[base+1], rm=rs_part[base+2];
    float mm = rm*(1.0f/512.0f);
    a0 += mm; a1 += (double)mm*mm; a2 += (double)mm*rc; a3 += (double)mm*ro;
  }
  __shared__ double dbuf[256];
  a0 = blockReduceD(a0,dbuf);
  a1 = blockReduceD(a1,dbuf);
  a2 = blockReduceD(a2,dbuf);
  a3 = blockReduceD(a3,dbuf);
  if (t==0){
    hq_sums[hq*4+0]=a0; hq_sums[hq*4+1]=a1; hq_sums[hq*4+2]=a2; hq_sums[hq*4+3]=a3;
  }
}

// ---------------------------------------------------------------- F: MLP + stds + mix params
__global__ void __launch_bounds__(256) finalize_kernel(
    const float* __restrict__ qgp, const float* __restrict__ kgp,
    const float* __restrict__ wp1w, const float* __restrict__ wp1b,
    const float* __restrict__ wplg, const float* __restrict__ wplb,
    const float* __restrict__ wp2w, const float* __restrict__ wp2b,
    const float* __restrict__ wp3w, const float* __restrict__ wp3b,
    const float* __restrict__ temp,
    const float* __restrict__ mom_part, const double* __restrict__ hq_sums,
    float* __restrict__ params)
{
  int t = threadIdx.x;
  __shared__ float feats[8][128];
  __shared__ float h1s[8][64];
  __shared__ float h2s[8][32];
  __shared__ float wts[8][3];
  __shared__ double Sh[8][9];
  for (int idx=t; idx<512; idx+=256){
    int h = idx>>6, d = idx&63;
    float s1=0, s2=0;
    for (int qq=0; qq<QB; qq++){ s1 += qgp[(h*QB+qq)*64+d]; s2 += kgp[(h*QB+qq)*64+d]; }
    feats[h][d]    = s1*(1.0f/8192.0f);
    feats[h][64+d] = s2*(1.0f/8192.0f);
  }
  __syncthreads();
  int w = t>>6, j = t&63;
  for (int pp=0; pp<2; pp++){
    int h = w + pp*4;
    float acc = wp1b[j];
    for (int k=0;k<128;k++) acc += feats[h][k]*wp1w[k*64+j];
    float s=acc, s2=acc*acc;
    #pragma unroll
    for (int m=32;m>0;m>>=1){ s+=__shfl_xor(s,m,64); s2+=__shfl_xor(s2,m,64); }
    float mean = s*(1.0f/64.0f);
    float var  = s2*(1.0f/64.0f) - mean*mean;
    float xh = (acc-mean)*rsqrtf(var+1e-5f)*wplg[j] + wplb[j];
    h1s[h][j] = fmaxf(xh, 0.0f);
  }
  __syncthreads();
  {
    int h = t>>5, j2 = t&31;
    float acc = wp2b[j2];
    for (int k=0;k<64;k++) acc += h1s[h][k]*wp2w[k*32+j2];
    h2s[h][j2] = fmaxf(acc, 0.0f);
  }
  __syncthreads();
  if (t<8){
    int h = t;
    float z[3] = {wp3b[0], wp3b[1], wp3b[2]};
    for (int k=0;k<32;k++){
      float hv = h2s[h][k];
      z[0]+=hv*wp3w[k*3]; z[1]+=hv*wp3w[k*3+1]; z[2]+=hv*wp3w[k*3+2];
    }
    float mx = fmaxf(z[0], fmaxf(z[1], z[2]));
    float e0=expf(z[0]-mx), e1=expf(z[1]-mx), e2=expf(z[2]-mx);
    float inv = 1.0f/(e0+e1+e2);
    float l0=e0*inv, l1=e1*inv, l2=e2*inv;
    float tv = temp[0]; tv = fminf(fmaxf(tv, 0.1f), 20.0f);
    float y0=l0/tv, y1=l1/tv, y2=l2/tv;
    float mx2 = fmaxf(y0, fmaxf(y1, y2));
    float f0=expf(y0-mx2), f1=expf(y1-mx2), f2=expf(y2-mx2);
    float inv2 = 1.0f/(f0+f1+f2);
    wts[h][0]=f0*inv2; wts[h][1]=f1*inv2; wts[h][2]=f2*inv2;
  }
  __syncthreads();
  if (t<40){
    int h = t/5, c = t%5;
    double s = 0;
    for (int b2=0; b2<64; b2++) s += (double)mom_part[(size_t)(h*64+b2)*5 + c];
    Sh[h][c] = s;
  }
  __syncthreads();
  if (t<32){
    int h = t>>2, c = t&3;
    double s = 0;
    for (int qq=0; qq<QB; qq++) s += hq_sums[(h*QB+qq)*4 + c];
    Sh[h][5+c] = s;
  }
  __syncthreads();
  if (t==0){
    const double Ntot = 33554432.0;
    double T1c=0,T2c=0,T1o=0,T2o=0,T1v=0,T2v=0;
    for (int h=0;h<8;h++){
      T1c+=Sh[h][0]; T2c+=Sh[h][1]; T1o+=Sh[h][2]; T2o+=Sh[h][3];
      T1v+=512.0*Sh[h][5]; T2v+=512.0*Sh[h][6];
    }
    double stdc = sqrt(fmax((T2c - T1c*T1c/Ntot)/(Ntot-1.0), 0.0));
    double stdo = sqrt(fmax((T2o - T1o*T1o/Ntot)/(Ntot-1.0), 0.0));
    double stdv = sqrt(fmax((T2v - T1v*T1v/Ntot)/(Ntot-1.0), 0.0));
    double ah[8], bh[8];
    double Sd1=0, Sd2=0;
    for (int h=0;h<8;h++){
      double a = (double)wts[h][0]/(stdc+1e-8);
      double b = (double)wts[h][1]*0.1/(stdo+1e-8);
      double c = (double)wts[h][2]*0.1/(stdv+1e-8);
      ah[h]=a; bh[h]=b;
      Sd1 += a*Sh[h][0] + b*Sh[h][2] + c*512.0*Sh[h][5];
      Sd2 += a*a*Sh[h][1] + b*b*Sh[h][3] + c*c*512.0*Sh[h][6]
           + 2.0*a*b*Sh[h][4] + 2.0*a*c*Sh[h][7] + 2.0*b*c*Sh[h][8];
    }
    double stdd = sqrt(fmax((Sd2 - Sd1*Sd1/Ntot)/(Ntot-1.0), 0.0));
    double att = 1.0 + 0.5*stdd;
    att = fmin(fmax(att, 0.5), 5.0);
    double scale = 1.0/att;
    for (int h=0;h<8;h++){
      params[h*2+0] = (float)(scale*ah[h]);
      params[h*2+1] = (float)(scale*bh[h]);
    }
  }
}

// ---------------------------------------------------------------- M2: logits + flash softmax + PV (MFMA)
__global__ void __launch_bounds__(256) attn_m2_kernel(
    const unsigned short* __restrict__ fq, const unsigned short* __restrict__ fk,
    const unsigned short* __restrict__ fvT,
    const float* __restrict__ aqA, const float* __restrict__ c1A, const float* __restrict__ i1qA,
    const float* __restrict__ rskA, const float* __restrict__ i1kA,
    const float* __restrict__ c2A, const float* __restrict__ params,
    unsigned short* __restrict__ attn_bf)
{
  int strip=blockIdx.x, q_=blockIdx.y, h=blockIdx.z;
  int hq=h*QB+q_, n0=strip*128;
  const unsigned short* Fq=fq+(size_t)hq*SEQ*DHD;
  const unsigned short* Fk=fk+(size_t)hq*SEQ*DHD;
  const unsigned short* FvT=fvT+(size_t)hq*DHD*SEQ;
  __shared__ unsigned short KT[128*64];     // aliased as P after barrier
  __shared__ unsigned short VT[64*128];     // [d][m], pitch 256B
  __shared__ float kdL[128], i1kL[128];
  __shared__ float aqL[128], c1L[128], i1qL[128];
  int t=threadIdx.x, w=t>>6, lane=t&63, l16=lane&15, lh=lane>>4;
  float c2v=c2A[hq];
  float pa=params[h*2], pb=params[h*2+1];
  if (t<128){
    aqL[t]=aqA[hq*SEQ+n0+t]; c1L[t]=c1A[hq*SEQ+n0+t]; i1qL[t]=i1qA[hq*SEQ+n0+t];
  }
  short8 qa[2][2];
  #pragma unroll
  for (int rf=0;rf<2;rf++){
    int ng = n0 + w*32 + rf*16 + l16;
    #pragma unroll
    for (int ks=0;ks<2;ks++)
      qa[rf][ks] = *reinterpret_cast<const short8*>(&Fq[(size_t)ng*DHD + ks*32 + lh*8]);
  }
  f32x4 accO[2][4];
  #pragma unroll
  for (int rf=0;rf<2;rf++){ for (int j=0;j<4;j++) accO[rf][j]=(f32x4){0.f,0.f,0.f,0.f}; }
  float Mr[8], Dr[8];
  #pragma unroll
  for (int s=0;s<8;s++){ Mr[s]=-3.0e38f; Dr[s]=0.f; }
  for (int mc=0;mc<4;mc++){
    int m0=mc*128;
    __syncthreads();
    for (int it=0;it<4;++it){
      int idx=it*256+t,row=idx>>3,qc=idx&7;
      ushort8v vv = *reinterpret_cast<const ushort8v*>(&Fk[(size_t)(m0+row)*DHD + qc*8]);
      tile_st16(KT,row,128,qc*16,vv);
    }
    for (int it=0;it<4;++it){
      int idx=it*256+t, dd=idx>>4, c=idx&15;
      ushort8v vv=*reinterpret_cast<const ushort8v*>(&FvT[(size_t)dd*SEQ + m0 + c*8]);
      tile_st16(VT, dd, 256, c*16, vv);
    }
    if (t<128){ kdL[t]=rskA[hq*SEQ+m0+t]-c2v; i1kL[t]=i1kA[hq*SEQ+m0+t]; }
    __syncthreads();
    f32x4 acc[2][8];
    #pragma unroll
    for (int rf=0;rf<2;rf++){ for (int cf=0;cf<8;cf++) acc[rf][cf]=(f32x4){0.f,0.f,0.f,0.f}; }
    #pragma unroll
    for (int cf=0; cf<8; ++cf){
      #pragma unroll
      for (int ks=0; ks<2; ++ks){
        short8 b = frag_ld(KT, cf*16+l16, 128, lh*16+ks*64);
        acc[0][cf]=MFMA(qa[0][ks],b,acc[0][cf]);
        acc[1][cf]=MFMA(qa[1][ks],b,acc[1][cf]);
      }
    }
    // transform to mixed logits
    #pragma unroll
    for (int rf=0;rf<2;rf++){
      #pragma unroll
      for (int reg=0;reg<4;reg++){
        int rl = w*32 + rf*16 + lh*4 + reg;
        float aqv=aqL[rl], c1v=c1L[rl], iq1=i1qL[rl];
        #pragma unroll
        for (int cf=0;cf<8;cf++){
          int ml = cf*16 + l16;
          float S = acc[rf][cf][reg];
          float cosv = clampf(S*iq1*i1kL[ml], -0.99f, 0.99f);
          float covv = clampf((S - c1v - aqv*kdL[ml])*KCOV, -10.0f, 10.0f);
          acc[rf][cf][reg] = pa*cosv + pb*covv;
        }
      }
    }
    // flash update
    float Fsc[8];
    #pragma unroll
    for (int rf=0;rf<2;rf++){
      #pragma unroll
      for (int reg=0;reg<4;reg++){
        int s=rf*4+reg;
        float mx=acc[rf][0][reg];
        #pragma unroll
        for (int cf=1;cf<8;cf++) mx=fmaxf(mx,acc[rf][cf][reg]);
        #pragma unroll
        for (int m=1;m<16;m<<=1) mx=fmaxf(mx,__shfl_xor(mx,m,64));
        float Mn=fmaxf(Mr[s],mx);
        Fsc[s]=__expf(Mr[s]-Mn);
        Mr[s]=Mn;
        float ps=0.f;
        #pragma unroll
        for (int cf=0;cf<8;cf++){
          float e=__expf(acc[rf][cf][reg]-Mn);
          acc[rf][cf][reg]=e; ps+=e;
        }
        #pragma unroll
        for (int m=1;m<16;m<<=1) ps+=__shfl_xor(ps,m,64);
        Dr[s]=Dr[s]*Fsc[s]+ps;
      }
    }
    #pragma unroll
    for (int rf=0;rf<2;rf++){
      #pragma unroll
      for (int j=0;j<4;j++){
        #pragma unroll
        for (int reg=0;reg<4;reg++) accO[rf][j][reg]*=Fsc[rf*4+reg];
      }
    }
    __syncthreads();   // all waves done reading KT -> safe to alias as P
    unsigned short* P = KT;
    #pragma unroll
    for (int mh=0;mh<2;mh++){
      #pragma unroll
      for (int rf=0;rf<2;rf++){
        #pragma unroll
        for (int reg=0;reg<4;reg++){
          int prow = w*32 + rf*16 + lh*4 + reg;
          #pragma unroll
          for (int cfl=0; cfl<4; ++cfl){
            int addr = prow*128 + (((cfl*16+l16)*2) ^ ((prow&7)<<4));
            *reinterpret_cast<unsigned short*>(reinterpret_cast<char*>(P) + addr)
              = f2bf(acc[rf][mh*4+cfl][reg]);
          }
        }
      }
      #pragma unroll
      for (int ks=0;ks<2;ks++){
        int kb = lh*16 + ks*64;
        short8 pA[2];
        #pragma unroll
        for (int rf=0;rf<2;rf++) pA[rf]=frag_ld(P, w*32+rf*16+l16, 128, kb);
        short8 vB[4];
        #pragma unroll
        for (int dcf=0;dcf<4;dcf++) vB[dcf]=frag_ld(VT, dcf*16+l16, 256, mh*128 + kb);
        #pragma unroll
        for (int rf=0;rf<2;rf++){
          #pragma unroll
          for (int dcf=0;dcf<4;dcf++) accO[rf][dcf]=MFMA(pA[rf],vB[dcf],accO[rf][dcf]);
        }
      }
    }
  }
  // epilogue: normalize, bounce own 32x64 tile through LDS, coalesced store
  float invD[8];
  #pragma unroll
  for (int s=0;s<8;s++) invD[s]=1.0f/Dr[s];
  unsigned short* P = KT;
  #pragma unroll
  for (int rf=0;rf<2;rf++){
    #pragma unroll
    for (int dcf=0;dcf<4;dcf++){
      #pragma unroll
      for (int reg=0;reg<4;reg++){
        int prow = w*32 + rf*16 + lh*4 + reg;
        int addr = prow*128 + (((dcf*16+l16)*2) ^ ((prow&7)<<4));
        *reinterpret_cast<unsigned short*>(reinterpret_cast<char*>(P) + addr)
          = f2bf(accO[rf][dcf][reg]*invD[rf*4+reg]);
      }
    }
  }
  for (int it=0; it<4; ++it){
    int idx = it*64 + lane;
    int row = idx>>3, c = idx&7;
    int prow = w*32 + row;
    int addr = prow*128 + ((c*16) ^ ((prow&7)<<4));
    ushort8v vv = *reinterpret_cast<ushort8v*>(reinterpret_cast<char*>(P) + addr);
    *reinterpret_cast<ushort8v*>(
      &attn_bf[(size_t)(q_*SEQ + n0 + w*32 + row)*DMODEL + h*DHD + c*8]) = vv;
  }
}

// ---------------------------------------------------------------- KO: output projection (MFMA)
__global__ void __launch_bounds__(256) out_mfma_kernel(
    const unsigned short* __restrict__ attn_bf, const unsigned short* __restrict__ WoT,
    const float* __restrict__ bias, float* __restrict__ out)
{
  int r0=blockIdx.x*128;  // m rows
  int c0=blockIdx.y*128;  // out cols
  __shared__ unsigned short AT[128*64];
  __shared__ unsigned short WT[128*64];
  int t=threadIdx.x, w=t>>6, lane=t&63, l16=lane&15, lh=lane>>4;
  f32x4 acc[4][4];
  #pragma unroll
  for(int i=0;i<4;i++){ for(int j=0;j<4;j++) acc[i][j]=(f32x4){0.f,0.f,0.f,0.f}; }
  for (int k0=0;k0<DMODEL;k0+=64){
    __syncthreads();
    for (int it=0; it<4; ++it){
      int idx=it*256+t, row=idx>>3, q=idx&7;
      ushort8v v = *reinterpret_cast<const ushort8v*>(&attn_bf[(size_t)(r0+row)*DMODEL + k0 + q*8]);
      tile_st16(AT, row, 128, q*16, v);
    }
    for (int it=0; it<4; ++it){
      int idx=it*256+t, row=idx>>3, q=idx&7;
      ushort8v v = *reinterpret_cast<const ushort8v*>(&WoT[(size_t)(c0+row)*DMODEL + k0 + q*8]);
      tile_st16(WT, row, 128, q*16, v);
    }
    __syncthreads();
    int nr=(w&1)*64, mr=(w>>1)*64;
    #pragma unroll
    for (int ks=0; ks<2; ++ks){
      int kb = lh*16 + ks*64;
      short8 a[4], b[4];
      #pragma unroll
      for (int i=0;i<4;i++) a[i] = frag_ld(WT, nr+i*16+l16, 128, kb);
      #pragma unroll
      for (int j=0;j<4;j++) b[j] = frag_ld(AT, mr+j*16+l16, 128, kb);
      #pragma unroll
      for (int i=0;i<4;i++){
        #pragma unroll
        for (int j=0;j<4;j++) acc[i][j]=MFMA(a[i],b[j],acc[i][j]);
      }
    }
  }
  #pragma unroll
  for (int i=0;i<4;i++){
    int nb = c0+(w&1)*64+i*16+lh*4;
    float4 b4 = *reinterpret_cast<const float4*>(&bias[nb]);
    #pragma unroll
    for (int j=0;j<4;j++){
      int mg = r0+(w>>1)*64+j*16+l16;
      f32x4 o = acc[i][j];
      o[0]+=b4.x; o[1]+=b4.y; o[2]+=b4.z; o[3]+=b4.w;
      *reinterpret_cast<f32x4*>(&out[(size_t)mg*DMODEL + nb]) = o;
    }
  }
}

// ----------------------------------------------------------------
extern "C" void kernel_launch(void* const* d_in, const int* in_sizes, int n_in,
                              void* d_out, int out_size, void* d_ws, size_t ws_size,
                              hipStream_t stream)
{
  (void)in_sizes; (void)n_in; (void)out_size; (void)ws_size;
  const float* q     = (const float*)d_in[0];
  const float* k     = (const float*)d_in[1];
  const float* v     = (const float*)d_in[2];
  const float* ln_g  = (const float*)d_in[3];
  const float* ln_b  = (const float*)d_in[4];
  const float* W_in  = (const float*)d_in[5];
  const float* wp1w  = (const float*)d_in[6];
  const float* wp1b  = (const float*)d_in[7];
  const float* wplg  = (const float*)d_in[8];
  const float* wplb  = (const float*)d_in[9];
  const float* wp2w  = (const float*)d_in[10];
  const float* wp2b  = (const float*)d_in[11];
  const float* wp3w  = (const float*)d_in[12];
  const float* wp3b  = (const float*)d_in[13];
  const float* temp  = (const float*)d_in[14];
  const float* W_out = (const float*)d_in[15];
  const float* b_out = (const float*)d_in[16];
  float* out = (float*)d_out;

  char* wsb = (char*)d_ws;
  size_t off = 0;
  auto alloc = [&](size_t bytes)->char*{
    char* p = wsb + off; off += (bytes + 255) & ~(size_t)255; return p;
  };
  unsigned short* fq_b   = (unsigned short*)alloc((size_t)NHQ*SEQ*DHD*2);
  unsigned short* fk_b   = (unsigned short*)alloc((size_t)NHQ*SEQ*DHD*2);
  unsigned short* fvT_b  = (unsigned short*)alloc((size_t)NHQ*SEQ*DHD*2);
  unsigned short* attn_b = (unsigned short*)alloc((size_t)NROWS*DMODEL*2);
  unsigned short* WiT    = (unsigned short*)alloc((size_t)DMODEL*DMODEL*2);
  unsigned short* WoT    = (unsigned short*)alloc((size_t)DMODEL*DMODEL*2);
  float* mu    = (float*)alloc(3*NROWS*4);
  float* rstd  = (float*)alloc(3*NROWS*4);
  float* aqA   = (float*)alloc(NHQ*SEQ*4);
  float* c1A   = (float*)alloc(NHQ*SEQ*4);
  float* i1qA  = (float*)alloc(NHQ*SEQ*4);
  float* i2qA  = (float*)alloc(NHQ*SEQ*4);
  float* rskA  = (float*)alloc(NHQ*SEQ*4);
  float* i1kA  = (float*)alloc(NHQ*SEQ*4);
  float* i2kA  = (float*)alloc(NHQ*SEQ*4);
  float* c2A   = (float*)alloc(NHQ*4);
  float* qgp   = (float*)alloc(NHQ*64*4);
  float* kgp   = (float*)alloc(NHQ*64*4);
  float* rs_part  = (float*)alloc((size_t)NHQ*SEQ*3*4);
  float* mom_part = (float*)alloc(512*5*4);
  float* params   = (float*)alloc(64);
  double* hq_sums = (double*)alloc(NHQ*4*8);

  ln_stats_kernel<<<dim3(NROWS/4, 3), 256, 0, stream>>>(q, k, v, mu, rstd);
  convert_w_kernel<<<dim3(8,8,2), 256, 0, stream>>>(W_in, W_out, WiT, WoT);
  proj_mfma_kernel<<<dim3(64,4,3), 256, 0, stream>>>(q, k, v, ln_g, ln_b, WiT, mu, rstd,
                                                     fq_b, fk_b, fvT_b);
  stats_kernel<<<dim3(NHQ), 256, 0, stream>>>(fq_b, fk_b, aqA, c1A, i1qA, i2qA,
                                              rskA, i1kA, i2kA, c2A, qgp, kgp);
  score_m1_kernel<<<dim3(4, QB, NH), 256, 0, stream>>>(fq_b, fk_b, aqA, c1A, i1qA, i2qA,
                                                       rskA, i1kA, i2kA, c2A, rs_part, mom_part);
  rowred_kernel<<<dim3(NHQ), 256, 0, stream>>>(rs_part, hq_sums);
  finalize_kernel<<<1, 256, 0, stream>>>(qgp, kgp, wp1w, wp1b, wplg, wplb, wp2w, wp2b,
                                         wp3w, wp3b, temp, mom_part, hq_sums, params);
  attn_m2_kernel<<<dim3(4, QB, NH), 256, 0, stream>>>(fq_b, fk_b, fvT_b, aqA, c1A, i1qA,
                                                      rskA, i1kA, c2A, params, attn_b);
  out_mfma_kernel<<<dim3(64,4), 256, 0, stream>>>(attn_b, WoT, b_out, out);
}

// Round 3
// 175.748 us; speedup vs baseline: 4.3751x; 1.7279x over previous
//
#include <hip/hip_runtime.h>
#include <math.h>

#define NH 8
#define DHD 64
#define DMODEL 512
#define QB 16
#define SEQ 512
#define NROWS (QB*SEQ)      /* 8192 rows per input */
#define NHQ (NH*QB)         /* 128 (h,q) pairs */
#define KCOV ((float)((0.001/512.0)/(8.0+1e-8)))

typedef __attribute__((ext_vector_type(8))) short short8;      // 8 bf16 -> 4 VGPR
typedef __attribute__((ext_vector_type(8))) unsigned short ushort8v;
typedef __attribute__((ext_vector_type(4))) unsigned short ushort4v;
typedef __attribute__((ext_vector_type(4))) float f32x4;

__device__ __forceinline__ float bf2f(unsigned short u){
  union { unsigned int i; float f; } c; c.i = ((unsigned int)u)<<16; return c.f;
}
__device__ __forceinline__ unsigned short f2bf(float f){
  union { float f; unsigned int i; } c; c.f = f;
  unsigned int u = c.i;
  u += 0x7fffu + ((u>>16)&1u);   // RNE
  return (unsigned short)(u>>16);
}
__device__ __forceinline__ float clampf(float x, float lo, float hi){ return fminf(fmaxf(x,lo),hi); }

__device__ __forceinline__ f32x4 MFMA(short8 a, short8 b, f32x4 c){
  return __builtin_amdgcn_mfma_f32_16x16x32_bf16(a, b, c, 0, 0, 0);
}
// swizzled-tile access: element (row, kbyte), rowbytes pitch, XOR-swizzle bits 4-6 by row&7
__device__ __forceinline__ short8 frag_ld(const unsigned short* T, int row, int rowbytes, int kbyte){
  int addr = row*rowbytes + (kbyte ^ ((row&7)<<4));
  return *reinterpret_cast<const short8*>(reinterpret_cast<const char*>(T) + addr);
}
__device__ __forceinline__ void tile_st16(unsigned short* T, int row, int rowbytes, int kbyte, ushort8v v){
  int addr = row*rowbytes + (kbyte ^ ((row&7)<<4));
  *reinterpret_cast<ushort8v*>(reinterpret_cast<char*>(T) + addr) = v;
}
__device__ __forceinline__ void tile_st8(unsigned short* T, int row, int rowbytes, int kbyte, ushort4v v){
  int addr = row*rowbytes + (kbyte ^ ((row&7)<<4));
  *reinterpret_cast<ushort4v*>(reinterpret_cast<char*>(T) + addr) = v;
}

// ---------------------------------------------------------------- K1a: LN row stats
__global__ void __launch_bounds__(256) ln_stats_kernel(
    const float* __restrict__ xq, const float* __restrict__ xk, const float* __restrict__ xv,
    float* __restrict__ mu, float* __restrict__ rstd)
{
  int which = blockIdx.y;
  const float* src = which==0 ? xq : (which==1 ? xk : xv);
  int w = threadIdx.x >> 6, lane = threadIdx.x & 63;
  int row = blockIdx.x*4 + w;
  const float* x = src + (size_t)row*DMODEL;
  float4 v1 = *reinterpret_cast<const float4*>(&x[lane*8]);
  float4 v2 = *reinterpret_cast<const float4*>(&x[lane*8+4]);
  float s  = v1.x+v1.y+v1.z+v1.w + v2.x+v2.y+v2.z+v2.w;
  float ss = v1.x*v1.x+v1.y*v1.y+v1.z*v1.z+v1.w*v1.w
           + v2.x*v2.x+v2.y*v2.y+v2.z*v2.z+v2.w*v2.w;
  #pragma unroll
  for (int m=32; m>0; m>>=1){ s += __shfl_xor(s,m,64); ss += __shfl_xor(ss,m,64); }
  if (lane==0){
    float m_ = s*(1.0f/DMODEL);
    float var = ss*(1.0f/DMODEL) - m_*m_;
    mu[(size_t)which*NROWS + row]   = m_;
    rstd[(size_t)which*NROWS + row] = rsqrtf(var + 1e-5f);
  }
}

// ---------------------------------------------------------------- K1w: transpose+cast weights
__global__ void __launch_bounds__(256) convert_w_kernel(
    const float* __restrict__ Wi, const float* __restrict__ Wo,
    unsigned short* __restrict__ WiT, unsigned short* __restrict__ WoT)
{
  const float* src = blockIdx.z ? Wo : Wi;
  unsigned short* dst = blockIdx.z ? WoT : WiT;
  int r0 = blockIdx.x*64, c0 = blockIdx.y*64;
  __shared__ float T[64][68];
  int t = threadIdx.x;
  for (int it=0; it<4; ++it){
    int idx = it*256+t, row = idx>>4, q = idx&15;
    float4 v = *reinterpret_cast<const float4*>(&src[(size_t)(r0+row)*DMODEL + c0 + q*4]);
    T[row][q*4+0]=v.x; T[row][q*4+1]=v.y; T[row][q*4+2]=v.z; T[row][q*4+3]=v.w;
  }
  __syncthreads();
  for (int it=0; it<4; ++it){
    int idx = it*256+t, oc = idx>>4, q = idx&15;
    ushort4v o;
    o[0]=f2bf(T[q*4+0][oc]); o[1]=f2bf(T[q*4+1][oc]);
    o[2]=f2bf(T[q*4+2][oc]); o[3]=f2bf(T[q*4+3][oc]);
    *reinterpret_cast<ushort4v*>(&dst[(size_t)(c0+oc)*DMODEL + r0 + q*4]) = o;
  }
}

// ---------------------------------------------------------------- K1b: LN-fused projection (MFMA)
// which<2: writes f[hq][n][d] bf16 (row-major).  which==2: writes fvT[hq][d][n] bf16.
__global__ void __launch_bounds__(256) proj_mfma_kernel(
    const float* __restrict__ xq, const float* __restrict__ xk, const float* __restrict__ xv,
    const float* __restrict__ g, const float* __restrict__ bb,
    const unsigned short* __restrict__ WiT,
    const float* __restrict__ mu, const float* __restrict__ rstd,
    unsigned short* __restrict__ fq, unsigned short* __restrict__ fk, unsigned short* __restrict__ fvT)
{
  int which = blockIdx.z;
  const float* src = which==0?xq:(which==1?xk:xv);
  int r0 = blockIdx.x*128;   // x rows (n-dim)
  int c0 = blockIdx.y*128;   // output cols (head*64+d dim)
  __shared__ unsigned short XT[128*64];  // LN(x) tile, rows n-local, pitch 128B
  __shared__ unsigned short WT[128*64];  // WiT tile, rows c-local, pitch 128B
  __shared__ float gs[DMODEL], bs[DMODEL], mus[128], rss[128];
  int t = threadIdx.x;
  for (int i=t;i<DMODEL;i+=256){ gs[i]=g[i]; bs[i]=bb[i]; }
  if (t<128){ mus[t]=mu[(size_t)which*NROWS+r0+t]; rss[t]=rstd[(size_t)which*NROWS+r0+t]; }
  int w=t>>6, lane=t&63, l16=lane&15, lh=lane>>4;
  f32x4 acc[4][4];
  #pragma unroll
  for(int i=0;i<4;i++){ for(int j=0;j<4;j++) acc[i][j]=(f32x4){0.f,0.f,0.f,0.f}; }
  for (int k0=0;k0<DMODEL;k0+=64){
    __syncthreads();
    for (int it=0; it<8; ++it){
      int idx=it*256+t, row=idx>>4, q=idx&15;
      float4 x4 = *reinterpret_cast<const float4*>(&src[(size_t)(r0+row)*DMODEL + k0 + q*4]);
      float m_=mus[row], rs_=rss[row];
      const float* g4=&gs[k0+q*4]; const float* b4=&bs[k0+q*4];
      ushort4v o;
      o[0]=f2bf((x4.x-m_)*rs_*g4[0]+b4[0]);
      o[1]=f2bf((x4.y-m_)*rs_*g4[1]+b4[1]);
      o[2]=f2bf((x4.z-m_)*rs_*g4[2]+b4[2]);
      o[3]=f2bf((x4.w-m_)*rs_*g4[3]+b4[3]);
      tile_st8(XT, row, 128, q*8, o);
    }
    for (int it=0; it<4; ++it){
      int idx=it*256+t, row=idx>>3, q=idx&7;
      ushort8v v = *reinterpret_cast<const ushort8v*>(&WiT[(size_t)(c0+row)*DMODEL + k0 + q*8]);
      tile_st16(WT, row, 128, q*16, v);
    }
    __syncthreads();
    if (which<2){
      int dr=(w&1)*64, nc=(w>>1)*64;   // D rows = c-local, D cols = n-local
      #pragma unroll
      for (int ks=0; ks<2; ++ks){
        int kb = lh*16 + ks*64;
        short8 a[4], b[4];
        #pragma unroll
        for (int i=0;i<4;i++) a[i] = frag_ld(WT, dr+i*16+l16, 128, kb);
        #pragma unroll
        for (int j=0;j<4;j++) b[j] = frag_ld(XT, nc+j*16+l16, 128, kb);
        #pragma unroll
        for (int i=0;i<4;i++){
          #pragma unroll
          for (int j=0;j<4;j++) acc[i][j]=MFMA(a[i],b[j],acc[i][j]);
        }
      }
    } else {
      int nr=(w>>1)*64, dc=(w&1)*64;   // D rows = n-local, D cols = d-local
      #pragma unroll
      for (int ks=0; ks<2; ++ks){
        int kb = lh*16 + ks*64;
        short8 a[4], b[4];
        #pragma unroll
        for (int i=0;i<4;i++) a[i] = frag_ld(XT, nr+i*16+l16, 128, kb);
        #pragma unroll
        for (int j=0;j<4;j++) b[j] = frag_ld(WT, dc+j*16+l16, 128, kb);
        #pragma unroll
        for (int i=0;i<4;i++){
          #pragma unroll
          for (int j=0;j<4;j++) acc[i][j]=MFMA(a[i],b[j],acc[i][j]);
        }
      }
    }
  }
  if (which<2){
    unsigned short* dst = which ? fk : fq;
    int dr=(w&1)*64, nc=(w>>1)*64;
    #pragma unroll
    for (int i=0;i<4;i++){
      #pragma unroll
      for (int j=0;j<4;j++){
        int cl = c0 + dr + i*16 + lh*4;   // 4 consecutive output cols
        int ng = r0 + nc + j*16 + l16;    // row
        int head = cl>>6, dd = cl&63;
        int hq = head*QB + (ng>>9);
        int n = ng&511;
        ushort4v o;
        o[0]=f2bf(acc[i][j][0]); o[1]=f2bf(acc[i][j][1]);
        o[2]=f2bf(acc[i][j][2]); o[3]=f2bf(acc[i][j][3]);
        *reinterpret_cast<ushort4v*>(&dst[((size_t)hq*SEQ+n)*DHD + dd]) = o;
      }
    }
  } else {
    int nr=(w>>1)*64, dc=(w&1)*64;
    #pragma unroll
    for (int i=0;i<4;i++){
      #pragma unroll
      for (int j=0;j<4;j++){
        int ngb = r0 + nr + i*16 + lh*4;  // 4 consecutive n
        int dg  = c0 + dc + j*16 + l16;   // col
        int head = dg>>6, dd = dg&63;
        int hq = head*QB + (ngb>>9);
        int n = ngb&511;
        ushort4v o;
        o[0]=f2bf(acc[i][j][0]); o[1]=f2bf(acc[i][j][1]);
        o[2]=f2bf(acc[i][j][2]); o[3]=f2bf(acc[i][j][3]);
        *reinterpret_cast<ushort4v*>(&fvT[((size_t)hq*DHD+dd)*SEQ + n]) = o;
      }
    }
  }
}

// ---------------------------------------------------------------- S1: row stats (quad-per-row)
__global__ void __launch_bounds__(256) rowstats_kernel(
    const unsigned short* __restrict__ fq, const unsigned short* __restrict__ fk,
    float* __restrict__ aqA, float* __restrict__ i1qA, float* __restrict__ i2qA,
    float* __restrict__ rskA, float* __restrict__ i1kA, float* __restrict__ i2kA)
{
  int hq = blockIdx.x, part = blockIdx.y, isk = blockIdx.z;
  const unsigned short* F = (isk ? fk : fq) + (size_t)hq*SEQ*DHD;
  int t = threadIdx.x;
  int quad = t>>2, qq = t&3;
  int n = part*64 + quad;
  const unsigned short* row = &F[(size_t)n*DHD + qq*16];
  ushort8v a = *reinterpret_cast<const ushort8v*>(row);
  ushort8v b = *reinterpret_cast<const ushort8v*>(row+8);
  float s=0.f, ss=0.f;
  #pragma unroll
  for (int i=0;i<8;i++){ float v=bf2f(a[i]); s+=v; ss=fmaf(v,v,ss); }
  #pragma unroll
  for (int i=0;i<8;i++){ float v=bf2f(b[i]); s+=v; ss=fmaf(v,v,ss); }
  s += __shfl_xor(s,1,64); ss += __shfl_xor(ss,1,64);
  s += __shfl_xor(s,2,64); ss += __shfl_xor(ss,2,64);
  if (qq==0){
    float nrm = sqrtf(ss);
    if (isk){
      rskA[hq*SEQ+n] = s;
      i1kA[hq*SEQ+n] = 1.0f/(nrm+1e-8f);
      i2kA[hq*SEQ+n] = 1.0f/fmaxf(nrm,1e-8f);
    } else {
      aqA[hq*SEQ+n]  = s*(1.0f/64.0f);
      i1qA[hq*SEQ+n] = 1.0f/(nrm+1e-8f);
      i2qA[hq*SEQ+n] = 1.0f/fmaxf(nrm,1e-8f);
    }
  }
}

// ---------------------------------------------------------------- S2: column-sum partials
// colpart[isk][hq][quarter][64]
__global__ void __launch_bounds__(256) colsum_kernel(
    const unsigned short* __restrict__ fq, const unsigned short* __restrict__ fk,
    float* __restrict__ colpart)
{
  int hq = blockIdx.x, quarter = blockIdx.y, isk = blockIdx.z;
  const unsigned short* F = (isk ? fk : fq) + (size_t)hq*SEQ*DHD;
  int t = threadIdx.x, g = t&15, rg = t>>4;   // g: col group of 4, rg: row group of 16
  float acc0=0.f, acc1=0.f, acc2=0.f, acc3=0.f;
  #pragma unroll
  for (int i=0;i<8;i++){
    int r = quarter*128 + rg + 16*i;
    ushort4v v = *reinterpret_cast<const ushort4v*>(&F[(size_t)r*DHD + g*4]);
    acc0+=bf2f(v[0]); acc1+=bf2f(v[1]); acc2+=bf2f(v[2]); acc3+=bf2f(v[3]);
  }
  __shared__ float sh[16][68];
  sh[rg][g*4+0]=acc0; sh[rg][g*4+1]=acc1; sh[rg][g*4+2]=acc2; sh[rg][g*4+3]=acc3;
  __syncthreads();
  if (t<64){
    float s=0.f;
    #pragma unroll
    for (int r=0;r<16;r++) s += sh[r][t];
    colpart[(((size_t)isk*NHQ + hq)*4 + quarter)*64 + t] = s;
  }
}

// ---------------------------------------------------------------- S3: combine colsums -> qgp,kgp,c2
__global__ void __launch_bounds__(64) colreduce_kernel(
    const float* __restrict__ colpart,
    float* __restrict__ qgp, float* __restrict__ kgp, float* __restrict__ c2A)
{
  int hq = blockIdx.x, d = threadIdx.x;
  float sq=0.f, sk=0.f;
  #pragma unroll
  for (int qu=0;qu<4;qu++){
    sq += colpart[(((size_t)0*NHQ + hq)*4 + qu)*64 + d];
    sk += colpart[(((size_t)1*NHQ + hq)*4 + qu)*64 + d];
  }
  qgp[hq*64+d]=sq; kgp[hq*64+d]=sk;
  float c = sk*(1.0f/512.0f);
  #pragma unroll
  for (int m=32;m>0;m>>=1) c += __shfl_xor(c,m,64);
  if (d==0) c2A[hq]=c;
}

// ---------------------------------------------------------------- S4: c1[n] = Fq[n] . bar_k
__global__ void __launch_bounds__(256) c1_kernel(
    const unsigned short* __restrict__ fq, const float* __restrict__ kgp,
    float* __restrict__ c1A)
{
  int hq = blockIdx.x, part = blockIdx.y;
  __shared__ float bk[64];
  int t = threadIdx.x;
  if (t<64) bk[t] = kgp[hq*64+t]*(1.0f/512.0f);
  __syncthreads();
  int quad = t>>2, qq = t&3;
  int n = part*64 + quad;
  const unsigned short* row = &fq[((size_t)hq*SEQ + n)*DHD + qq*16];
  ushort8v a = *reinterpret_cast<const ushort8v*>(row);
  ushort8v b = *reinterpret_cast<const ushort8v*>(row+8);
  float s=0.f;
  #pragma unroll
  for (int i=0;i<8;i++) s = fmaf(bf2f(a[i]), bk[qq*16+i], s);
  #pragma unroll
  for (int i=0;i<8;i++) s = fmaf(bf2f(b[i]), bk[qq*16+8+i], s);
  s += __shfl_xor(s,1,64);
  s += __shfl_xor(s,2,64);
  if (qq==0) c1A[hq*SEQ+n] = s;
}

// ---------------------------------------------------------------- M1: moment pass (MFMA)
__global__ void __launch_bounds__(256) score_m1_kernel(
    const unsigned short* __restrict__ fq, const unsigned short* __restrict__ fk,
    const float* __restrict__ aqA, const float* __restrict__ c1A,
    const float* __restrict__ i1qA, const float* __restrict__ i2qA,
    const float* __restrict__ rskA, const float* __restrict__ i1kA, const float* __restrict__ i2kA,
    const float* __restrict__ c2A,
    float* __restrict__ rs_part, float* __restrict__ mom_part)
{
  int strip = blockIdx.x, q_=blockIdx.y, h=blockIdx.z;
  int hq = h*QB+q_;
  int n0 = strip*128;
  const unsigned short* Fq = fq + (size_t)hq*SEQ*DHD;
  const unsigned short* Fk = fk + (size_t)hq*SEQ*DHD;
  __shared__ unsigned short KT[128*64];
  __shared__ float kdL[128], i1kL[128], i2kL[128];
  __shared__ float aqL[128], c1L[128], i1qL[128], i2qL[128];
  __shared__ float red[256];
  int t=threadIdx.x, w=t>>6, lane=t&63, l16=lane&15, lh=lane>>4;
  float c2v = c2A[hq];
  if (t<128){
    aqL[t]=aqA[hq*SEQ+n0+t]; c1L[t]=c1A[hq*SEQ+n0+t];
    i1qL[t]=i1qA[hq*SEQ+n0+t]; i2qL[t]=i2qA[hq*SEQ+n0+t];
  }
  short8 qa[2][2];
  #pragma unroll
  for (int rf=0;rf<2;rf++){
    int ng = n0 + w*32 + rf*16 + l16;
    #pragma unroll
    for (int ks=0;ks<2;ks++)
      qa[rf][ks] = *reinterpret_cast<const short8*>(&Fq[(size_t)ng*DHD + ks*32 + lh*8]);
  }
  float sc=0,sc2=0,so=0,so2=0,sco=0;
  float rcs[8]={0,0,0,0,0,0,0,0}, rco[8]={0,0,0,0,0,0,0,0}, rcm[8]={0,0,0,0,0,0,0,0};
  for (int mc=0;mc<4;mc++){
    int m0=mc*128;
    __syncthreads();
    for (int it=0;it<4;++it){
      int idx=it*256+t,row=idx>>3,qc=idx&7;
      ushort8v vv = *reinterpret_cast<const ushort8v*>(&Fk[(size_t)(m0+row)*DHD + qc*8]);
      tile_st16(KT,row,128,qc*16,vv);
    }
    if (t<128){
      kdL[t]=rskA[hq*SEQ+m0+t]-c2v;
      i1kL[t]=i1kA[hq*SEQ+m0+t];
      i2kL[t]=i2kA[hq*SEQ+m0+t];
    }
    __syncthreads();
    f32x4 acc[2][8];
    #pragma unroll
    for (int rf=0;rf<2;rf++){ for (int cf=0;cf<8;cf++) acc[rf][cf]=(f32x4){0.f,0.f,0.f,0.f}; }
    #pragma unroll
    for (int cf=0; cf<8; ++cf){
      #pragma unroll
      for (int ks=0; ks<2; ++ks){
        short8 b = frag_ld(KT, cf*16+l16, 128, lh*16+ks*64);
        acc[0][cf]=MFMA(qa[0][ks],b,acc[0][cf]);
        acc[1][cf]=MFMA(qa[1][ks],b,acc[1][cf]);
      }
    }
    #pragma unroll
    for (int rf=0;rf<2;rf++){
      #pragma unroll
      for (int reg=0;reg<4;reg++){
        int rl = w*32 + rf*16 + lh*4 + reg;
        float aqv=aqL[rl], c1v=c1L[rl], iq1=i1qL[rl], iq2=i2qL[rl];
        int s = rf*4+reg;
        #pragma unroll
        for (int cf=0;cf<8;cf++){
          int ml = cf*16 + l16;
          float S = acc[rf][cf][reg];
          float cosv = clampf(S*iq1*i1kL[ml], -0.99f, 0.99f);
          float covv = clampf((S - c1v - aqv*kdL[ml])*KCOV, -10.0f, 10.0f);
          float csv  = clampf(S*iq2*i2kL[ml], -0.99f, 0.99f);
          float marg = clampf(0.01f - csv, 0.0f, 2.0f);
          sc += cosv; sc2 = fmaf(cosv,cosv,sc2);
          so += covv; so2 = fmaf(covv,covv,so2);
          sco = fmaf(cosv,covv,sco);
          rcs[s]+=cosv; rco[s]+=covv; rcm[s]+=marg;
        }
      }
    }
  }
  #pragma unroll
  for (int m=1;m<16;m<<=1){
    #pragma unroll
    for (int s=0;s<8;s++){
      rcs[s]+=__shfl_xor(rcs[s],m,64);
      rco[s]+=__shfl_xor(rco[s],m,64);
      rcm[s]+=__shfl_xor(rcm[s],m,64);
    }
  }
  if (l16==0){
    #pragma unroll
    for (int s=0;s<8;s++){
      int rf=s>>2, reg=s&3;
      int n = n0 + w*32 + rf*16 + lh*4 + reg;
      size_t base=((size_t)hq*SEQ+n)*3;
      rs_part[base]=rcs[s]; rs_part[base+1]=rco[s]; rs_part[base+2]=rcm[s];
    }
  }
  float sums[5]={sc,sc2,so,so2,sco};
  for (int c=0;c<5;c++){
    __syncthreads();
    red[t]=sums[c]; __syncthreads();
    for (int o=128;o>0;o>>=1){ if (t<o) red[t]+=red[t+o]; __syncthreads(); }
    if (t==0) mom_part[(size_t)(hq*4+strip)*5 + c] = red[0];
  }
}

// ---------------------------------------------------------------- R: reduce row-partials
__device__ __forceinline__ double blockReduceD(double v, double* buf){
  int t = threadIdx.x;
  buf[t]=v; __syncthreads();
  for (int o=128;o>0;o>>=1){ if (t<o) buf[t]+=buf[t+o]; __syncthreads(); }
  double r = buf[0]; __syncthreads();
  return r;
}

__global__ void __launch_bounds__(256) rowred_kernel(
    const float* __restrict__ rs_part, double* __restrict__ hq_sums)
{
  int hq = blockIdx.x, t = threadIdx.x;
  double a0=0,a1=0,a2=0,a3=0;
  for (int n=t; n<SEQ; n+=256){
    size_t base = ((size_t)hq*SEQ + n)*3;
    float rc=rs_part[base], ro=rs_part[base+1], rm=rs_part[base+2];
    float mm = rm*(1.0f/512.0f);
    a0 += mm; a1 += (double)mm*mm; a2 += (double)mm*rc; a3 += (double)mm*ro;
  }
  __shared__ double dbuf[256];
  a0 = blockReduceD(a0,dbuf);
  a1 = blockReduceD(a1,dbuf);
  a2 = blockReduceD(a2,dbuf);
  a3 = blockReduceD(a3,dbuf);
  if (t==0){
    hq_sums[hq*4+0]=a0; hq_sums[hq*4+1]=a1; hq_sums[hq*4+2]=a2; hq_sums[hq*4+3]=a3;
  }
}

// ---------------------------------------------------------------- F: MLP + stds + mix params
__global__ void __launch_bounds__(256) finalize_kernel(
    const float* __restrict__ qgp, const float* __restrict__ kgp,
    const float* __restrict__ wp1w, const float* __restrict__ wp1b,
    const float* __restrict__ wplg, const float* __restrict__ wplb,
    const float* __restrict__ wp2w, const float* __restrict__ wp2b,
    const float* __restrict__ wp3w, const float* __restrict__ wp3b,
    const float* __restrict__ temp,
    const float* __restrict__ mom_part, const double* __restrict__ hq_sums,
    float* __restrict__ params)
{
  int t = threadIdx.x;
  __shared__ float feats[8][128];
  __shared__ float h1s[8][64];
  __shared__ float h2s[8][32];
  __shared__ float wts[8][3];
  __shared__ double Sh[8][9];
  for (int idx=t; idx<512; idx+=256){
    int h = idx>>6, d = idx&63;
    float s1=0, s2=0;
    for (int qq=0; qq<QB; qq++){ s1 += qgp[(h*QB+qq)*64+d]; s2 += kgp[(h*QB+qq)*64+d]; }
    feats[h][d]    = s1*(1.0f/8192.0f);
    feats[h][64+d] = s2*(1.0f/8192.0f);
  }
  __syncthreads();
  int w = t>>6, j = t&63;
  for (int pp=0; pp<2; pp++){
    int h = w + pp*4;
    float acc = wp1b[j];
    for (int k=0;k<128;k++) acc += feats[h][k]*wp1w[k*64+j];
    float s=acc, s2=acc*acc;
    #pragma unroll
    for (int m=32;m>0;m>>=1){ s+=__shfl_xor(s,m,64); s2+=__shfl_xor(s2,m,64); }
    float mean = s*(1.0f/64.0f);
    float var  = s2*(1.0f/64.0f) - mean*mean;
    float xh = (acc-mean)*rsqrtf(var+1e-5f)*wplg[j] + wplb[j];
    h1s[h][j] = fmaxf(xh, 0.0f);
  }
  __syncthreads();
  {
    int h = t>>5, j2 = t&31;
    float acc = wp2b[j2];
    for (int k=0;k<64;k++) acc += h1s[h][k]*wp2w[k*32+j2];
    h2s[h][j2] = fmaxf(acc, 0.0f);
  }
  __syncthreads();
  if (t<8){
    int h = t;
    float z[3] = {wp3b[0], wp3b[1], wp3b[2]};
    for (int k=0;k<32;k++){
      float hv = h2s[h][k];
      z[0]+=hv*wp3w[k*3]; z[1]+=hv*wp3w[k*3+1]; z[2]+=hv*wp3w[k*3+2];
    }
    float mx = fmaxf(z[0], fmaxf(z[1], z[2]));
    float e0=expf(z[0]-mx), e1=expf(z[1]-mx), e2=expf(z[2]-mx);
    float inv = 1.0f/(e0+e1+e2);
    float l0=e0*inv, l1=e1*inv, l2=e2*inv;
    float tv = temp[0]; tv = fminf(fmaxf(tv, 0.1f), 20.0f);
    float y0=l0/tv, y1=l1/tv, y2=l2/tv;
    float mx2 = fmaxf(y0, fmaxf(y1, y2));
    float f0=expf(y0-mx2), f1=expf(y1-mx2), f2=expf(y2-mx2);
    float inv2 = 1.0f/(f0+f1+f2);
    wts[h][0]=f0*inv2; wts[h][1]=f1*inv2; wts[h][2]=f2*inv2;
  }
  __syncthreads();
  if (t<40){
    int h = t/5, c = t%5;
    double s = 0;
    for (int b2=0; b2<64; b2++) s += (double)mom_part[(size_t)(h*64+b2)*5 + c];
    Sh[h][c] = s;
  }
  __syncthreads();
  if (t<32){
    int h = t>>2, c = t&3;
    double s = 0;
    for (int qq=0; qq<QB; qq++) s += hq_sums[(h*QB+qq)*4 + c];
    Sh[h][5+c] = s;
  }
  __syncthreads();
  if (t==0){
    const double Ntot = 33554432.0;
    double T1c=0,T2c=0,T1o=0,T2o=0,T1v=0,T2v=0;
    for (int h=0;h<8;h++){
      T1c+=Sh[h][0]; T2c+=Sh[h][1]; T1o+=Sh[h][2]; T2o+=Sh[h][3];
      T1v+=512.0*Sh[h][5]; T2v+=512.0*Sh[h][6];
    }
    double stdc = sqrt(fmax((T2c - T1c*T1c/Ntot)/(Ntot-1.0), 0.0));
    double stdo = sqrt(fmax((T2o - T1o*T1o/Ntot)/(Ntot-1.0), 0.0));
    double stdv = sqrt(fmax((T2v - T1v*T1v/Ntot)/(Ntot-1.0), 0.0));
    double ah[8], bh[8];
    double Sd1=0, Sd2=0;
    for (int h=0;h<8;h++){
      double a = (double)wts[h][0]/(stdc+1e-8);
      double b = (double)wts[h][1]*0.1/(stdo+1e-8);
      double c = (double)wts[h][2]*0.1/(stdv+1e-8);
      ah[h]=a; bh[h]=b;
      Sd1 += a*Sh[h][0] + b*Sh[h][2] + c*512.0*Sh[h][5];
      Sd2 += a*a*Sh[h][1] + b*b*Sh[h][3] + c*c*512.0*Sh[h][6]
           + 2.0*a*b*Sh[h][4] + 2.0*a*c*Sh[h][7] + 2.0*b*c*Sh[h][8];
    }
    double stdd = sqrt(fmax((Sd2 - Sd1*Sd1/Ntot)/(Ntot-1.0), 0.0));
    double att = 1.0 + 0.5*stdd;
    att = fmin(fmax(att, 0.5), 5.0);
    double scale = 1.0/att;
    for (int h=0;h<8;h++){
      params[h*2+0] = (float)(scale*ah[h]);
      params[h*2+1] = (float)(scale*bh[h]);
    }
  }
}

// ---------------------------------------------------------------- M2: logits + flash softmax + PV (MFMA)
__global__ void __launch_bounds__(256) attn_m2_kernel(
    const unsigned short* __restrict__ fq, const unsigned short* __restrict__ fk,
    const unsigned short* __restrict__ fvT,
    const float* __restrict__ aqA, const float* __restrict__ c1A, const float* __restrict__ i1qA,
    const float* __restrict__ rskA, const float* __restrict__ i1kA,
    const float* __restrict__ c2A, const float* __restrict__ params,
    unsigned short* __restrict__ attn_bf)
{
  int strip=blockIdx.x, q_=blockIdx.y, h=blockIdx.z;
  int hq=h*QB+q_, n0=strip*128;
  const unsigned short* Fq=fq+(size_t)hq*SEQ*DHD;
  const unsigned short* Fk=fk+(size_t)hq*SEQ*DHD;
  const unsigned short* FvT=fvT+(size_t)hq*DHD*SEQ;
  __shared__ unsigned short KT[128*64];     // aliased as P after barrier
  __shared__ unsigned short VT[64*128];     // [d][m], pitch 256B
  __shared__ float kdL[128], i1kL[128];
  __shared__ float aqL[128], c1L[128], i1qL[128];
  int t=threadIdx.x, w=t>>6, lane=t&63, l16=lane&15, lh=lane>>4;
  float c2v=c2A[hq];
  float pa=params[h*2], pb=params[h*2+1];
  if (t<128){
    aqL[t]=aqA[hq*SEQ+n0+t]; c1L[t]=c1A[hq*SEQ+n0+t]; i1qL[t]=i1qA[hq*SEQ+n0+t];
  }
  short8 qa[2][2];
  #pragma unroll
  for (int rf=0;rf<2;rf++){
    int ng = n0 + w*32 + rf*16 + l16;
    #pragma unroll
    for (int ks=0;ks<2;ks++)
      qa[rf][ks] = *reinterpret_cast<const short8*>(&Fq[(size_t)ng*DHD + ks*32 + lh*8]);
  }
  f32x4 accO[2][4];
  #pragma unroll
  for (int rf=0;rf<2;rf++){ for (int j=0;j<4;j++) accO[rf][j]=(f32x4){0.f,0.f,0.f,0.f}; }
  float Mr[8], Dr[8];
  #pragma unroll
  for (int s=0;s<8;s++){ Mr[s]=-3.0e38f; Dr[s]=0.f; }
  for (int mc=0;mc<4;mc++){
    int m0=mc*128;
    __syncthreads();
    for (int it=0;it<4;++it){
      int idx=it*256+t,row=idx>>3,qc=idx&7;
      ushort8v vv = *reinterpret_cast<const ushort8v*>(&Fk[(size_t)(m0+row)*DHD + qc*8]);
      tile_st16(KT,row,128,qc*16,vv);
    }
    for (int it=0;it<4;++it){
      int idx=it*256+t, dd=idx>>4, c=idx&15;
      ushort8v vv=*reinterpret_cast<const ushort8v*>(&FvT[(size_t)dd*SEQ + m0 + c*8]);
      tile_st16(VT, dd, 256, c*16, vv);
    }
    if (t<128){ kdL[t]=rskA[hq*SEQ+m0+t]-c2v; i1kL[t]=i1kA[hq*SEQ+m0+t]; }
    __syncthreads();
    f32x4 acc[2][8];
    #pragma unroll
    for (int rf=0;rf<2;rf++){ for (int cf=0;cf<8;cf++) acc[rf][cf]=(f32x4){0.f,0.f,0.f,0.f}; }
    #pragma unroll
    for (int cf=0; cf<8; ++cf){
      #pragma unroll
      for (int ks=0; ks<2; ++ks){
        short8 b = frag_ld(KT, cf*16+l16, 128, lh*16+ks*64);
        acc[0][cf]=MFMA(qa[0][ks],b,acc[0][cf]);
        acc[1][cf]=MFMA(qa[1][ks],b,acc[1][cf]);
      }
    }
    // transform to mixed logits
    #pragma unroll
    for (int rf=0;rf<2;rf++){
      #pragma unroll
      for (int reg=0;reg<4;reg++){
        int rl = w*32 + rf*16 + lh*4 + reg;
        float aqv=aqL[rl], c1v=c1L[rl], iq1=i1qL[rl];
        #pragma unroll
        for (int cf=0;cf<8;cf++){
          int ml = cf*16 + l16;
          float S = acc[rf][cf][reg];
          float cosv = clampf(S*iq1*i1kL[ml], -0.99f, 0.99f);
          float covv = clampf((S - c1v - aqv*kdL[ml])*KCOV, -10.0f, 10.0f);
          acc[rf][cf][reg] = pa*cosv + pb*covv;
        }
      }
    }
    // flash update
    float Fsc[8];
    #pragma unroll
    for (int rf=0;rf<2;rf++){
      #pragma unroll
      for (int reg=0;reg<4;reg++){
        int s=rf*4+reg;
        float mx=acc[rf][0][reg];
        #pragma unroll
        for (int cf=1;cf<8;cf++) mx=fmaxf(mx,acc[rf][cf][reg]);
        #pragma unroll
        for (int m=1;m<16;m<<=1) mx=fmaxf(mx,__shfl_xor(mx,m,64));
        float Mn=fmaxf(Mr[s],mx);
        Fsc[s]=__expf(Mr[s]-Mn);
        Mr[s]=Mn;
        float ps=0.f;
        #pragma unroll
        for (int cf=0;cf<8;cf++){
          float e=__expf(acc[rf][cf][reg]-Mn);
          acc[rf][cf][reg]=e; ps+=e;
        }
        #pragma unroll
        for (int m=1;m<16;m<<=1) ps+=__shfl_xor(ps,m,64);
        Dr[s]=Dr[s]*Fsc[s]+ps;
      }
    }
    #pragma unroll
    for (int rf=0;rf<2;rf++){
      #pragma unroll
      for (int j=0;j<4;j++){
        #pragma unroll
        for (int reg=0;reg<4;reg++) accO[rf][j][reg]*=Fsc[rf*4+reg];
      }
    }
    __syncthreads();   // all waves done reading KT -> safe to alias as P
    unsigned short* P = KT;
    #pragma unroll
    for (int mh=0;mh<2;mh++){
      #pragma unroll
      for (int rf=0;rf<2;rf++){
        #pragma unroll
        for (int reg=0;reg<4;reg++){
          int prow = w*32 + rf*16 + lh*4 + reg;
          #pragma unroll
          for (int cfl=0; cfl<4; ++cfl){
            int addr = prow*128 + (((cfl*16+l16)*2) ^ ((prow&7)<<4));
            *reinterpret_cast<unsigned short*>(reinterpret_cast<char*>(P) + addr)
              = f2bf(acc[rf][mh*4+cfl][reg]);
          }
        }
      }
      #pragma unroll
      for (int ks=0;ks<2;ks++){
        int kb = lh*16 + ks*64;
        short8 pA[2];
        #pragma unroll
        for (int rf=0;rf<2;rf++) pA[rf]=frag_ld(P, w*32+rf*16+l16, 128, kb);
        short8 vB[4];
        #pragma unroll
        for (int dcf=0;dcf<4;dcf++) vB[dcf]=frag_ld(VT, dcf*16+l16, 256, mh*128 + kb);
        #pragma unroll
        for (int rf=0;rf<2;rf++){
          #pragma unroll
          for (int dcf=0;dcf<4;dcf++) accO[rf][dcf]=MFMA(pA[rf],vB[dcf],accO[rf][dcf]);
        }
      }
    }
  }
  // epilogue: normalize, bounce own 32x64 tile through LDS, coalesced store
  float invD[8];
  #pragma unroll
  for (int s=0;s<8;s++) invD[s]=1.0f/Dr[s];
  unsigned short* P = KT;
  #pragma unroll
  for (int rf=0;rf<2;rf++){
    #pragma unroll
    for (int dcf=0;dcf<4;dcf++){
      #pragma unroll
      for (int reg=0;reg<4;reg++){
        int prow = w*32 + rf*16 + lh*4 + reg;
        int addr = prow*128 + (((dcf*16+l16)*2) ^ ((prow&7)<<4));
        *reinterpret_cast<unsigned short*>(reinterpret_cast<char*>(P) + addr)
          = f2bf(accO[rf][dcf][reg]*invD[rf*4+reg]);
      }
    }
  }
  for (int it=0; it<4; ++it){
    int idx = it*64 + lane;
    int row = idx>>3, c = idx&7;
    int prow = w*32 + row;
    int addr = prow*128 + ((c*16) ^ ((prow&7)<<4));
    ushort8v vv = *reinterpret_cast<ushort8v*>(reinterpret_cast<char*>(P) + addr);
    *reinterpret_cast<ushort8v*>(
      &attn_bf[(size_t)(q_*SEQ + n0 + w*32 + row)*DMODEL + h*DHD + c*8]) = vv;
  }
}

// ---------------------------------------------------------------- KO: output projection (MFMA)
__global__ void __launch_bounds__(256) out_mfma_kernel(
    const unsigned short* __restrict__ attn_bf, const unsigned short* __restrict__ WoT,
    const float* __restrict__ bias, float* __restrict__ out)
{
  int r0=blockIdx.x*128;  // m rows
  int c0=blockIdx.y*128;  // out cols
  __shared__ unsigned short AT[128*64];
  __shared__ unsigned short WT[128*64];
  int t=threadIdx.x, w=t>>6, lane=t&63, l16=lane&15, lh=lane>>4;
  f32x4 acc[4][4];
  #pragma unroll
  for(int i=0;i<4;i++){ for(int j=0;j<4;j++) acc[i][j]=(f32x4){0.f,0.f,0.f,0.f}; }
  for (int k0=0;k0<DMODEL;k0+=64){
    __syncthreads();
    for (int it=0; it<4; ++it){
      int idx=it*256+t, row=idx>>3, q=idx&7;
      ushort8v v = *reinterpret_cast<const ushort8v*>(&attn_bf[(size_t)(r0+row)*DMODEL + k0 + q*8]);
      tile_st16(AT, row, 128, q*16, v);
    }
    for (int it=0; it<4; ++it){
      int idx=it*256+t, row=idx>>3, q=idx&7;
      ushort8v v = *reinterpret_cast<const ushort8v*>(&WoT[(size_t)(c0+row)*DMODEL + k0 + q*8]);
      tile_st16(WT, row, 128, q*16, v);
    }
    __syncthreads();
    int nr=(w&1)*64, mr=(w>>1)*64;
    #pragma unroll
    for (int ks=0; ks<2; ++ks){
      int kb = lh*16 + ks*64;
      short8 a[4], b[4];
      #pragma unroll
      for (int i=0;i<4;i++) a[i] = frag_ld(WT, nr+i*16+l16, 128, kb);
      #pragma unroll
      for (int j=0;j<4;j++) b[j] = frag_ld(AT, mr+j*16+l16, 128, kb);
      #pragma unroll
      for (int i=0;i<4;i++){
        #pragma unroll
        for (int j=0;j<4;j++) acc[i][j]=MFMA(a[i],b[j],acc[i][j]);
      }
    }
  }
  #pragma unroll
  for (int i=0;i<4;i++){
    int nb = c0+(w&1)*64+i*16+lh*4;
    float4 b4 = *reinterpret_cast<const float4*>(&bias[nb]);
    #pragma unroll
    for (int j=0;j<4;j++){
      int mg = r0+(w>>1)*64+j*16+l16;
      f32x4 o = acc[i][j];
      o[0]+=b4.x; o[1]+=b4.y; o[2]+=b4.z; o[3]+=b4.w;
      *reinterpret_cast<f32x4*>(&out[(size_t)mg*DMODEL + nb]) = o;
    }
  }
}

// ----------------------------------------------------------------
extern "C" void kernel_launch(void* const* d_in, const int* in_sizes, int n_in,
                              void* d_out, int out_size, void* d_ws, size_t ws_size,
                              hipStream_t stream)
{
  (void)in_sizes; (void)n_in; (void)out_size; (void)ws_size;
  const float* q     = (const float*)d_in[0];
  const float* k     = (const float*)d_in[1];
  const float* v     = (const float*)d_in[2];
  const float* ln_g  = (const float*)d_in[3];
  const float* ln_b  = (const float*)d_in[4];
  const float* W_in  = (const float*)d_in[5];
  const float* wp1w  = (const float*)d_in[6];
  const float* wp1b  = (const float*)d_in[7];
  const float* wplg  = (const float*)d_in[8];
  const float* wplb  = (const float*)d_in[9];
  const float* wp2w  = (const float*)d_in[10];
  const float* wp2b  = (const float*)d_in[11];
  const float* wp3w  = (const float*)d_in[12];
  const float* wp3b  = (const float*)d_in[13];
  const float* temp  = (const float*)d_in[14];
  const float* W_out = (const float*)d_in[15];
  const float* b_out = (const float*)d_in[16];
  float* out = (float*)d_out;

  char* wsb = (char*)d_ws;
  size_t off = 0;
  auto alloc = [&](size_t bytes)->char*{
    char* p = wsb + off; off += (bytes + 255) & ~(size_t)255; return p;
  };
  unsigned short* fq_b   = (unsigned short*)alloc((size_t)NHQ*SEQ*DHD*2);
  unsigned short* fk_b   = (unsigned short*)alloc((size_t)NHQ*SEQ*DHD*2);
  unsigned short* fvT_b  = (unsigned short*)alloc((size_t)NHQ*SEQ*DHD*2);
  unsigned short* attn_b = (unsigned short*)alloc((size_t)NROWS*DMODEL*2);
  unsigned short* WiT    = (unsigned short*)alloc((size_t)DMODEL*DMODEL*2);
  unsigned short* WoT    = (unsigned short*)alloc((size_t)DMODEL*DMODEL*2);
  float* mu    = (float*)alloc(3*NROWS*4);
  float* rstd  = (float*)alloc(3*NROWS*4);
  float* aqA   = (float*)alloc(NHQ*SEQ*4);
  float* c1A   = (float*)alloc(NHQ*SEQ*4);
  float* i1qA  = (float*)alloc(NHQ*SEQ*4);
  float* i2qA  = (float*)alloc(NHQ*SEQ*4);
  float* rskA  = (float*)alloc(NHQ*SEQ*4);
  float* i1kA  = (float*)alloc(NHQ*SEQ*4);
  float* i2kA  = (float*)alloc(NHQ*SEQ*4);
  float* c2A   = (float*)alloc(NHQ*4);
  float* qgp   = (float*)alloc(NHQ*64*4);
  float* kgp   = (float*)alloc(NHQ*64*4);
  float* colpart  = (float*)alloc((size_t)2*NHQ*4*64*4);
  float* rs_part  = (float*)alloc((size_t)NHQ*SEQ*3*4);
  float* mom_part = (float*)alloc(512*5*4);
  float* params   = (float*)alloc(64);
  double* hq_sums = (double*)alloc(NHQ*4*8);

  ln_stats_kernel<<<dim3(NROWS/4, 3), 256, 0, stream>>>(q, k, v, mu, rstd);
  convert_w_kernel<<<dim3(8,8,2), 256, 0, stream>>>(W_in, W_out, WiT, WoT);
  proj_mfma_kernel<<<dim3(64,4,3), 256, 0, stream>>>(q, k, v, ln_g, ln_b, WiT, mu, rstd,
                                                     fq_b, fk_b, fvT_b);
  rowstats_kernel<<<dim3(NHQ, SEQ/64, 2), 256, 0, stream>>>(fq_b, fk_b, aqA, i1qA, i2qA,
                                                            rskA, i1kA, i2kA);
  colsum_kernel<<<dim3(NHQ, 4, 2), 256, 0, stream>>>(fq_b, fk_b, colpart);
  colreduce_kernel<<<dim3(NHQ), 64, 0, stream>>>(colpart, qgp, kgp, c2A);
  c1_kernel<<<dim3(NHQ, SEQ/64), 256, 0, stream>>>(fq_b, kgp, c1A);
  score_m1_kernel<<<dim3(4, QB, NH), 256, 0, stream>>>(fq_b, fk_b, aqA, c1A, i1qA, i2qA,
                                                       rskA, i1kA, i2kA, c2A, rs_part, mom_part);
  rowred_kernel<<<dim3(NHQ), 256, 0, stream>>>(rs_part, hq_sums);
  finalize_kernel<<<1, 256, 0, stream>>>(qgp, kgp, wp1w, wp1b, wplg, wplb, wp2w, wp2b,
                                         wp3w, wp3b, temp, mom_part, hq_sums, params);
  attn_m2_kernel<<<dim3(4, QB, NH), 256, 0, stream>>>(fq_b, fk_b, fvT_b, aqA, c1A, i1qA,
                                                      rskA, i1kA, c2A, params, attn_b);
  out_mfma_kernel<<<dim3(64,4), 256, 0, stream>>>(attn_b, WoT, b_out, out);
}

// Round 4
// 173.859 us; speedup vs baseline: 4.4227x; 1.0109x over previous
//
#include <hip/hip_runtime.h>
#include <math.h>

#define NH 8
#define DHD 64
#define DMODEL 512
#define QB 16
#define SEQ 512
#define NROWS (QB*SEQ)      /* 8192 rows per input */
#define NHQ (NH*QB)         /* 128 (h,q) pairs */
#define KCOV ((float)((0.001/512.0)/(8.0+1e-8)))

typedef __attribute__((ext_vector_type(8))) short short8;      // 8 bf16 -> 4 VGPR
typedef __attribute__((ext_vector_type(8))) unsigned short ushort8v;
typedef __attribute__((ext_vector_type(4))) unsigned short ushort4v;
typedef __attribute__((ext_vector_type(4))) float f32x4;

__device__ __forceinline__ float bf2f(unsigned short u){
  union { unsigned int i; float f; } c; c.i = ((unsigned int)u)<<16; return c.f;
}
__device__ __forceinline__ unsigned short f2bf(float f){
  union { float f; unsigned int i; } c; c.f = f;
  unsigned int u = c.i;
  u += 0x7fffu + ((u>>16)&1u);   // RNE
  return (unsigned short)(u>>16);
}
__device__ __forceinline__ unsigned cvtpk(float a, float b){
  unsigned r; asm("v_cvt_pk_bf16_f32 %0, %1, %2" : "=v"(r) : "v"(a), "v"(b)); return r;
}
__device__ __forceinline__ float clampf(float x, float lo, float hi){ return fminf(fmaxf(x,lo),hi); }

__device__ __forceinline__ f32x4 MFMA(short8 a, short8 b, f32x4 c){
  return __builtin_amdgcn_mfma_f32_16x16x32_bf16(a, b, c, 0, 0, 0);
}
// swizzled-tile access: element (row, kbyte), rowbytes pitch, XOR-swizzle bits 4-6 by row&7
__device__ __forceinline__ short8 frag_ld(const unsigned short* T, int row, int rowbytes, int kbyte){
  int addr = row*rowbytes + (kbyte ^ ((row&7)<<4));
  return *reinterpret_cast<const short8*>(reinterpret_cast<const char*>(T) + addr);
}
__device__ __forceinline__ void tile_st16(unsigned short* T, int row, int rowbytes, int kbyte, ushort8v v){
  int addr = row*rowbytes + (kbyte ^ ((row&7)<<4));
  *reinterpret_cast<ushort8v*>(reinterpret_cast<char*>(T) + addr) = v;
}
__device__ __forceinline__ void tile_st8(unsigned short* T, int row, int rowbytes, int kbyte, ushort4v v){
  int addr = row*rowbytes + (kbyte ^ ((row&7)<<4));
  *reinterpret_cast<ushort4v*>(reinterpret_cast<char*>(T) + addr) = v;
}

// ---------------------------------------------------------------- P0: LN row stats + weight convert (fused)
__global__ void __launch_bounds__(256) prep_kernel(
    const float* __restrict__ xq, const float* __restrict__ xk, const float* __restrict__ xv,
    const float* __restrict__ Wi, const float* __restrict__ Wo,
    float* __restrict__ mu, float* __restrict__ rstd,
    unsigned short* __restrict__ WiT, unsigned short* __restrict__ WoT)
{
  __shared__ float T[64][68];
  int b = blockIdx.x, t = threadIdx.x;
  if (b < 6144){
    int which = b >> 11, rowblk = b & 2047;
    const float* src = which==0 ? xq : (which==1 ? xk : xv);
    int w = t >> 6, lane = t & 63;
    int row = rowblk*4 + w;
    const float* x = src + (size_t)row*DMODEL;
    float4 v1 = *reinterpret_cast<const float4*>(&x[lane*8]);
    float4 v2 = *reinterpret_cast<const float4*>(&x[lane*8+4]);
    float s  = v1.x+v1.y+v1.z+v1.w + v2.x+v2.y+v2.z+v2.w;
    float ss = v1.x*v1.x+v1.y*v1.y+v1.z*v1.z+v1.w*v1.w
             + v2.x*v2.x+v2.y*v2.y+v2.z*v2.z+v2.w*v2.w;
    #pragma unroll
    for (int m=32; m>0; m>>=1){ s += __shfl_xor(s,m,64); ss += __shfl_xor(ss,m,64); }
    if (lane==0){
      float m_ = s*(1.0f/DMODEL);
      float var = ss*(1.0f/DMODEL) - m_*m_;
      mu[(size_t)which*NROWS + row]   = m_;
      rstd[(size_t)which*NROWS + row] = rsqrtf(var + 1e-5f);
    }
  } else {
    int wb = b - 6144;
    const float* src = (wb>=64) ? Wo : Wi;
    unsigned short* dst = (wb>=64) ? WoT : WiT;
    int rc = wb & 63;
    int r0 = (rc>>3)*64, c0 = (rc&7)*64;
    for (int it=0; it<4; ++it){
      int idx = it*256+t, row = idx>>4, q = idx&15;
      float4 v = *reinterpret_cast<const float4*>(&src[(size_t)(r0+row)*DMODEL + c0 + q*4]);
      T[row][q*4+0]=v.x; T[row][q*4+1]=v.y; T[row][q*4+2]=v.z; T[row][q*4+3]=v.w;
    }
    __syncthreads();
    for (int it=0; it<4; ++it){
      int idx = it*256+t, oc = idx>>4, q = idx&15;
      ushort4v o;
      o[0]=f2bf(T[q*4+0][oc]); o[1]=f2bf(T[q*4+1][oc]);
      o[2]=f2bf(T[q*4+2][oc]); o[3]=f2bf(T[q*4+3][oc]);
      *reinterpret_cast<ushort4v*>(&dst[(size_t)(c0+oc)*DMODEL + r0 + q*4]) = o;
    }
  }
}

// ---------------------------------------------------------------- K1b: LN-fused projection (MFMA) + row stats
__global__ void __launch_bounds__(256) proj_mfma_kernel(
    const float* __restrict__ xq, const float* __restrict__ xk, const float* __restrict__ xv,
    const float* __restrict__ g, const float* __restrict__ bb,
    const unsigned short* __restrict__ WiT,
    const float* __restrict__ mu, const float* __restrict__ rstd,
    unsigned short* __restrict__ fq, unsigned short* __restrict__ fk, unsigned short* __restrict__ fvT,
    float* __restrict__ aqA, float* __restrict__ i1qA,
    float* __restrict__ rskA, float* __restrict__ i1kA)
{
  int which = blockIdx.z;
  const float* src = which==0?xq:(which==1?xk:xv);
  int r0 = blockIdx.x*128;   // x rows (n-dim)
  int c0 = blockIdx.y*128;   // output cols (head*64+d dim)
  __shared__ unsigned short XT[128*64];
  __shared__ unsigned short WT[128*64];
  __shared__ float gs[DMODEL], bs[DMODEL], mus[128], rss[128];
  int t = threadIdx.x;
  for (int i=t;i<DMODEL;i+=256){ gs[i]=g[i]; bs[i]=bb[i]; }
  if (t<128){ mus[t]=mu[(size_t)which*NROWS+r0+t]; rss[t]=rstd[(size_t)which*NROWS+r0+t]; }
  int w=t>>6, lane=t&63, l16=lane&15, lh=lane>>4;
  f32x4 acc[4][4];
  #pragma unroll
  for(int i=0;i<4;i++){ for(int j=0;j<4;j++) acc[i][j]=(f32x4){0.f,0.f,0.f,0.f}; }
  for (int k0=0;k0<DMODEL;k0+=64){
    __syncthreads();
    for (int it=0; it<8; ++it){
      int idx=it*256+t, row=idx>>4, q=idx&15;
      float4 x4 = *reinterpret_cast<const float4*>(&src[(size_t)(r0+row)*DMODEL + k0 + q*4]);
      float m_=mus[row], rs_=rss[row];
      const float* g4=&gs[k0+q*4]; const float* b4=&bs[k0+q*4];
      ushort4v o;
      o[0]=f2bf((x4.x-m_)*rs_*g4[0]+b4[0]);
      o[1]=f2bf((x4.y-m_)*rs_*g4[1]+b4[1]);
      o[2]=f2bf((x4.z-m_)*rs_*g4[2]+b4[2]);
      o[3]=f2bf((x4.w-m_)*rs_*g4[3]+b4[3]);
      tile_st8(XT, row, 128, q*8, o);
    }
    for (int it=0; it<4; ++it){
      int idx=it*256+t, row=idx>>3, q=idx&7;
      ushort8v v = *reinterpret_cast<const ushort8v*>(&WiT[(size_t)(c0+row)*DMODEL + k0 + q*8]);
      tile_st16(WT, row, 128, q*16, v);
    }
    __syncthreads();
    if (which<2){
      int dr=(w&1)*64, nc=(w>>1)*64;
      #pragma unroll
      for (int ks=0; ks<2; ++ks){
        int kb = lh*16 + ks*64;
        short8 a[4], b[4];
        #pragma unroll
        for (int i=0;i<4;i++) a[i] = frag_ld(WT, dr+i*16+l16, 128, kb);
        #pragma unroll
        for (int j=0;j<4;j++) b[j] = frag_ld(XT, nc+j*16+l16, 128, kb);
        #pragma unroll
        for (int i=0;i<4;i++){
          #pragma unroll
          for (int j=0;j<4;j++) acc[i][j]=MFMA(a[i],b[j],acc[i][j]);
        }
      }
    } else {
      int nr=(w>>1)*64, dc=(w&1)*64;
      #pragma unroll
      for (int ks=0; ks<2; ++ks){
        int kb = lh*16 + ks*64;
        short8 a[4], b[4];
        #pragma unroll
        for (int i=0;i<4;i++) a[i] = frag_ld(XT, nr+i*16+l16, 128, kb);
        #pragma unroll
        for (int j=0;j<4;j++) b[j] = frag_ld(WT, dc+j*16+l16, 128, kb);
        #pragma unroll
        for (int i=0;i<4;i++){
          #pragma unroll
          for (int j=0;j<4;j++) acc[i][j]=MFMA(a[i],b[j],acc[i][j]);
        }
      }
    }
  }
  if (which<2){
    unsigned short* dst = which ? fk : fq;
    int dr=(w&1)*64, nc=(w>>1)*64;
    #pragma unroll
    for (int i=0;i<4;i++){
      #pragma unroll
      for (int j=0;j<4;j++){
        int cl = c0 + dr + i*16 + lh*4;
        int ng = r0 + nc + j*16 + l16;
        int head = cl>>6, dd = cl&63;
        int hq = head*QB + (ng>>9);
        int n = ng&511;
        ushort4v o;
        o[0]=f2bf(acc[i][j][0]); o[1]=f2bf(acc[i][j][1]);
        o[2]=f2bf(acc[i][j][2]); o[3]=f2bf(acc[i][j][3]);
        *reinterpret_cast<ushort4v*>(&dst[((size_t)hq*SEQ+n)*DHD + dd]) = o;
      }
    }
    // fused row stats: sum_d f, sum_d f^2 for this wave's head
    int head = (c0>>6) + (w&1);
    #pragma unroll
    for (int j=0;j<4;j++){
      float s=0.f, ss=0.f;
      #pragma unroll
      for (int i=0;i<4;i++){
        #pragma unroll
        for (int r=0;r<4;r++){ float x = acc[i][j][r]; s += x; ss = fmaf(x,x,ss); }
      }
      s += __shfl_xor(s,16,64); ss += __shfl_xor(ss,16,64);
      s += __shfl_xor(s,32,64); ss += __shfl_xor(ss,32,64);
      if (lh==0){
        int ng = r0 + nc + j*16 + l16;
        int hq = head*QB + (ng>>9);
        int n = ng&511;
        float nrm = sqrtf(ss);
        if (which==0){
          aqA[hq*SEQ+n]  = s*(1.0f/64.0f);
          i1qA[hq*SEQ+n] = 1.0f/(nrm+1e-8f);
        } else {
          rskA[hq*SEQ+n] = s;
          i1kA[hq*SEQ+n] = 1.0f/(nrm+1e-8f);
        }
      }
    }
  } else {
    int nr=(w>>1)*64, dc=(w&1)*64;
    #pragma unroll
    for (int i=0;i<4;i++){
      #pragma unroll
      for (int j=0;j<4;j++){
        int ngb = r0 + nr + i*16 + lh*4;
        int dg  = c0 + dc + j*16 + l16;
        int head = dg>>6, dd = dg&63;
        int hq = head*QB + (ngb>>9);
        int n = ngb&511;
        ushort4v o;
        o[0]=f2bf(acc[i][j][0]); o[1]=f2bf(acc[i][j][1]);
        o[2]=f2bf(acc[i][j][2]); o[3]=f2bf(acc[i][j][3]);
        *reinterpret_cast<ushort4v*>(&fvT[((size_t)hq*DHD+dd)*SEQ + n]) = o;
      }
    }
  }
}

// ---------------------------------------------------------------- S2: column-sum partials
// colpart[isk][hq][quarter][64]
__global__ void __launch_bounds__(256) colsum_kernel(
    const unsigned short* __restrict__ fq, const unsigned short* __restrict__ fk,
    float* __restrict__ colpart)
{
  int hq = blockIdx.x, quarter = blockIdx.y, isk = blockIdx.z;
  const unsigned short* F = (isk ? fk : fq) + (size_t)hq*SEQ*DHD;
  int t = threadIdx.x, g = t&15, rg = t>>4;
  float acc0=0.f, acc1=0.f, acc2=0.f, acc3=0.f;
  #pragma unroll
  for (int i=0;i<8;i++){
    int r = quarter*128 + rg + 16*i;
    ushort4v v = *reinterpret_cast<const ushort4v*>(&F[(size_t)r*DHD + g*4]);
    acc0+=bf2f(v[0]); acc1+=bf2f(v[1]); acc2+=bf2f(v[2]); acc3+=bf2f(v[3]);
  }
  __shared__ float sh[16][68];
  sh[rg][g*4+0]=acc0; sh[rg][g*4+1]=acc1; sh[rg][g*4+2]=acc2; sh[rg][g*4+3]=acc3;
  __syncthreads();
  if (t<64){
    float s=0.f;
    #pragma unroll
    for (int r=0;r<16;r++) s += sh[r][t];
    colpart[(((size_t)isk*NHQ + hq)*4 + quarter)*64 + t] = s;
  }
}

// ---------------------------------------------------------------- S3: combine colsums -> qgp,kgp,c2
__global__ void __launch_bounds__(64) colreduce_kernel(
    const float* __restrict__ colpart,
    float* __restrict__ qgp, float* __restrict__ kgp, float* __restrict__ c2A)
{
  int hq = blockIdx.x, d = threadIdx.x;
  float sq=0.f, sk=0.f;
  #pragma unroll
  for (int qu=0;qu<4;qu++){
    sq += colpart[(((size_t)0*NHQ + hq)*4 + qu)*64 + d];
    sk += colpart[(((size_t)1*NHQ + hq)*4 + qu)*64 + d];
  }
  qgp[hq*64+d]=sq; kgp[hq*64+d]=sk;
  float c = sk*(1.0f/512.0f);
  #pragma unroll
  for (int m=32;m>0;m>>=1) c += __shfl_xor(c,m,64);
  if (d==0) c2A[hq]=c;
}

// ---------------------------------------------------------------- M1: moments + rowmax + c1 (swapped-QK MFMA)
__global__ void __launch_bounds__(256) score_m1_kernel(
    const unsigned short* __restrict__ fq, const unsigned short* __restrict__ fk,
    const float* __restrict__ aqA, const float* __restrict__ i1qA,
    const float* __restrict__ rskA, const float* __restrict__ i1kA,
    const float* __restrict__ c2A, const float* __restrict__ kgp,
    float* __restrict__ c1A, float* __restrict__ rmaxcA, float* __restrict__ rmaxoA,
    float* __restrict__ momf, double* __restrict__ varp)
{
  int strip=blockIdx.x, q_=blockIdx.y, h=blockIdx.z;
  int hq=h*QB+q_, n0=strip*64;
  const unsigned short* Fq=fq+(size_t)hq*SEQ*DHD;
  const unsigned short* Fk=fk+(size_t)hq*SEQ*DHD;
  __shared__ unsigned short KT[128*64];
  __shared__ float red[256];
  __shared__ double dred[256];
  int t=threadIdx.x, w=t>>6, lane=t&63, l16=lane&15, lh=lane>>4;
  int n = n0 + w*16 + l16;
  float c2v = c2A[hq];
  float aqv = aqA[hq*SEQ+n];
  float iq1 = i1qA[hq*SEQ+n];
  short8 qa[2];
  #pragma unroll
  for (int ks=0;ks<2;ks++)
    qa[ks] = *reinterpret_cast<const short8*>(&Fq[(size_t)n*DHD + ks*32 + lh*8]);
  // c1[n] = fq[n] . (kgp/512)
  float c1v = 0.f;
  #pragma unroll
  for (int ks=0;ks<2;ks++){
    const float* bkp = &kgp[hq*64 + ks*32 + lh*8];
    float4 b0 = *reinterpret_cast<const float4*>(bkp);
    float4 b1 = *reinterpret_cast<const float4*>(bkp+4);
    float bb[8] = {b0.x,b0.y,b0.z,b0.w,b1.x,b1.y,b1.z,b1.w};
    #pragma unroll
    for (int i=0;i<8;i++) c1v = fmaf(bf2f((unsigned short)qa[ks][i]), bb[i], c1v);
  }
  c1v *= (1.0f/512.0f);
  c1v += __shfl_xor(c1v,16,64);
  c1v += __shfl_xor(c1v,32,64);
  if (lane<16) c1A[hq*SEQ+n] = c1v;
  float c1x = KCOV*(c1v - aqv*c2v);
  float aqx = KCOV*aqv;
  float sc=0.f,sc2=0.f,so=0.f,so2=0.f,sco=0.f;
  float rc=0.f, ro=0.f, rm=0.f, rmc=-1e30f, rmo=-1e30f;
  for (int mc=0;mc<4;mc++){
    int m0=mc*128;
    __syncthreads();
    for (int it=0;it<4;++it){
      int idx=it*256+t, row=idx>>3, qc=idx&7;
      ushort8v vv = *reinterpret_cast<const ushort8v*>(&Fk[(size_t)(m0+row)*DHD + qc*8]);
      tile_st16(KT,row,128,qc*16,vv);
    }
    __syncthreads();
    #pragma unroll
    for (int mh=0;mh<2;mh++){
      int mb = mh*64;
      f32x4 acc[4];
      #pragma unroll
      for (int mf=0;mf<4;mf++) acc[mf]=(f32x4){0.f,0.f,0.f,0.f};
      #pragma unroll
      for (int mf=0;mf<4;mf++){
        #pragma unroll
        for (int ks=0;ks<2;ks++){
          short8 kf = frag_ld(KT, mb+mf*16+l16, 128, lh*16+ks*64);
          acc[mf] = MFMA(kf, qa[ks], acc[mf]);
        }
      }
      #pragma unroll
      for (int mf=0;mf<4;mf++){
        int mg = hq*SEQ + m0 + mb + mf*16 + lh*4;
        float4 rsk4 = *reinterpret_cast<const float4*>(&rskA[mg]);
        float4 i1k4 = *reinterpret_cast<const float4*>(&i1kA[mg]);
        float rk[4]={rsk4.x,rsk4.y,rsk4.z,rsk4.w};
        float ik[4]={i1k4.x,i1k4.y,i1k4.z,i1k4.w};
        #pragma unroll
        for (int r=0;r<4;r++){
          float S = acc[mf][r];
          float cosv = clampf(S*iq1*ik[r], -0.99f, 0.99f);
          float u = fmaf(KCOV, S, -c1x);
          float covv = fmaf(-aqx, rk[r], u);
          covv = clampf(covv, -10.0f, 10.0f);
          float marg = clampf(0.01f - cosv, 0.0f, 2.0f);
          sc += cosv; sc2 = fmaf(cosv,cosv,sc2);
          so += covv; so2 = fmaf(covv,covv,so2);
          sco = fmaf(cosv,covv,sco);
          rc += cosv; ro += covv; rm += marg;
          rmc = fmaxf(rmc, cosv); rmo = fmaxf(rmo, covv);
        }
      }
    }
  }
  // row reductions across lh (lanes sharing l16)
  rc += __shfl_xor(rc,16,64); rc += __shfl_xor(rc,32,64);
  ro += __shfl_xor(ro,16,64); ro += __shfl_xor(ro,32,64);
  rm += __shfl_xor(rm,16,64); rm += __shfl_xor(rm,32,64);
  rmc = fmaxf(rmc, __shfl_xor(rmc,16,64)); rmc = fmaxf(rmc, __shfl_xor(rmc,32,64));
  rmo = fmaxf(rmo, __shfl_xor(rmo,16,64)); rmo = fmaxf(rmo, __shfl_xor(rmo,32,64));
  if (lane<16){
    rmaxcA[hq*SEQ+n] = rmc;
    rmaxoA[hq*SEQ+n] = rmo;
  }
  double vm=0.0, vm2=0.0, vmc=0.0, vmo=0.0;
  if (lane<16){
    float mm = rm*(1.0f/512.0f);
    vm  = (double)mm;
    vm2 = (double)mm*(double)mm;
    vmc = (double)mm*(double)rc;
    vmo = (double)mm*(double)ro;
  }
  float fs[5]={sc,sc2,so,so2,sco};
  for (int c=0;c<5;c++){
    __syncthreads();
    red[t]=fs[c]; __syncthreads();
    for (int o=128;o>0;o>>=1){ if (t<o) red[t]+=red[t+o]; __syncthreads(); }
    if (t==0) momf[(size_t)(hq*8+strip)*5 + c] = red[0];
  }
  double ds[4]={vm,vm2,vmc,vmo};
  for (int c=0;c<4;c++){
    __syncthreads();
    dred[t]=ds[c]; __syncthreads();
    for (int o=128;o>0;o>>=1){ if (t<o) dred[t]+=dred[t+o]; __syncthreads(); }
    if (t==0) varp[(size_t)(hq*8+strip)*4 + c] = dred[0];
  }
}

// ---------------------------------------------------------------- F: MLP + stds + mix params
__global__ void __launch_bounds__(256) finalize_kernel(
    const float* __restrict__ qgp, const float* __restrict__ kgp,
    const float* __restrict__ wp1w, const float* __restrict__ wp1b,
    const float* __restrict__ wplg, const float* __restrict__ wplb,
    const float* __restrict__ wp2w, const float* __restrict__ wp2b,
    const float* __restrict__ wp3w, const float* __restrict__ wp3b,
    const float* __restrict__ temp,
    const float* __restrict__ momf, const double* __restrict__ varp,
    float* __restrict__ params)
{
  int t = threadIdx.x;
  __shared__ float feats[8][128];
  __shared__ float h1s[8][64];
  __shared__ float h2s[8][32];
  __shared__ float wts[8][3];
  __shared__ double Sh[8][9];
  for (int idx=t; idx<512; idx+=256){
    int h = idx>>6, d = idx&63;
    float s1=0, s2=0;
    for (int qq=0; qq<QB; qq++){ s1 += qgp[(h*QB+qq)*64+d]; s2 += kgp[(h*QB+qq)*64+d]; }
    feats[h][d]    = s1*(1.0f/8192.0f);
    feats[h][64+d] = s2*(1.0f/8192.0f);
  }
  __syncthreads();
  int w = t>>6, j = t&63;
  for (int pp=0; pp<2; pp++){
    int h = w + pp*4;
    float acc = wp1b[j];
    for (int k=0;k<128;k++) acc += feats[h][k]*wp1w[k*64+j];
    float s=acc, s2=acc*acc;
    #pragma unroll
    for (int m=32;m>0;m>>=1){ s+=__shfl_xor(s,m,64); s2+=__shfl_xor(s2,m,64); }
    float mean = s*(1.0f/64.0f);
    float var  = s2*(1.0f/64.0f) - mean*mean;
    float xh = (acc-mean)*rsqrtf(var+1e-5f)*wplg[j] + wplb[j];
    h1s[h][j] = fmaxf(xh, 0.0f);
  }
  __syncthreads();
  {
    int h = t>>5, j2 = t&31;
    float acc = wp2b[j2];
    for (int k=0;k<64;k++) acc += h1s[h][k]*wp2w[k*32+j2];
    h2s[h][j2] = fmaxf(acc, 0.0f);
  }
  __syncthreads();
  if (t<8){
    int h = t;
    float z[3] = {wp3b[0], wp3b[1], wp3b[2]};
    for (int k=0;k<32;k++){
      float hv = h2s[h][k];
      z[0]+=hv*wp3w[k*3]; z[1]+=hv*wp3w[k*3+1]; z[2]+=hv*wp3w[k*3+2];
    }
    float mx = fmaxf(z[0], fmaxf(z[1], z[2]));
    float e0=expf(z[0]-mx), e1=expf(z[1]-mx), e2=expf(z[2]-mx);
    float inv = 1.0f/(e0+e1+e2);
    float l0=e0*inv, l1=e1*inv, l2=e2*inv;
    float tv = temp[0]; tv = fminf(fmaxf(tv, 0.1f), 20.0f);
    float y0=l0/tv, y1=l1/tv, y2=l2/tv;
    float mx2 = fmaxf(y0, fmaxf(y1, y2));
    float f0=expf(y0-mx2), f1=expf(y1-mx2), f2=expf(y2-mx2);
    float inv2 = 1.0f/(f0+f1+f2);
    wts[h][0]=f0*inv2; wts[h][1]=f1*inv2; wts[h][2]=f2*inv2;
  }
  __syncthreads();
  if (t<40){
    int h = t/5, c = t%5;
    double s = 0;
    for (int e=0; e<128; e++) s += (double)momf[(size_t)(h*128+e)*5 + c];
    Sh[h][c] = s;
  }
  __syncthreads();
  if (t<32){
    int h = t>>2, c = t&3;
    double s = 0;
    for (int e=0; e<128; e++) s += varp[(size_t)(h*128+e)*4 + c];
    Sh[h][5+c] = s;
  }
  __syncthreads();
  if (t==0){
    const double Ntot = 33554432.0;
    double T1c=0,T2c=0,T1o=0,T2o=0,T1v=0,T2v=0;
    for (int h=0;h<8;h++){
      T1c+=Sh[h][0]; T2c+=Sh[h][1]; T1o+=Sh[h][2]; T2o+=Sh[h][3];
      T1v+=512.0*Sh[h][5]; T2v+=512.0*Sh[h][6];
    }
    double stdc = sqrt(fmax((T2c - T1c*T1c/Ntot)/(Ntot-1.0), 0.0));
    double stdo = sqrt(fmax((T2o - T1o*T1o/Ntot)/(Ntot-1.0), 0.0));
    double stdv = sqrt(fmax((T2v - T1v*T1v/Ntot)/(Ntot-1.0), 0.0));
    double ah[8], bh[8];
    double Sd1=0, Sd2=0;
    for (int h=0;h<8;h++){
      double a = (double)wts[h][0]/(stdc+1e-8);
      double b = (double)wts[h][1]*0.1/(stdo+1e-8);
      double c = (double)wts[h][2]*0.1/(stdv+1e-8);
      ah[h]=a; bh[h]=b;
      Sd1 += a*Sh[h][0] + b*Sh[h][2] + c*512.0*Sh[h][5];
      Sd2 += a*a*Sh[h][1] + b*b*Sh[h][3] + c*c*512.0*Sh[h][6]
           + 2.0*a*b*Sh[h][4] + 2.0*a*c*Sh[h][7] + 2.0*b*c*Sh[h][8];
    }
    double stdd = sqrt(fmax((Sd2 - Sd1*Sd1/Ntot)/(Ntot-1.0), 0.0));
    double att = 1.0 + 0.5*stdd;
    att = fmin(fmax(att, 0.5), 5.0);
    double scale = 1.0/att;
    for (int h=0;h<8;h++){
      params[h*2+0] = (float)(scale*ah[h]);
      params[h*2+1] = (float)(scale*bh[h]);
    }
  }
}

// ---------------------------------------------------------------- M2: fixed-max softmax + PV (swapped-QK MFMA)
__global__ void __launch_bounds__(256) attn_m2_kernel(
    const unsigned short* __restrict__ fq, const unsigned short* __restrict__ fk,
    const unsigned short* __restrict__ fvT,
    const float* __restrict__ aqA, const float* __restrict__ c1A, const float* __restrict__ i1qA,
    const float* __restrict__ rskA, const float* __restrict__ i1kA,
    const float* __restrict__ c2A, const float* __restrict__ params,
    const float* __restrict__ rmaxcA, const float* __restrict__ rmaxoA,
    unsigned short* __restrict__ attn_bf)
{
  int strip=blockIdx.x, q_=blockIdx.y, h=blockIdx.z;
  int hq=h*QB+q_, n0=strip*64;
  const unsigned short* Fq=fq+(size_t)hq*SEQ*DHD;
  const unsigned short* Fk=fk+(size_t)hq*SEQ*DHD;
  const unsigned short* FvT=fvT+(size_t)hq*DHD*SEQ;
  __shared__ unsigned short KT[128*64];     // K rows (m) x 64 d
  __shared__ unsigned short VT[64*128];     // [d][m], pitch 256B
  __shared__ unsigned short P[64*64];       // [n][m-half] bf16, pitch 128B
  int t=threadIdx.x, w=t>>6, lane=t&63, l16=lane&15, lh=lane>>4;
  int n = n0 + w*16 + l16;
  float c2v=c2A[hq];
  float pa=params[h*2], pb=params[h*2+1];
  float aqv = aqA[hq*SEQ+n];
  float c1v = c1A[hq*SEQ+n];
  float iq1 = i1qA[hq*SEQ+n];
  float rmc = rmaxcA[hq*SEQ+n];
  float rmo = rmaxoA[hq*SEQ+n];
  float pbk = pb*KCOV;
  float ra  = pa*iq1;
  float bndc = 0.99f*pa;
  float rowc = -pbk*(c1v - aqv*c2v);
  float r3   = pbk*aqv;
  float Mrow = fmaf(pa, rmc, pb*rmo);
  short8 qa[2];
  #pragma unroll
  for (int ks=0;ks<2;ks++)
    qa[ks] = *reinterpret_cast<const short8*>(&Fq[(size_t)n*DHD + ks*32 + lh*8]);
  short8 ones;
  #pragma unroll
  for (int i=0;i<8;i++) ones[i] = (short)0x3F80;
  f32x4 accO[4];
  #pragma unroll
  for (int j=0;j<4;j++) accO[j]=(f32x4){0.f,0.f,0.f,0.f};
  f32x4 den = (f32x4){0.f,0.f,0.f,0.f};
  for (int mc=0;mc<4;mc++){
    int m0=mc*128;
    __syncthreads();
    for (int it=0;it<4;++it){
      int idx=it*256+t, row=idx>>3, qc=idx&7;
      ushort8v vv = *reinterpret_cast<const ushort8v*>(&Fk[(size_t)(m0+row)*DHD + qc*8]);
      tile_st16(KT,row,128,qc*16,vv);
    }
    for (int it=0;it<4;++it){
      int idx=it*256+t, dd=idx>>4, c=idx&15;
      ushort8v vv=*reinterpret_cast<const ushort8v*>(&FvT[(size_t)dd*SEQ + m0 + c*8]);
      tile_st16(VT, dd, 256, c*16, vv);
    }
    __syncthreads();
    #pragma unroll
    for (int mh=0;mh<2;mh++){
      int mb = mh*64;
      // QK^T (swapped): acc rows = K rows m, cols = own n
      f32x4 acc[4];
      #pragma unroll
      for (int mf=0;mf<4;mf++) acc[mf]=(f32x4){0.f,0.f,0.f,0.f};
      #pragma unroll
      for (int mf=0;mf<4;mf++){
        #pragma unroll
        for (int ks=0;ks<2;ks++){
          short8 kf = frag_ld(KT, mb+mf*16+l16, 128, lh*16+ks*64);
          acc[mf] = MFMA(kf, qa[ks], acc[mf]);
        }
      }
      // transform + exp(logit - Mrow), write P[n][m] packed
      int prow = w*16 + l16;
      #pragma unroll
      for (int mf=0;mf<4;mf++){
        int mg = hq*SEQ + m0 + mb + mf*16 + lh*4;
        float4 rsk4 = *reinterpret_cast<const float4*>(&rskA[mg]);
        float4 i1k4 = *reinterpret_cast<const float4*>(&i1kA[mg]);
        float rk[4]={rsk4.x,rsk4.y,rsk4.z,rsk4.w};
        float ik[4]={i1k4.x,i1k4.y,i1k4.z,i1k4.w};
        #pragma unroll
        for (int r=0;r<4;r++){
          float S = acc[mf][r];
          float tt = S*ra; tt *= ik[r];
          float cc = clampf(tt, -bndc, bndc);
          float u = fmaf(pbk, S, rowc);
          float lin = fmaf(-r3, rk[r], u);
          acc[mf][r] = __expf(cc + lin - Mrow);
        }
        unsigned lo = cvtpk(acc[mf][0], acc[mf][1]);
        unsigned hi = cvtpk(acc[mf][2], acc[mf][3]);
        int pbyte = (mf*32 + lh*8) ^ ((prow&7)<<4);
        *reinterpret_cast<uint2*>(reinterpret_cast<char*>(P) + prow*128 + pbyte)
          = make_uint2(lo, hi);
      }
      // PV + denominator (wave-local P rows; in-wave LDS ordering suffices)
      #pragma unroll
      for (int ks=0;ks<2;ks++){
        short8 pfrag = frag_ld(P, prow, 128, lh*16 + ks*64);
        #pragma unroll
        for (int dcf=0;dcf<4;dcf++){
          short8 vb = frag_ld(VT, dcf*16+l16, 256, mb*2 + ks*64 + lh*16);
          accO[dcf] = MFMA(pfrag, vb, accO[dcf]);
        }
        den = MFMA(pfrag, ones, den);
      }
    }
  }
  // epilogue: normalize, bounce through P, coalesced store
  f32x4 invD;
  #pragma unroll
  for (int r=0;r<4;r++) invD[r] = 1.0f/den[r];
  #pragma unroll
  for (int dcf=0;dcf<4;dcf++){
    #pragma unroll
    for (int r=0;r<4;r++){
      int row = w*16 + lh*4 + r;
      int col = dcf*16 + l16;
      int addr = row*128 + ((col*2) ^ ((row&7)<<4));
      *reinterpret_cast<unsigned short*>(reinterpret_cast<char*>(P) + addr)
        = f2bf(accO[dcf][r]*invD[r]);
    }
  }
  __syncthreads();
  for (int it=0; it<2; ++it){
    int idx = it*256 + t;
    int row = idx>>3, c = idx&7;
    int addr = row*128 + ((c*16) ^ ((row&7)<<4));
    ushort8v vv = *reinterpret_cast<ushort8v*>(reinterpret_cast<char*>(P) + addr);
    *reinterpret_cast<ushort8v*>(
      &attn_bf[(size_t)(q_*SEQ + n0 + row)*DMODEL + h*DHD + c*8]) = vv;
  }
}

// ---------------------------------------------------------------- KO: output projection (MFMA)
__global__ void __launch_bounds__(256) out_mfma_kernel(
    const unsigned short* __restrict__ attn_bf, const unsigned short* __restrict__ WoT,
    const float* __restrict__ bias, float* __restrict__ out)
{
  int r0=blockIdx.x*128;
  int c0=blockIdx.y*128;
  __shared__ unsigned short AT[128*64];
  __shared__ unsigned short WT[128*64];
  int t=threadIdx.x, w=t>>6, lane=t&63, l16=lane&15, lh=lane>>4;
  f32x4 acc[4][4];
  #pragma unroll
  for(int i=0;i<4;i++){ for(int j=0;j<4;j++) acc[i][j]=(f32x4){0.f,0.f,0.f,0.f}; }
  for (int k0=0;k0<DMODEL;k0+=64){
    __syncthreads();
    for (int it=0; it<4; ++it){
      int idx=it*256+t, row=idx>>3, q=idx&7;
      ushort8v v = *reinterpret_cast<const ushort8v*>(&attn_bf[(size_t)(r0+row)*DMODEL + k0 + q*8]);
      tile_st16(AT, row, 128, q*16, v);
    }
    for (int it=0; it<4; ++it){
      int idx=it*256+t, row=idx>>3, q=idx&7;
      ushort8v v = *reinterpret_cast<const ushort8v*>(&WoT[(size_t)(c0+row)*DMODEL + k0 + q*8]);
      tile_st16(WT, row, 128, q*16, v);
    }
    __syncthreads();
    int nr=(w&1)*64, mr=(w>>1)*64;
    #pragma unroll
    for (int ks=0; ks<2; ++ks){
      int kb = lh*16 + ks*64;
      short8 a[4], b[4];
      #pragma unroll
      for (int i=0;i<4;i++) a[i] = frag_ld(WT, nr+i*16+l16, 128, kb);
      #pragma unroll
      for (int j=0;j<4;j++) b[j] = frag_ld(AT, mr+j*16+l16, 128, kb);
      #pragma unroll
      for (int i=0;i<4;i++){
        #pragma unroll
        for (int j=0;j<4;j++) acc[i][j]=MFMA(a[i],b[j],acc[i][j]);
      }
    }
  }
  #pragma unroll
  for (int i=0;i<4;i++){
    int nb = c0+(w&1)*64+i*16+lh*4;
    float4 b4 = *reinterpret_cast<const float4*>(&bias[nb]);
    #pragma unroll
    for (int j=0;j<4;j++){
      int mg = r0+(w>>1)*64+j*16+l16;
      f32x4 o = acc[i][j];
      o[0]+=b4.x; o[1]+=b4.y; o[2]+=b4.z; o[3]+=b4.w;
      *reinterpret_cast<f32x4*>(&out[(size_t)mg*DMODEL + nb]) = o;
    }
  }
}

// ----------------------------------------------------------------
extern "C" void kernel_launch(void* const* d_in, const int* in_sizes, int n_in,
                              void* d_out, int out_size, void* d_ws, size_t ws_size,
                              hipStream_t stream)
{
  (void)in_sizes; (void)n_in; (void)out_size; (void)ws_size;
  const float* q     = (const float*)d_in[0];
  const float* k     = (const float*)d_in[1];
  const float* v     = (const float*)d_in[2];
  const float* ln_g  = (const float*)d_in[3];
  const float* ln_b  = (const float*)d_in[4];
  const float* W_in  = (const float*)d_in[5];
  const float* wp1w  = (const float*)d_in[6];
  const float* wp1b  = (const float*)d_in[7];
  const float* wplg  = (const float*)d_in[8];
  const float* wplb  = (const float*)d_in[9];
  const float* wp2w  = (const float*)d_in[10];
  const float* wp2b  = (const float*)d_in[11];
  const float* wp3w  = (const float*)d_in[12];
  const float* wp3b  = (const float*)d_in[13];
  const float* temp  = (const float*)d_in[14];
  const float* W_out = (const float*)d_in[15];
  const float* b_out = (const float*)d_in[16];
  float* out = (float*)d_out;

  char* wsb = (char*)d_ws;
  size_t off = 0;
  auto alloc = [&](size_t bytes)->char*{
    char* p = wsb + off; off += (bytes + 255) & ~(size_t)255; return p;
  };
  unsigned short* fq_b   = (unsigned short*)alloc((size_t)NHQ*SEQ*DHD*2);
  unsigned short* fk_b   = (unsigned short*)alloc((size_t)NHQ*SEQ*DHD*2);
  unsigned short* fvT_b  = (unsigned short*)alloc((size_t)NHQ*SEQ*DHD*2);
  unsigned short* attn_b = (unsigned short*)alloc((size_t)NROWS*DMODEL*2);
  unsigned short* WiT    = (unsigned short*)alloc((size_t)DMODEL*DMODEL*2);
  unsigned short* WoT    = (unsigned short*)alloc((size_t)DMODEL*DMODEL*2);
  float* mu     = (float*)alloc(3*NROWS*4);
  float* rstd   = (float*)alloc(3*NROWS*4);
  float* aqA    = (float*)alloc(NHQ*SEQ*4);
  float* c1A    = (float*)alloc(NHQ*SEQ*4);
  float* i1qA   = (float*)alloc(NHQ*SEQ*4);
  float* rskA   = (float*)alloc(NHQ*SEQ*4);
  float* i1kA   = (float*)alloc(NHQ*SEQ*4);
  float* rmaxcA = (float*)alloc(NHQ*SEQ*4);
  float* rmaxoA = (float*)alloc(NHQ*SEQ*4);
  float* c2A    = (float*)alloc(NHQ*4);
  float* qgp    = (float*)alloc(NHQ*64*4);
  float* kgp    = (float*)alloc(NHQ*64*4);
  float* colpart= (float*)alloc((size_t)2*NHQ*4*64*4);
  float* momf   = (float*)alloc((size_t)NHQ*8*5*4);
  double* varp  = (double*)alloc((size_t)NHQ*8*4*8);
  float* params = (float*)alloc(64);

  prep_kernel<<<6272, 256, 0, stream>>>(q, k, v, W_in, W_out, mu, rstd, WiT, WoT);
  proj_mfma_kernel<<<dim3(64,4,3), 256, 0, stream>>>(q, k, v, ln_g, ln_b, WiT, mu, rstd,
                                                     fq_b, fk_b, fvT_b, aqA, i1qA, rskA, i1kA);
  colsum_kernel<<<dim3(NHQ, 4, 2), 256, 0, stream>>>(fq_b, fk_b, colpart);
  colreduce_kernel<<<dim3(NHQ), 64, 0, stream>>>(colpart, qgp, kgp, c2A);
  score_m1_kernel<<<dim3(8, QB, NH), 256, 0, stream>>>(fq_b, fk_b, aqA, i1qA, rskA, i1kA,
                                                       c2A, kgp, c1A, rmaxcA, rmaxoA, momf, varp);
  finalize_kernel<<<1, 256, 0, stream>>>(qgp, kgp, wp1w, wp1b, wplg, wplb, wp2w, wp2b,
                                         wp3w, wp3b, temp, momf, varp, params);
  attn_m2_kernel<<<dim3(8, QB, NH), 256, 0, stream>>>(fq_b, fk_b, fvT_b, aqA, c1A, i1qA,
                                                      rskA, i1kA, c2A, params, rmaxcA, rmaxoA, attn_b);
  out_mfma_kernel<<<dim3(64,4), 256, 0, stream>>>(attn_b, WoT, b_out, out);
}

// Round 5
// 169.562 us; speedup vs baseline: 4.5348x; 1.0253x over previous
//
#include <hip/hip_runtime.h>
#include <math.h>

#define NH 8
#define DHD 64
#define DMODEL 512
#define QB 16
#define SEQ 512
#define NROWS (QB*SEQ)      /* 8192 rows per input */
#define NHQ (NH*QB)         /* 128 (h,q) pairs */
#define KCOV ((float)((0.001/512.0)/(8.0+1e-8)))

typedef __attribute__((ext_vector_type(8))) short short8;      // 8 bf16 -> 4 VGPR
typedef __attribute__((ext_vector_type(8))) unsigned short ushort8v;
typedef __attribute__((ext_vector_type(4))) unsigned short ushort4v;
typedef __attribute__((ext_vector_type(4))) float f32x4;

__device__ __forceinline__ float bf2f(unsigned short u){
  union { unsigned int i; float f; } c; c.i = ((unsigned int)u)<<16; return c.f;
}
__device__ __forceinline__ unsigned short f2bf(float f){
  union { float f; unsigned int i; } c; c.f = f;
  unsigned int u = c.i;
  u += 0x7fffu + ((u>>16)&1u);   // RNE
  return (unsigned short)(u>>16);
}
__device__ __forceinline__ unsigned cvtpk(float a, float b){
  unsigned r; asm("v_cvt_pk_bf16_f32 %0, %1, %2" : "=v"(r) : "v"(a), "v"(b)); return r;
}
__device__ __forceinline__ float clampf(float x, float lo, float hi){ return fminf(fmaxf(x,lo),hi); }

__device__ __forceinline__ f32x4 MFMA(short8 a, short8 b, f32x4 c){
  return __builtin_amdgcn_mfma_f32_16x16x32_bf16(a, b, c, 0, 0, 0);
}
// swizzled-tile access: element (row, kbyte), rowbytes pitch, XOR-swizzle bits 4-6 by row&7
__device__ __forceinline__ short8 frag_ld(const unsigned short* T, int row, int rowbytes, int kbyte){
  int addr = row*rowbytes + (kbyte ^ ((row&7)<<4));
  return *reinterpret_cast<const short8*>(reinterpret_cast<const char*>(T) + addr);
}
__device__ __forceinline__ void tile_st16(unsigned short* T, int row, int rowbytes, int kbyte, ushort8v v){
  int addr = row*rowbytes + (kbyte ^ ((row&7)<<4));
  *reinterpret_cast<ushort8v*>(reinterpret_cast<char*>(T) + addr) = v;
}

// ---------------------------------------------------------------- P0: LN stats+apply (bf16 out) + weight convert
__global__ void __launch_bounds__(256) prep_kernel(
    const float* __restrict__ xq, const float* __restrict__ xk, const float* __restrict__ xv,
    const float* __restrict__ ln_g, const float* __restrict__ ln_b,
    const float* __restrict__ Wi, const float* __restrict__ Wo,
    unsigned short* __restrict__ xln,
    unsigned short* __restrict__ WiT, unsigned short* __restrict__ WoT)
{
  __shared__ float T[64][68];
  int b = blockIdx.x, t = threadIdx.x;
  if (b < 6144){
    int which = b >> 11, rowblk = b & 2047;
    const float* src = which==0 ? xq : (which==1 ? xk : xv);
    int w = t >> 6, lane = t & 63;
    int row = rowblk*4 + w;
    const float* x = src + (size_t)row*DMODEL;
    float4 v1 = *reinterpret_cast<const float4*>(&x[lane*8]);
    float4 v2 = *reinterpret_cast<const float4*>(&x[lane*8+4]);
    float s  = v1.x+v1.y+v1.z+v1.w + v2.x+v2.y+v2.z+v2.w;
    float ss = v1.x*v1.x+v1.y*v1.y+v1.z*v1.z+v1.w*v1.w
             + v2.x*v2.x+v2.y*v2.y+v2.z*v2.z+v2.w*v2.w;
    #pragma unroll
    for (int m=32; m>0; m>>=1){ s += __shfl_xor(s,m,64); ss += __shfl_xor(ss,m,64); }
    float m_ = s*(1.0f/DMODEL);
    float var = ss*(1.0f/DMODEL) - m_*m_;
    float r_ = rsqrtf(var + 1e-5f);
    float4 g1 = *reinterpret_cast<const float4*>(&ln_g[lane*8]);
    float4 g2 = *reinterpret_cast<const float4*>(&ln_g[lane*8+4]);
    float4 b1 = *reinterpret_cast<const float4*>(&ln_b[lane*8]);
    float4 b2 = *reinterpret_cast<const float4*>(&ln_b[lane*8+4]);
    ushort8v o;
    o[0]=f2bf((v1.x-m_)*r_*g1.x + b1.x);
    o[1]=f2bf((v1.y-m_)*r_*g1.y + b1.y);
    o[2]=f2bf((v1.z-m_)*r_*g1.z + b1.z);
    o[3]=f2bf((v1.w-m_)*r_*g1.w + b1.w);
    o[4]=f2bf((v2.x-m_)*r_*g2.x + b2.x);
    o[5]=f2bf((v2.y-m_)*r_*g2.y + b2.y);
    o[6]=f2bf((v2.z-m_)*r_*g2.z + b2.z);
    o[7]=f2bf((v2.w-m_)*r_*g2.w + b2.w);
    *reinterpret_cast<ushort8v*>(&xln[((size_t)which*NROWS + row)*DMODEL + lane*8]) = o;
  } else {
    int wb = b - 6144;
    const float* src = (wb>=64) ? Wo : Wi;
    unsigned short* dst = (wb>=64) ? WoT : WiT;
    int rc = wb & 63;
    int r0 = (rc>>3)*64, c0 = (rc&7)*64;
    for (int it=0; it<4; ++it){
      int idx = it*256+t, row = idx>>4, q = idx&15;
      float4 v = *reinterpret_cast<const float4*>(&src[(size_t)(r0+row)*DMODEL + c0 + q*4]);
      T[row][q*4+0]=v.x; T[row][q*4+1]=v.y; T[row][q*4+2]=v.z; T[row][q*4+3]=v.w;
    }
    __syncthreads();
    for (int it=0; it<4; ++it){
      int idx = it*256+t, oc = idx>>4, q = idx&15;
      ushort4v o;
      o[0]=f2bf(T[q*4+0][oc]); o[1]=f2bf(T[q*4+1][oc]);
      o[2]=f2bf(T[q*4+2][oc]); o[3]=f2bf(T[q*4+3][oc]);
      *reinterpret_cast<ushort4v*>(&dst[(size_t)(c0+oc)*DMODEL + r0 + q*4]) = o;
    }
  }
}

// ---------------------------------------------------------------- K1b: projection GEMM (pure bf16 MFMA) + row stats
__global__ void __launch_bounds__(256) proj_mfma_kernel(
    const unsigned short* __restrict__ xln,
    const unsigned short* __restrict__ WiT,
    unsigned short* __restrict__ fq, unsigned short* __restrict__ fk, unsigned short* __restrict__ fvT,
    float* __restrict__ aqA, float* __restrict__ i1qA,
    float* __restrict__ rskA, float* __restrict__ i1kA)
{
  int which = blockIdx.z;
  const unsigned short* src = xln + (size_t)which*NROWS*DMODEL;
  int r0 = blockIdx.x*128;   // x rows (n-dim)
  int c0 = blockIdx.y*128;   // output cols (head*64+d dim)
  __shared__ unsigned short XT[128*64];
  __shared__ unsigned short WT[128*64];
  int t = threadIdx.x;
  int w=t>>6, lane=t&63, l16=lane&15, lh=lane>>4;
  f32x4 acc[4][4];
  #pragma unroll
  for(int i=0;i<4;i++){ for(int j=0;j<4;j++) acc[i][j]=(f32x4){0.f,0.f,0.f,0.f}; }
  for (int k0=0;k0<DMODEL;k0+=64){
    __syncthreads();
    for (int it=0; it<4; ++it){
      int idx=it*256+t, row=idx>>3, q=idx&7;
      ushort8v v = *reinterpret_cast<const ushort8v*>(&src[(size_t)(r0+row)*DMODEL + k0 + q*8]);
      tile_st16(XT, row, 128, q*16, v);
    }
    for (int it=0; it<4; ++it){
      int idx=it*256+t, row=idx>>3, q=idx&7;
      ushort8v v = *reinterpret_cast<const ushort8v*>(&WiT[(size_t)(c0+row)*DMODEL + k0 + q*8]);
      tile_st16(WT, row, 128, q*16, v);
    }
    __syncthreads();
    if (which<2){
      int dr=(w&1)*64, nc=(w>>1)*64;
      #pragma unroll
      for (int ks=0; ks<2; ++ks){
        int kb = lh*16 + ks*64;
        short8 a[4], b[4];
        #pragma unroll
        for (int i=0;i<4;i++) a[i] = frag_ld(WT, dr+i*16+l16, 128, kb);
        #pragma unroll
        for (int j=0;j<4;j++) b[j] = frag_ld(XT, nc+j*16+l16, 128, kb);
        #pragma unroll
        for (int i=0;i<4;i++){
          #pragma unroll
          for (int j=0;j<4;j++) acc[i][j]=MFMA(a[i],b[j],acc[i][j]);
        }
      }
    } else {
      int nr=(w>>1)*64, dc=(w&1)*64;
      #pragma unroll
      for (int ks=0; ks<2; ++ks){
        int kb = lh*16 + ks*64;
        short8 a[4], b[4];
        #pragma unroll
        for (int i=0;i<4;i++) a[i] = frag_ld(XT, nr+i*16+l16, 128, kb);
        #pragma unroll
        for (int j=0;j<4;j++) b[j] = frag_ld(WT, dc+j*16+l16, 128, kb);
        #pragma unroll
        for (int i=0;i<4;i++){
          #pragma unroll
          for (int j=0;j<4;j++) acc[i][j]=MFMA(a[i],b[j],acc[i][j]);
        }
      }
    }
  }
  if (which<2){
    unsigned short* dst = which ? fk : fq;
    int dr=(w&1)*64, nc=(w>>1)*64;
    #pragma unroll
    for (int i=0;i<4;i++){
      #pragma unroll
      for (int j=0;j<4;j++){
        int cl = c0 + dr + i*16 + lh*4;
        int ng = r0 + nc + j*16 + l16;
        int head = cl>>6, dd = cl&63;
        int hq = head*QB + (ng>>9);
        int n = ng&511;
        ushort4v o;
        o[0]=f2bf(acc[i][j][0]); o[1]=f2bf(acc[i][j][1]);
        o[2]=f2bf(acc[i][j][2]); o[3]=f2bf(acc[i][j][3]);
        *reinterpret_cast<ushort4v*>(&dst[((size_t)hq*SEQ+n)*DHD + dd]) = o;
      }
    }
    // fused row stats: sum_d f, sum_d f^2 for this wave's head
    int head = (c0>>6) + (w&1);
    #pragma unroll
    for (int j=0;j<4;j++){
      float s=0.f, ss=0.f;
      #pragma unroll
      for (int i=0;i<4;i++){
        #pragma unroll
        for (int r=0;r<4;r++){ float x = acc[i][j][r]; s += x; ss = fmaf(x,x,ss); }
      }
      s += __shfl_xor(s,16,64); ss += __shfl_xor(ss,16,64);
      s += __shfl_xor(s,32,64); ss += __shfl_xor(ss,32,64);
      if (lh==0){
        int ng = r0 + nc + j*16 + l16;
        int hq = head*QB + (ng>>9);
        int n = ng&511;
        float nrm = sqrtf(ss);
        if (which==0){
          aqA[hq*SEQ+n]  = s*(1.0f/64.0f);
          i1qA[hq*SEQ+n] = 1.0f/(nrm+1e-8f);
        } else {
          rskA[hq*SEQ+n] = s;
          i1kA[hq*SEQ+n] = 1.0f/(nrm+1e-8f);
        }
      }
    }
  } else {
    int nr=(w>>1)*64, dc=(w&1)*64;
    #pragma unroll
    for (int i=0;i<4;i++){
      #pragma unroll
      for (int j=0;j<4;j++){
        int ngb = r0 + nr + i*16 + lh*4;
        int dg  = c0 + dc + j*16 + l16;
        int head = dg>>6, dd = dg&63;
        int hq = head*QB + (ngb>>9);
        int n = ngb&511;
        ushort4v o;
        o[0]=f2bf(acc[i][j][0]); o[1]=f2bf(acc[i][j][1]);
        o[2]=f2bf(acc[i][j][2]); o[3]=f2bf(acc[i][j][3]);
        *reinterpret_cast<ushort4v*>(&fvT[((size_t)hq*DHD+dd)*SEQ + n]) = o;
      }
    }
  }
}

// ---------------------------------------------------------------- S: full column stats (one block per hq,isk)
__global__ void __launch_bounds__(256) colstat_kernel(
    const unsigned short* __restrict__ fq, const unsigned short* __restrict__ fk,
    float* __restrict__ qgp, float* __restrict__ kgp, float* __restrict__ c2A)
{
  int hq = blockIdx.x, isk = blockIdx.y;
  const unsigned short* F = (isk ? fk : fq) + (size_t)hq*SEQ*DHD;
  int t = threadIdx.x, g = t&15, rg = t>>4;
  float acc0=0.f, acc1=0.f, acc2=0.f, acc3=0.f;
  #pragma unroll 4
  for (int i=0;i<32;i++){
    int r = rg + 16*i;
    ushort4v v = *reinterpret_cast<const ushort4v*>(&F[(size_t)r*DHD + g*4]);
    acc0+=bf2f(v[0]); acc1+=bf2f(v[1]); acc2+=bf2f(v[2]); acc3+=bf2f(v[3]);
  }
  __shared__ float sh[16][68];
  sh[rg][g*4+0]=acc0; sh[rg][g*4+1]=acc1; sh[rg][g*4+2]=acc2; sh[rg][g*4+3]=acc3;
  __syncthreads();
  if (t<64){
    float s=0.f;
    #pragma unroll
    for (int r=0;r<16;r++) s += sh[r][t];
    if (isk){
      kgp[hq*64+t]=s;
      float c = s*(1.0f/512.0f);
      #pragma unroll
      for (int m=32;m>0;m>>=1) c += __shfl_xor(c,m,64);
      if (t==0) c2A[hq]=c;
    } else {
      qgp[hq*64+t]=s;
    }
  }
}

// ---------------------------------------------------------------- M1: moments + rowmax + c1 (swapped-QK MFMA)
__global__ void __launch_bounds__(256) score_m1_kernel(
    const unsigned short* __restrict__ fq, const unsigned short* __restrict__ fk,
    const float* __restrict__ aqA, const float* __restrict__ i1qA,
    const float* __restrict__ rskA, const float* __restrict__ i1kA,
    const float* __restrict__ c2A, const float* __restrict__ kgp,
    float* __restrict__ c1A, float* __restrict__ rmaxcA, float* __restrict__ rmaxoA,
    float* __restrict__ momf, double* __restrict__ varp)
{
  int strip=blockIdx.x, q_=blockIdx.y, h=blockIdx.z;
  int hq=h*QB+q_, n0=strip*64;
  const unsigned short* Fq=fq+(size_t)hq*SEQ*DHD;
  const unsigned short* Fk=fk+(size_t)hq*SEQ*DHD;
  __shared__ unsigned short KT[128*64];
  __shared__ float rskL[512], i1kL[512];
  __shared__ float red[256];
  __shared__ double dred[256];
  int t=threadIdx.x, w=t>>6, lane=t&63, l16=lane&15, lh=lane>>4;
  int n = n0 + w*16 + l16;
  for (int i=t;i<512;i+=256){ rskL[i]=rskA[hq*SEQ+i]; i1kL[i]=i1kA[hq*SEQ+i]; }
  float c2v = c2A[hq];
  float aqv = aqA[hq*SEQ+n];
  float iq1 = i1qA[hq*SEQ+n];
  short8 qa[2];
  #pragma unroll
  for (int ks=0;ks<2;ks++)
    qa[ks] = *reinterpret_cast<const short8*>(&Fq[(size_t)n*DHD + ks*32 + lh*8]);
  // c1[n] = fq[n] . (kgp/512)
  float c1v = 0.f;
  #pragma unroll
  for (int ks=0;ks<2;ks++){
    const float* bkp = &kgp[hq*64 + ks*32 + lh*8];
    float4 b0 = *reinterpret_cast<const float4*>(bkp);
    float4 b1 = *reinterpret_cast<const float4*>(bkp+4);
    float bb[8] = {b0.x,b0.y,b0.z,b0.w,b1.x,b1.y,b1.z,b1.w};
    #pragma unroll
    for (int i=0;i<8;i++) c1v = fmaf(bf2f((unsigned short)qa[ks][i]), bb[i], c1v);
  }
  c1v *= (1.0f/512.0f);
  c1v += __shfl_xor(c1v,16,64);
  c1v += __shfl_xor(c1v,32,64);
  if (lane<16) c1A[hq*SEQ+n] = c1v;
  float c1x = KCOV*(c1v - aqv*c2v);
  float aqx = KCOV*aqv;
  float sc=0.f,sc2=0.f,so=0.f,so2=0.f,sco=0.f;
  float rc=0.f, ro=0.f, rm=0.f, rmc=-1e30f, rmo=-1e30f;
  for (int mc=0;mc<4;mc++){
    int m0=mc*128;
    __syncthreads();
    for (int it=0;it<4;++it){
      int idx=it*256+t, row=idx>>3, qc=idx&7;
      ushort8v vv = *reinterpret_cast<const ushort8v*>(&Fk[(size_t)(m0+row)*DHD + qc*8]);
      tile_st16(KT,row,128,qc*16,vv);
    }
    __syncthreads();
    #pragma unroll
    for (int mh=0;mh<2;mh++){
      int mb = mh*64;
      f32x4 acc[4];
      #pragma unroll
      for (int mf=0;mf<4;mf++) acc[mf]=(f32x4){0.f,0.f,0.f,0.f};
      #pragma unroll
      for (int mf=0;mf<4;mf++){
        #pragma unroll
        for (int ks=0;ks<2;ks++){
          short8 kf = frag_ld(KT, mb+mf*16+l16, 128, lh*16+ks*64);
          acc[mf] = MFMA(kf, qa[ks], acc[mf]);
        }
      }
      #pragma unroll
      for (int mf=0;mf<4;mf++){
        int ml = m0 + mb + mf*16 + lh*4;
        float4 rsk4 = *reinterpret_cast<const float4*>(&rskL[ml]);
        float4 i1k4 = *reinterpret_cast<const float4*>(&i1kL[ml]);
        float rk[4]={rsk4.x,rsk4.y,rsk4.z,rsk4.w};
        float ik[4]={i1k4.x,i1k4.y,i1k4.z,i1k4.w};
        #pragma unroll
        for (int r=0;r<4;r++){
          float S = acc[mf][r];
          float cosv = clampf(S*iq1*ik[r], -0.99f, 0.99f);
          float u = fmaf(KCOV, S, -c1x);
          float covv = fmaf(-aqx, rk[r], u);
          covv = clampf(covv, -10.0f, 10.0f);
          float marg = clampf(0.01f - cosv, 0.0f, 2.0f);
          sc += cosv; sc2 = fmaf(cosv,cosv,sc2);
          so += covv; so2 = fmaf(covv,covv,so2);
          sco = fmaf(cosv,covv,sco);
          rc += cosv; ro += covv; rm += marg;
          rmc = fmaxf(rmc, cosv); rmo = fmaxf(rmo, covv);
        }
      }
    }
  }
  // row reductions across lh (lanes sharing l16)
  rc += __shfl_xor(rc,16,64); rc += __shfl_xor(rc,32,64);
  ro += __shfl_xor(ro,16,64); ro += __shfl_xor(ro,32,64);
  rm += __shfl_xor(rm,16,64); rm += __shfl_xor(rm,32,64);
  rmc = fmaxf(rmc, __shfl_xor(rmc,16,64)); rmc = fmaxf(rmc, __shfl_xor(rmc,32,64));
  rmo = fmaxf(rmo, __shfl_xor(rmo,16,64)); rmo = fmaxf(rmo, __shfl_xor(rmo,32,64));
  if (lane<16){
    rmaxcA[hq*SEQ+n] = rmc;
    rmaxoA[hq*SEQ+n] = rmo;
  }
  double vm=0.0, vm2=0.0, vmc=0.0, vmo=0.0;
  if (lane<16){
    float mm = rm*(1.0f/512.0f);
    vm  = (double)mm;
    vm2 = (double)mm*(double)mm;
    vmc = (double)mm*(double)rc;
    vmo = (double)mm*(double)ro;
  }
  float fs[5]={sc,sc2,so,so2,sco};
  for (int c=0;c<5;c++){
    __syncthreads();
    red[t]=fs[c]; __syncthreads();
    for (int o=128;o>0;o>>=1){ if (t<o) red[t]+=red[t+o]; __syncthreads(); }
    if (t==0) momf[(size_t)(hq*8+strip)*5 + c] = red[0];
  }
  double ds[4]={vm,vm2,vmc,vmo};
  for (int c=0;c<4;c++){
    __syncthreads();
    dred[t]=ds[c]; __syncthreads();
    for (int o=128;o>0;o>>=1){ if (t<o) dred[t]+=dred[t+o]; __syncthreads(); }
    if (t==0) varp[(size_t)(hq*8+strip)*4 + c] = dred[0];
  }
}

// ---------------------------------------------------------------- F: MLP + stds + mix params
__global__ void __launch_bounds__(256) finalize_kernel(
    const float* __restrict__ qgp, const float* __restrict__ kgp,
    const float* __restrict__ wp1w, const float* __restrict__ wp1b,
    const float* __restrict__ wplg, const float* __restrict__ wplb,
    const float* __restrict__ wp2w, const float* __restrict__ wp2b,
    const float* __restrict__ wp3w, const float* __restrict__ wp3b,
    const float* __restrict__ temp,
    const float* __restrict__ momf, const double* __restrict__ varp,
    float* __restrict__ params)
{
  int t = threadIdx.x;
  __shared__ float feats[8][128];
  __shared__ float h1s[8][64];
  __shared__ float h2s[8][32];
  __shared__ float wts[8][3];
  __shared__ double Sh[8][9];
  for (int idx=t; idx<512; idx+=256){
    int h = idx>>6, d = idx&63;
    float s1=0, s2=0;
    for (int qq=0; qq<QB; qq++){ s1 += qgp[(h*QB+qq)*64+d]; s2 += kgp[(h*QB+qq)*64+d]; }
    feats[h][d]    = s1*(1.0f/8192.0f);
    feats[h][64+d] = s2*(1.0f/8192.0f);
  }
  __syncthreads();
  int w = t>>6, j = t&63;
  for (int pp=0; pp<2; pp++){
    int h = w + pp*4;
    float acc = wp1b[j];
    for (int k=0;k<128;k++) acc += feats[h][k]*wp1w[k*64+j];
    float s=acc, s2=acc*acc;
    #pragma unroll
    for (int m=32;m>0;m>>=1){ s+=__shfl_xor(s,m,64); s2+=__shfl_xor(s2,m,64); }
    float mean = s*(1.0f/64.0f);
    float var  = s2*(1.0f/64.0f) - mean*mean;
    float xh = (acc-mean)*rsqrtf(var+1e-5f)*wplg[j] + wplb[j];
    h1s[h][j] = fmaxf(xh, 0.0f);
  }
  __syncthreads();
  {
    int h = t>>5, j2 = t&31;
    float acc = wp2b[j2];
    for (int k=0;k<64;k++) acc += h1s[h][k]*wp2w[k*32+j2];
    h2s[h][j2] = fmaxf(acc, 0.0f);
  }
  __syncthreads();
  if (t<8){
    int h = t;
    float z[3] = {wp3b[0], wp3b[1], wp3b[2]};
    for (int k=0;k<32;k++){
      float hv = h2s[h][k];
      z[0]+=hv*wp3w[k*3]; z[1]+=hv*wp3w[k*3+1]; z[2]+=hv*wp3w[k*3+2];
    }
    float mx = fmaxf(z[0], fmaxf(z[1], z[2]));
    float e0=expf(z[0]-mx), e1=expf(z[1]-mx), e2=expf(z[2]-mx);
    float inv = 1.0f/(e0+e1+e2);
    float l0=e0*inv, l1=e1*inv, l2=e2*inv;
    float tv = temp[0]; tv = fminf(fmaxf(tv, 0.1f), 20.0f);
    float y0=l0/tv, y1=l1/tv, y2=l2/tv;
    float mx2 = fmaxf(y0, fmaxf(y1, y2));
    float f0=expf(y0-mx2), f1=expf(y1-mx2), f2=expf(y2-mx2);
    float inv2 = 1.0f/(f0+f1+f2);
    wts[h][0]=f0*inv2; wts[h][1]=f1*inv2; wts[h][2]=f2*inv2;
  }
  __syncthreads();
  if (t<40){
    int h = t/5, c = t%5;
    double s = 0;
    for (int e=0; e<128; e++) s += (double)momf[(size_t)(h*128+e)*5 + c];
    Sh[h][c] = s;
  }
  __syncthreads();
  if (t<32){
    int h = t>>2, c = t&3;
    double s = 0;
    for (int e=0; e<128; e++) s += varp[(size_t)(h*128+e)*4 + c];
    Sh[h][5+c] = s;
  }
  __syncthreads();
  if (t==0){
    const double Ntot = 33554432.0;
    double T1c=0,T2c=0,T1o=0,T2o=0,T1v=0,T2v=0;
    for (int h=0;h<8;h++){
      T1c+=Sh[h][0]; T2c+=Sh[h][1]; T1o+=Sh[h][2]; T2o+=Sh[h][3];
      T1v+=512.0*Sh[h][5]; T2v+=512.0*Sh[h][6];
    }
    double stdc = sqrt(fmax((T2c - T1c*T1c/Ntot)/(Ntot-1.0), 0.0));
    double stdo = sqrt(fmax((T2o - T1o*T1o/Ntot)/(Ntot-1.0), 0.0));
    double stdv = sqrt(fmax((T2v - T1v*T1v/Ntot)/(Ntot-1.0), 0.0));
    double ah[8], bh[8];
    double Sd1=0, Sd2=0;
    for (int h=0;h<8;h++){
      double a = (double)wts[h][0]/(stdc+1e-8);
      double b = (double)wts[h][1]*0.1/(stdo+1e-8);
      double c = (double)wts[h][2]*0.1/(stdv+1e-8);
      ah[h]=a; bh[h]=b;
      Sd1 += a*Sh[h][0] + b*Sh[h][2] + c*512.0*Sh[h][5];
      Sd2 += a*a*Sh[h][1] + b*b*Sh[h][3] + c*c*512.0*Sh[h][6]
           + 2.0*a*b*Sh[h][4] + 2.0*a*c*Sh[h][7] + 2.0*b*c*Sh[h][8];
    }
    double stdd = sqrt(fmax((Sd2 - Sd1*Sd1/Ntot)/(Ntot-1.0), 0.0));
    double att = 1.0 + 0.5*stdd;
    att = fmin(fmax(att, 0.5), 5.0);
    double scale = 1.0/att;
    for (int h=0;h<8;h++){
      params[h*2+0] = (float)(scale*ah[h]);
      params[h*2+1] = (float)(scale*bh[h]);
    }
  }
}

// ---------------------------------------------------------------- M2: fixed-max softmax + PV (swapped-QK MFMA)
__global__ void __launch_bounds__(256) attn_m2_kernel(
    const unsigned short* __restrict__ fq, const unsigned short* __restrict__ fk,
    const unsigned short* __restrict__ fvT,
    const float* __restrict__ aqA, const float* __restrict__ c1A, const float* __restrict__ i1qA,
    const float* __restrict__ rskA, const float* __restrict__ i1kA,
    const float* __restrict__ c2A, const float* __restrict__ params,
    const float* __restrict__ rmaxcA, const float* __restrict__ rmaxoA,
    unsigned short* __restrict__ attn_bf)
{
  int strip=blockIdx.x, q_=blockIdx.y, h=blockIdx.z;
  int hq=h*QB+q_, n0=strip*64;
  const unsigned short* Fq=fq+(size_t)hq*SEQ*DHD;
  const unsigned short* Fk=fk+(size_t)hq*SEQ*DHD;
  const unsigned short* FvT=fvT+(size_t)hq*DHD*SEQ;
  __shared__ unsigned short KT[128*64];     // K rows (m) x 64 d
  __shared__ unsigned short VT[64*128];     // [d][m], pitch 256B
  __shared__ unsigned short P[64*64];       // [n][m-half] bf16, pitch 128B
  __shared__ float rskL[512], i1kL[512];
  int t=threadIdx.x, w=t>>6, lane=t&63, l16=lane&15, lh=lane>>4;
  int n = n0 + w*16 + l16;
  for (int i=t;i<512;i+=256){ rskL[i]=rskA[hq*SEQ+i]; i1kL[i]=i1kA[hq*SEQ+i]; }
  float c2v=c2A[hq];
  float pa=params[h*2], pb=params[h*2+1];
  float aqv = aqA[hq*SEQ+n];
  float c1v = c1A[hq*SEQ+n];
  float iq1 = i1qA[hq*SEQ+n];
  float rmc = rmaxcA[hq*SEQ+n];
  float rmo = rmaxoA[hq*SEQ+n];
  float pbk = pb*KCOV;
  float ra  = pa*iq1;
  float bndc = 0.99f*pa;
  float rowc = -pbk*(c1v - aqv*c2v);
  float r3   = pbk*aqv;
  float Mrow = fmaf(pa, rmc, pb*rmo);
  short8 qa[2];
  #pragma unroll
  for (int ks=0;ks<2;ks++)
    qa[ks] = *reinterpret_cast<const short8*>(&Fq[(size_t)n*DHD + ks*32 + lh*8]);
  short8 ones;
  #pragma unroll
  for (int i=0;i<8;i++) ones[i] = (short)0x3F80;
  f32x4 accO[4];
  #pragma unroll
  for (int j=0;j<4;j++) accO[j]=(f32x4){0.f,0.f,0.f,0.f};
  f32x4 den = (f32x4){0.f,0.f,0.f,0.f};
  for (int mc=0;mc<4;mc++){
    int m0=mc*128;
    __syncthreads();
    for (int it=0;it<4;++it){
      int idx=it*256+t, row=idx>>3, qc=idx&7;
      ushort8v vv = *reinterpret_cast<const ushort8v*>(&Fk[(size_t)(m0+row)*DHD + qc*8]);
      tile_st16(KT,row,128,qc*16,vv);
    }
    for (int it=0;it<4;++it){
      int idx=it*256+t, dd=idx>>4, c=idx&15;
      ushort8v vv=*reinterpret_cast<const ushort8v*>(&FvT[(size_t)dd*SEQ + m0 + c*8]);
      tile_st16(VT, dd, 256, c*16, vv);
    }
    __syncthreads();
    #pragma unroll
    for (int mh=0;mh<2;mh++){
      int mb = mh*64;
      // QK^T (swapped): acc rows = K rows m, cols = own n
      f32x4 acc[4];
      #pragma unroll
      for (int mf=0;mf<4;mf++) acc[mf]=(f32x4){0.f,0.f,0.f,0.f};
      #pragma unroll
      for (int mf=0;mf<4;mf++){
        #pragma unroll
        for (int ks=0;ks<2;ks++){
          short8 kf = frag_ld(KT, mb+mf*16+l16, 128, lh*16+ks*64);
          acc[mf] = MFMA(kf, qa[ks], acc[mf]);
        }
      }
      // transform + exp(logit - Mrow), write P[n][m] packed
      int prow = w*16 + l16;
      #pragma unroll
      for (int mf=0;mf<4;mf++){
        int ml = m0 + mb + mf*16 + lh*4;
        float4 rsk4 = *reinterpret_cast<const float4*>(&rskL[ml]);
        float4 i1k4 = *reinterpret_cast<const float4*>(&i1kL[ml]);
        float rk[4]={rsk4.x,rsk4.y,rsk4.z,rsk4.w};
        float ik[4]={i1k4.x,i1k4.y,i1k4.z,i1k4.w};
        #pragma unroll
        for (int r=0;r<4;r++){
          float S = acc[mf][r];
          float tt = S*ra; tt *= ik[r];
          float cc = clampf(tt, -bndc, bndc);
          float u = fmaf(pbk, S, rowc);
          float lin = fmaf(-r3, rk[r], u);
          acc[mf][r] = __expf(cc + lin - Mrow);
        }
        unsigned lo = cvtpk(acc[mf][0], acc[mf][1]);
        unsigned hi = cvtpk(acc[mf][2], acc[mf][3]);
        int pbyte = (mf*32 + lh*8) ^ ((prow&7)<<4);
        *reinterpret_cast<uint2*>(reinterpret_cast<char*>(P) + prow*128 + pbyte)
          = make_uint2(lo, hi);
      }
      // PV + denominator (wave-local P rows; in-wave LDS ordering suffices)
      #pragma unroll
      for (int ks=0;ks<2;ks++){
        short8 pfrag = frag_ld(P, prow, 128, lh*16 + ks*64);
        #pragma unroll
        for (int dcf=0;dcf<4;dcf++){
          short8 vb = frag_ld(VT, dcf*16+l16, 256, mb*2 + ks*64 + lh*16);
          accO[dcf] = MFMA(pfrag, vb, accO[dcf]);
        }
        den = MFMA(pfrag, ones, den);
      }
    }
  }
  // epilogue: normalize, bounce through P, coalesced store
  f32x4 invD;
  #pragma unroll
  for (int r=0;r<4;r++) invD[r] = 1.0f/den[r];
  #pragma unroll
  for (int dcf=0;dcf<4;dcf++){
    #pragma unroll
    for (int r=0;r<4;r++){
      int row = w*16 + lh*4 + r;
      int col = dcf*16 + l16;
      int addr = row*128 + ((col*2) ^ ((row&7)<<4));
      *reinterpret_cast<unsigned short*>(reinterpret_cast<char*>(P) + addr)
        = f2bf(accO[dcf][r]*invD[r]);
    }
  }
  __syncthreads();
  for (int it=0; it<2; ++it){
    int idx = it*256 + t;
    int row = idx>>3, c = idx&7;
    int addr = row*128 + ((c*16) ^ ((row&7)<<4));
    ushort8v vv = *reinterpret_cast<ushort8v*>(reinterpret_cast<char*>(P) + addr);
    *reinterpret_cast<ushort8v*>(
      &attn_bf[(size_t)(q_*SEQ + n0 + row)*DMODEL + h*DHD + c*8]) = vv;
  }
}

// ---------------------------------------------------------------- KO: output projection (MFMA)
__global__ void __launch_bounds__(256) out_mfma_kernel(
    const unsigned short* __restrict__ attn_bf, const unsigned short* __restrict__ WoT,
    const float* __restrict__ bias, float* __restrict__ out)
{
  int r0=blockIdx.x*128;
  int c0=blockIdx.y*128;
  __shared__ unsigned short AT[128*64];
  __shared__ unsigned short WT[128*64];
  int t=threadIdx.x, w=t>>6, lane=t&63, l16=lane&15, lh=lane>>4;
  f32x4 acc[4][4];
  #pragma unroll
  for(int i=0;i<4;i++){ for(int j=0;j<4;j++) acc[i][j]=(f32x4){0.f,0.f,0.f,0.f}; }
  for (int k0=0;k0<DMODEL;k0+=64){
    __syncthreads();
    for (int it=0; it<4; ++it){
      int idx=it*256+t, row=idx>>3, q=idx&7;
      ushort8v v = *reinterpret_cast<const ushort8v*>(&attn_bf[(size_t)(r0+row)*DMODEL + k0 + q*8]);
      tile_st16(AT, row, 128, q*16, v);
    }
    for (int it=0; it<4; ++it){
      int idx=it*256+t, row=idx>>3, q=idx&7;
      ushort8v v = *reinterpret_cast<const ushort8v*>(&WoT[(size_t)(c0+row)*DMODEL + k0 + q*8]);
      tile_st16(WT, row, 128, q*16, v);
    }
    __syncthreads();
    int nr=(w&1)*64, mr=(w>>1)*64;
    #pragma unroll
    for (int ks=0; ks<2; ++ks){
      int kb = lh*16 + ks*64;
      short8 a[4], b[4];
      #pragma unroll
      for (int i=0;i<4;i++) a[i] = frag_ld(WT, nr+i*16+l16, 128, kb);
      #pragma unroll
      for (int j=0;j<4;j++) b[j] = frag_ld(AT, mr+j*16+l16, 128, kb);
      #pragma unroll
      for (int i=0;i<4;i++){
        #pragma unroll
        for (int j=0;j<4;j++) acc[i][j]=MFMA(a[i],b[j],acc[i][j]);
      }
    }
  }
  #pragma unroll
  for (int i=0;i<4;i++){
    int nb = c0+(w&1)*64+i*16+lh*4;
    float4 b4 = *reinterpret_cast<const float4*>(&bias[nb]);
    #pragma unroll
    for (int j=0;j<4;j++){
      int mg = r0+(w>>1)*64+j*16+l16;
      f32x4 o = acc[i][j];
      o[0]+=b4.x; o[1]+=b4.y; o[2]+=b4.z; o[3]+=b4.w;
      *reinterpret_cast<f32x4*>(&out[(size_t)mg*DMODEL + nb]) = o;
    }
  }
}

// ----------------------------------------------------------------
extern "C" void kernel_launch(void* const* d_in, const int* in_sizes, int n_in,
                              void* d_out, int out_size, void* d_ws, size_t ws_size,
                              hipStream_t stream)
{
  (void)in_sizes; (void)n_in; (void)out_size; (void)ws_size;
  const float* q     = (const float*)d_in[0];
  const float* k     = (const float*)d_in[1];
  const float* v     = (const float*)d_in[2];
  const float* ln_g  = (const float*)d_in[3];
  const float* ln_b  = (const float*)d_in[4];
  const float* W_in  = (const float*)d_in[5];
  const float* wp1w  = (const float*)d_in[6];
  const float* wp1b  = (const float*)d_in[7];
  const float* wplg  = (const float*)d_in[8];
  const float* wplb  = (const float*)d_in[9];
  const float* wp2w  = (const float*)d_in[10];
  const float* wp2b  = (const float*)d_in[11];
  const float* wp3w  = (const float*)d_in[12];
  const float* wp3b  = (const float*)d_in[13];
  const float* temp  = (const float*)d_in[14];
  const float* W_out = (const float*)d_in[15];
  const float* b_out = (const float*)d_in[16];
  float* out = (float*)d_out;

  char* wsb = (char*)d_ws;
  size_t off = 0;
  auto alloc = [&](size_t bytes)->char*{
    char* p = wsb + off; off += (bytes + 255) & ~(size_t)255; return p;
  };
  unsigned short* xln    = (unsigned short*)alloc((size_t)3*NROWS*DMODEL*2);
  unsigned short* fq_b   = (unsigned short*)alloc((size_t)NHQ*SEQ*DHD*2);
  unsigned short* fk_b   = (unsigned short*)alloc((size_t)NHQ*SEQ*DHD*2);
  unsigned short* fvT_b  = (unsigned short*)alloc((size_t)NHQ*SEQ*DHD*2);
  unsigned short* attn_b = (unsigned short*)alloc((size_t)NROWS*DMODEL*2);
  unsigned short* WiT    = (unsigned short*)alloc((size_t)DMODEL*DMODEL*2);
  unsigned short* WoT    = (unsigned short*)alloc((size_t)DMODEL*DMODEL*2);
  float* aqA    = (float*)alloc(NHQ*SEQ*4);
  float* c1A    = (float*)alloc(NHQ*SEQ*4);
  float* i1qA   = (float*)alloc(NHQ*SEQ*4);
  float* rskA   = (float*)alloc(NHQ*SEQ*4);
  float* i1kA   = (float*)alloc(NHQ*SEQ*4);
  float* rmaxcA = (float*)alloc(NHQ*SEQ*4);
  float* rmaxoA = (float*)alloc(NHQ*SEQ*4);
  float* c2A    = (float*)alloc(NHQ*4);
  float* qgp    = (float*)alloc(NHQ*64*4);
  float* kgp    = (float*)alloc(NHQ*64*4);
  float* momf   = (float*)alloc((size_t)NHQ*8*5*4);
  double* varp  = (double*)alloc((size_t)NHQ*8*4*8);
  float* params = (float*)alloc(64);

  prep_kernel<<<6272, 256, 0, stream>>>(q, k, v, ln_g, ln_b, W_in, W_out, xln, WiT, WoT);
  proj_mfma_kernel<<<dim3(64,4,3), 256, 0, stream>>>(xln, WiT, fq_b, fk_b, fvT_b,
                                                     aqA, i1qA, rskA, i1kA);
  colstat_kernel<<<dim3(NHQ, 2), 256, 0, stream>>>(fq_b, fk_b, qgp, kgp, c2A);
  score_m1_kernel<<<dim3(8, QB, NH), 256, 0, stream>>>(fq_b, fk_b, aqA, i1qA, rskA, i1kA,
                                                       c2A, kgp, c1A, rmaxcA, rmaxoA, momf, varp);
  finalize_kernel<<<1, 256, 0, stream>>>(qgp, kgp, wp1w, wp1b, wplg, wplb, wp2w, wp2b,
                                         wp3w, wp3b, temp, momf, varp, params);
  attn_m2_kernel<<<dim3(8, QB, NH), 256, 0, stream>>>(fq_b, fk_b, fvT_b, aqA, c1A, i1qA,
                                                      rskA, i1kA, c2A, params, rmaxcA, rmaxoA, attn_b);
  out_mfma_kernel<<<dim3(64,4), 256, 0, stream>>>(attn_b, WoT, b_out, out);
}